// Round 3
// baseline (685.643 us; speedup 1.0000x reference)
//
#include <hip/hip_runtime.h>
#include <math.h>

static constexpr float kSigma2 = 0.05f * 0.05f;

__device__ __forceinline__ int load_idx(const void* ei, long long j, int is64) {
    if (is64) return (int)(((const long long*)ei)[j]);
    return ((const int*)ei)[j];
}

// Detect whether edge_index is int64 (all odd int32 words zero) or int32.
__global__ void k_detect(const int* __restrict__ ei32, int E, int* __restrict__ nz) {
    int t = threadIdx.x;
    int lim = E < 2048 ? E : 2048;
    int acc = 0;
    for (int k = t; k < lim; k += blockDim.x) acc |= ei32[2 * k + 1];
    if (acc) atomicOr(nz, 1);
}

// ---------------- shared Kabsch core (fp64, Jacobi on M^T M) ----------------
__device__ void kabsch_from_M(const double M[3][3], double Rm[3][3]) {
    Rm[0][0] = 1; Rm[0][1] = 0; Rm[0][2] = 0;
    Rm[1][0] = 0; Rm[1][1] = 1; Rm[1][2] = 0;
    Rm[2][0] = 0; Rm[2][1] = 0; Rm[2][2] = 1;

    double frob2 = 0.0;
#pragma unroll
    for (int r = 0; r < 3; ++r)
#pragma unroll
        for (int c = 0; c < 3; ++c) frob2 += M[r][c] * M[r][c];
    if (frob2 <= 1e-80) return;

    double A[3][3];
#pragma unroll
    for (int r = 0; r < 3; ++r)
#pragma unroll
        for (int c = 0; c < 3; ++c) {
            double s = 0.0;
#pragma unroll
            for (int k = 0; k < 3; ++k) s += M[k][r] * M[k][c];
            A[r][c] = s;
        }
    double V[3][3] = {{1, 0, 0}, {0, 1, 0}, {0, 0, 1}};
    const int PL[3] = {0, 0, 1};
    const int QL[3] = {1, 2, 2};
    for (int sweep = 0; sweep < 15; ++sweep) {
        double off = fabs(A[0][1]) + fabs(A[0][2]) + fabs(A[1][2]);
        if (off == 0.0) break;
        for (int pi = 0; pi < 3; ++pi) {
            int p = PL[pi], q = QL[pi], r3 = 3 - p - q;
            double apq = A[p][q];
            if (apq == 0.0) continue;
            double theta = (A[q][q] - A[p][p]) / (2.0 * apq);
            double t = copysign(1.0, theta) / (fabs(theta) + sqrt(theta * theta + 1.0));
            double c = 1.0 / sqrt(t * t + 1.0);
            double s = t * c;
            A[p][p] -= t * apq;
            A[q][q] += t * apq;
            A[p][q] = 0.0; A[q][p] = 0.0;
            double arp = A[r3][p], arq = A[r3][q];
            A[r3][p] = c * arp - s * arq; A[p][r3] = A[r3][p];
            A[r3][q] = s * arp + c * arq; A[q][r3] = A[r3][q];
#pragma unroll
            for (int k = 0; k < 3; ++k) {
                double vp = V[k][p], vq = V[k][q];
                V[k][p] = c * vp - s * vq;
                V[k][q] = s * vp + c * vq;
            }
        }
    }
    double lam[3] = {A[0][0], A[1][1], A[2][2]};
    int id0 = 0, id1 = 1, id2 = 2, tt;
    if (lam[id0] < lam[id1]) { tt = id0; id0 = id1; id1 = tt; }
    if (lam[id0] < lam[id2]) { tt = id0; id0 = id2; id2 = tt; }
    if (lam[id1] < lam[id2]) { tt = id1; id1 = id2; id2 = tt; }
    double v1[3] = {V[0][id0], V[1][id0], V[2][id0]};
    double v2[3] = {V[0][id1], V[1][id1], V[2][id1]};
    double v3[3] = {V[0][id2], V[1][id2], V[2][id2]};

    double b1[3], b2[3];
#pragma unroll
    for (int r = 0; r < 3; ++r) {
        b1[r] = M[r][0] * v1[0] + M[r][1] * v1[1] + M[r][2] * v1[2];
        b2[r] = M[r][0] * v2[0] + M[r][1] * v2[1] + M[r][2] * v2[2];
    }
    double n1 = sqrt(b1[0] * b1[0] + b1[1] * b1[1] + b1[2] * b1[2]);
    if (n1 <= 1e-150) return;
    double u1[3] = {b1[0] / n1, b1[1] / n1, b1[2] / n1};
    double dot = u1[0] * b2[0] + u1[1] * b2[1] + u1[2] * b2[2];
    double w2[3] = {b2[0] - dot * u1[0], b2[1] - dot * u1[1], b2[2] - dot * u1[2]};
    double n2 = sqrt(w2[0] * w2[0] + w2[1] * w2[1] + w2[2] * w2[2]);
    double u2[3];
    if (n2 > n1 * 1e-12) {
        u2[0] = w2[0] / n2; u2[1] = w2[1] / n2; u2[2] = w2[2] / n2;
    } else {
        double ex0 = (fabs(u1[0]) < 0.9) ? 1.0 : 0.0;
        double ex1 = 1.0 - ex0;
        double cx = u1[1] * 0.0 - u1[2] * ex1;
        double cy = u1[2] * ex0 - u1[0] * 0.0;
        double cz = u1[0] * ex1 - u1[1] * ex0;
        double cn = sqrt(cx * cx + cy * cy + cz * cz);
        u2[0] = cx / cn; u2[1] = cy / cn; u2[2] = cz / cn;
    }
    double u3[3] = {u1[1] * u2[2] - u1[2] * u2[1],
                    u1[2] * u2[0] - u1[0] * u2[2],
                    u1[0] * u2[1] - u1[1] * u2[0]};
    double dV = v1[0] * (v2[1] * v3[2] - v2[2] * v3[1])
              - v1[1] * (v2[0] * v3[2] - v2[2] * v3[0])
              + v1[2] * (v2[0] * v3[1] - v2[1] * v3[0]);
    dV = (dV >= 0.0) ? 1.0 : -1.0;
#pragma unroll
    for (int r = 0; r < 3; ++r)
#pragma unroll
        for (int c = 0; c < 3; ++c)
            Rm[r][c] = u1[r] * v1[c] + u2[r] * v2[c] + dV * u3[r] * v3[c];
}

// ---------------- bucketed counting-sort path ----------------
// bucket = dst >> 7 (128 nodes per bucket). payload: x = (nbr<<7)|(dst&127), y = weight bits.

__global__ void __launch_bounds__(256) k_bhist(const void* __restrict__ ei,
                                               int* __restrict__ btot16,
                                               const int* __restrict__ nz,
                                               int E, int N, int nbuckets) {
    __shared__ int lhist[1024];
    int t = threadIdx.x;
    long long base = (long long)blockIdx.x * 2048;
    long long rem = (long long)E - base;
    int cnt = (rem < 2048) ? (int)rem : 2048;
    int is64 = (*nz == 0);
    for (int i = t; i < 1024; i += 256) lhist[i] = 0;
    __syncthreads();
#pragma unroll
    for (int k = 0; k < 8; ++k) {
        int idx = (k << 8) + t;
        if (idx < cnt) {
            int d = load_idx(ei, base + idx, is64);
            if ((unsigned)d < (unsigned)N) atomicAdd(&lhist[d >> 7], 1);
        }
    }
    __syncthreads();
    for (int b = t; b < 1024; b += 256) {
        int c = lhist[b];
        if (c > 0 && b < nbuckets) atomicAdd(&btot16[b * 16], c);
    }
}

__global__ void k_scan(const int* __restrict__ btot16, int* __restrict__ boff,
                       int* __restrict__ cur16, int nbuckets) {
    __shared__ int sm[1024];
    int t = threadIdx.x;
    int v = (t < nbuckets) ? btot16[t * 16] : 0;
    sm[t] = v;
    __syncthreads();
    for (int s = 1; s < 1024; s <<= 1) {
        int x = (t >= s) ? sm[t - s] : 0;
        __syncthreads();
        sm[t] += x;
        __syncthreads();
    }
    if (t < nbuckets) {
        int excl = sm[t] - v;
        boff[t] = excl;
        cur16[t * 16] = excl;
    }
    if (t == nbuckets - 1) boff[nbuckets] = sm[t];
}

__global__ void __launch_bounds__(256) k_binscatter(const void* __restrict__ ei,
                                                    const float* __restrict__ ew,
                                                    int* __restrict__ cur16,
                                                    int2* __restrict__ sedge,
                                                    const int* __restrict__ nz,
                                                    int E, int N, int nbuckets) {
    __shared__ int2 stage[2048];
    __shared__ unsigned short binOf[2048];
    __shared__ int lhist[1024];
    __shared__ int lincl[1024];
    __shared__ int gbase[1024];
    int t = threadIdx.x;
    long long base = (long long)blockIdx.x * 2048;
    long long rem = (long long)E - base;
    int cnt = (rem < 2048) ? (int)rem : 2048;
    int is64 = (*nz == 0);
    for (int i = t; i < 1024; i += 256) lhist[i] = 0;
    __syncthreads();

    int mybin[8];
    int myrank[8];
    int2 mypay[8];
#pragma unroll
    for (int k = 0; k < 8; ++k) {
        mybin[k] = -1;
        int idx = (k << 8) + t;
        if (idx < cnt) {
            long long e = base + idx;
            int d = load_idx(ei, e, is64);
            int n = load_idx(ei, (long long)E + e, is64);
            if ((unsigned)d < (unsigned)N && (unsigned)n < (unsigned)N) {
                int bb = d >> 7;
                mybin[k] = bb;
                myrank[k] = atomicAdd(&lhist[bb], 1);
                mypay[k].x = (n << 7) | (d & 127);
                mypay[k].y = __float_as_int(ew[e]);
            }
        }
    }
    __syncthreads();
    for (int i = t; i < 1024; i += 256) lincl[i] = lhist[i];
    __syncthreads();
    for (int s = 1; s < 1024; s <<= 1) {
        int tmp[4];
#pragma unroll
        for (int j = 0; j < 4; ++j) {
            int i = (j << 8) + t;
            tmp[j] = (i >= s) ? lincl[i - s] : 0;
        }
        __syncthreads();
#pragma unroll
        for (int j = 0; j < 4; ++j) {
            int i = (j << 8) + t;
            lincl[i] += tmp[j];
        }
        __syncthreads();
    }
#pragma unroll
    for (int k = 0; k < 8; ++k) {
        if (mybin[k] >= 0) {
            int excl = lincl[mybin[k]] - lhist[mybin[k]];
            int lpos = excl + myrank[k];
            stage[lpos] = mypay[k];
            binOf[lpos] = (unsigned short)mybin[k];
        }
    }
    __syncthreads();
    for (int bb = t; bb < 1024; bb += 256) {
        int c = lhist[bb];
        gbase[bb] = (c > 0 && bb < nbuckets) ? atomicAdd(&cur16[bb * 16], c) : 0;
    }
    __syncthreads();
    int total = lincl[1023];
    for (int lpos = t; lpos < total; lpos += 256) {
        int bb = binOf[lpos];
        int excl = lincl[bb] - lhist[bb];
        sedge[gbase[bb] + (lpos - excl)] = stage[lpos];
    }
}

// One block per bucket (128 nodes): LDS-atomic accumulation, then per-thread Kabsch.
__global__ void __launch_bounds__(256) k_node(const int* __restrict__ boff,
                                              const int2* __restrict__ sedge,
                                              const float* __restrict__ src,
                                              const float* __restrict__ tgt,
                                              float* __restrict__ Rout,
                                              float* __restrict__ Tout, int N) {
    __shared__ float acc[7][128];   // cnt, sx, sy, sz, tx, ty, tz
    __shared__ float ctr[6][128];   // scx..., tcx...
    __shared__ float mm[9][128];
    int b = blockIdx.x, t = threadIdx.x;
    int e0 = boff[b], e1 = boff[b + 1];

    for (int i = t; i < 7 * 128; i += 256) ((float*)acc)[i] = 0.0f;
    for (int i = t; i < 9 * 128; i += 256) ((float*)mm)[i] = 0.0f;
    __syncthreads();

    for (int j = e0 + t; j < e1; j += 256) {
        int2 p = sedge[j];
        int dlow = p.x & 127;
        int n = ((unsigned)p.x) >> 7;
        atomicAdd(&acc[0][dlow], 1.0f);
        atomicAdd(&acc[1][dlow], src[3 * n + 0]);
        atomicAdd(&acc[2][dlow], src[3 * n + 1]);
        atomicAdd(&acc[3][dlow], src[3 * n + 2]);
        atomicAdd(&acc[4][dlow], tgt[3 * n + 0]);
        atomicAdd(&acc[5][dlow], tgt[3 * n + 1]);
        atomicAdd(&acc[6][dlow], tgt[3 * n + 2]);
    }
    __syncthreads();
    if (t < 128) {
        float inv = 1.0f / fmaxf(acc[0][t], 1.0f);
#pragma unroll
        for (int f = 0; f < 6; ++f) ctr[f][t] = acc[1 + f][t] * inv;
    }
    __syncthreads();
    for (int j = e0 + t; j < e1; j += 256) {
        int2 p = sedge[j];
        int dlow = p.x & 127;
        int n = ((unsigned)p.x) >> 7;
        float w = __int_as_float(p.y);
        float a0 = (src[3 * n + 0] - ctr[0][dlow]) * w;
        float a1 = (src[3 * n + 1] - ctr[1][dlow]) * w;
        float a2 = (src[3 * n + 2] - ctr[2][dlow]) * w;
        float b0 = tgt[3 * n + 0] - ctr[3][dlow];
        float b1 = tgt[3 * n + 1] - ctr[4][dlow];
        float b2 = tgt[3 * n + 2] - ctr[5][dlow];
        atomicAdd(&mm[0][dlow], a0 * b0); atomicAdd(&mm[1][dlow], a0 * b1); atomicAdd(&mm[2][dlow], a0 * b2);
        atomicAdd(&mm[3][dlow], a1 * b0); atomicAdd(&mm[4][dlow], a1 * b1); atomicAdd(&mm[5][dlow], a1 * b2);
        atomicAdd(&mm[6][dlow], a2 * b0); atomicAdd(&mm[7][dlow], a2 * b1); atomicAdd(&mm[8][dlow], a2 * b2);
    }
    __syncthreads();
    if (t < 128) {
        long long i = (long long)b * 128 + t;
        if (i < N) {
            double M[3][3] = {{mm[0][t], mm[1][t], mm[2][t]},
                              {mm[3][t], mm[4][t], mm[5][t]},
                              {mm[6][t], mm[7][t], mm[8][t]}};
            double Rm[3][3];
            kabsch_from_M(M, Rm);
            double scx = ctr[0][t], scy = ctr[1][t], scz = ctr[2][t];
            double tcx = ctr[3][t], tcy = ctr[4][t], tcz = ctr[5][t];
#pragma unroll
            for (int r = 0; r < 3; ++r)
#pragma unroll
                for (int c = 0; c < 3; ++c)
                    Rout[9 * i + 3 * r + c] = (float)Rm[r][c];
            Tout[3 * i + 0] = (float)(tcx - (Rm[0][0] * scx + Rm[0][1] * scy + Rm[0][2] * scz));
            Tout[3 * i + 1] = (float)(tcy - (Rm[1][0] * scx + Rm[1][1] * scy + Rm[1][2] * scz));
            Tout[3 * i + 2] = (float)(tcz - (Rm[2][0] * scx + Rm[2][1] * scy + Rm[2][2] * scz));
        }
    }
}

__global__ void k_weights(const void* __restrict__ ei,
                          const float* __restrict__ src,
                          const float* __restrict__ tgt,
                          const float* __restrict__ R,
                          const float* __restrict__ T,
                          float* __restrict__ wout,
                          const int* __restrict__ nz, int E, int N) {
    int e = blockIdx.x * blockDim.x + threadIdx.x;
    if (e >= E) return;
    int is64 = (*nz == 0);
    int n = load_idx(ei, (long long)E + e, is64);
    float w = 1.0f;
    if ((unsigned)n < (unsigned)N) {
        float p0 = src[3 * n + 0], p1 = src[3 * n + 1], p2 = src[3 * n + 2];
        float q0 = tgt[3 * n + 0], q1 = tgt[3 * n + 1], q2 = tgt[3 * n + 2];
        const float* Rn = R + 9 * (long long)n;
        const float* Tn = T + 3 * (long long)n;
        float x0 = Rn[0] * p0 + Rn[1] * p1 + Rn[2] * p2 + Tn[0];
        float x1 = Rn[3] * p0 + Rn[4] * p1 + Rn[5] * p2 + Tn[1];
        float x2 = Rn[6] * p0 + Rn[7] * p1 + Rn[8] * p2 + Tn[2];
        float d0 = x0 - q0, d1 = x1 - q1, d2 = x2 - q2;
        float dd = d0 * d0 + d1 * d1 + d2 * d2;
        w = kSigma2 / (dd + kSigma2);
    }
    wout[e] = w;
}

// ---------------- fallback atomic path ----------------

__global__ void k_accum1(const void* __restrict__ ei, const float* __restrict__ src,
                         const float* __restrict__ tgt, float* __restrict__ cnt,
                         float* __restrict__ ssum, float* __restrict__ tsum,
                         const int* __restrict__ nz, int E, int N) {
    int e = blockIdx.x * blockDim.x + threadIdx.x;
    if (e >= E) return;
    int is64 = (*nz == 0);
    int d = load_idx(ei, e, is64);
    int n = load_idx(ei, (long long)E + e, is64);
    if ((unsigned)d >= (unsigned)N || (unsigned)n >= (unsigned)N) return;
    atomicAdd(&cnt[d], 1.0f);
    atomicAdd(&ssum[3 * d + 0], src[3 * n + 0]);
    atomicAdd(&ssum[3 * d + 1], src[3 * n + 1]);
    atomicAdd(&ssum[3 * d + 2], src[3 * n + 2]);
    atomicAdd(&tsum[3 * d + 0], tgt[3 * n + 0]);
    atomicAdd(&tsum[3 * d + 1], tgt[3 * n + 1]);
    atomicAdd(&tsum[3 * d + 2], tgt[3 * n + 2]);
}

__global__ void k_centers(float* __restrict__ cnt, float* __restrict__ ssum,
                          float* __restrict__ tsum, int N) {
    int i = blockIdx.x * blockDim.x + threadIdx.x;
    if (i >= N) return;
    float inv = 1.0f / fmaxf(cnt[i], 1.0f);
    ssum[3 * i + 0] *= inv; ssum[3 * i + 1] *= inv; ssum[3 * i + 2] *= inv;
    tsum[3 * i + 0] *= inv; tsum[3 * i + 1] *= inv; tsum[3 * i + 2] *= inv;
}

__global__ void k_accum2(const void* __restrict__ ei, const float* __restrict__ src,
                         const float* __restrict__ tgt, const float* __restrict__ ew,
                         const float* __restrict__ sc, const float* __restrict__ tc,
                         float* __restrict__ Mm, const int* __restrict__ nz, int E, int N) {
    int e = blockIdx.x * blockDim.x + threadIdx.x;
    if (e >= E) return;
    int is64 = (*nz == 0);
    int d = load_idx(ei, e, is64);
    int n = load_idx(ei, (long long)E + e, is64);
    if ((unsigned)d >= (unsigned)N || (unsigned)n >= (unsigned)N) return;
    float w = ew[e];
    float a0 = (src[3 * n + 0] - sc[3 * d + 0]) * w;
    float a1 = (src[3 * n + 1] - sc[3 * d + 1]) * w;
    float a2 = (src[3 * n + 2] - sc[3 * d + 2]) * w;
    float b0 = tgt[3 * n + 0] - tc[3 * d + 0];
    float b1 = tgt[3 * n + 1] - tc[3 * d + 1];
    float b2 = tgt[3 * n + 2] - tc[3 * d + 2];
    float* Md = Mm + 9 * (long long)d;
    atomicAdd(Md + 0, a0 * b0); atomicAdd(Md + 1, a0 * b1); atomicAdd(Md + 2, a0 * b2);
    atomicAdd(Md + 3, a1 * b0); atomicAdd(Md + 4, a1 * b1); atomicAdd(Md + 5, a1 * b2);
    atomicAdd(Md + 6, a2 * b0); atomicAdd(Md + 7, a2 * b1); atomicAdd(Md + 8, a2 * b2);
}

__global__ void k_kabsch(const float* __restrict__ Mm, const float* __restrict__ sc,
                         const float* __restrict__ tc, float* __restrict__ Rout,
                         float* __restrict__ Tout, int N) {
    int i = blockIdx.x * blockDim.x + threadIdx.x;
    if (i >= N) return;
    double M[3][3];
#pragma unroll
    for (int r = 0; r < 3; ++r)
#pragma unroll
        for (int c = 0; c < 3; ++c)
            M[r][c] = (double)Mm[9 * (long long)i + 3 * r + c];
    double Rm[3][3];
    kabsch_from_M(M, Rm);
    double s0 = sc[3 * i + 0], s1 = sc[3 * i + 1], s2 = sc[3 * i + 2];
    double t0 = tc[3 * i + 0], t1 = tc[3 * i + 1], t2 = tc[3 * i + 2];
#pragma unroll
    for (int r = 0; r < 3; ++r)
#pragma unroll
        for (int c = 0; c < 3; ++c)
            Rout[9 * (long long)i + 3 * r + c] = (float)Rm[r][c];
    Tout[3 * i + 0] = (float)(t0 - (Rm[0][0] * s0 + Rm[0][1] * s1 + Rm[0][2] * s2));
    Tout[3 * i + 1] = (float)(t1 - (Rm[1][0] * s0 + Rm[1][1] * s1 + Rm[1][2] * s2));
    Tout[3 * i + 2] = (float)(t2 - (Rm[2][0] * s0 + Rm[2][1] * s1 + Rm[2][2] * s2));
}

extern "C" void kernel_launch(void* const* d_in, const int* in_sizes, int n_in,
                              void* d_out, int out_size, void* d_ws, size_t ws_size,
                              hipStream_t stream) {
    const float* src = (const float*)d_in[0];
    const float* tgt = (const float*)d_in[1];
    const void* ei = d_in[2];
    const float* ew = (const float*)d_in[3];
    int N = in_sizes[0] / 3;
    int E = in_sizes[3];

    float* out = (float*)d_out;
    float* Rout = out;
    float* Tout = out + (size_t)9 * N;
    float* Wout = out + (size_t)12 * N;

    int eb = (E + 255) / 256;
    int nb = (N + 255) / 256;
    int nbuckets = (N + 127) / 128;
    int tiles = (int)(((long long)E + 2047) / 2048);

    // ws layout: [nz(16) | btot16(nbuckets*16) | cur16(nbuckets*16) | boff(nbuckets+1) | pad | sedge(E int2)]
    size_t ctrl_ints = 16 + (size_t)nbuckets * 16 * 2 + (nbuckets + 1);
    ctrl_ints = (ctrl_ints + 1) & ~(size_t)1;
    size_t need = ctrl_ints * sizeof(int) + (size_t)E * sizeof(int2);

    if (N <= 131072 && nbuckets <= 1024 && ws_size >= need) {
        int* nz = (int*)d_ws;
        int* btot16 = nz + 16;
        int* cur16 = btot16 + (size_t)nbuckets * 16;
        int* boff = cur16 + (size_t)nbuckets * 16;
        int2* sedge = (int2*)((int*)d_ws + ctrl_ints);

        hipMemsetAsync(d_ws, 0, ctrl_ints * sizeof(int), stream);

        k_detect<<<1, 256, 0, stream>>>((const int*)ei, E, nz);
        k_bhist<<<tiles, 256, 0, stream>>>(ei, btot16, nz, E, N, nbuckets);
        k_scan<<<1, 1024, 0, stream>>>(btot16, boff, cur16, nbuckets);
        k_binscatter<<<tiles, 256, 0, stream>>>(ei, ew, cur16, sedge, nz, E, N, nbuckets);
        k_node<<<nbuckets, 256, 0, stream>>>(boff, sedge, src, tgt, Rout, Tout, N);
        k_weights<<<eb, 256, 0, stream>>>(ei, src, tgt, Rout, Tout, Wout, nz, E, N);
    } else {
        // fallback: atomic path
        float* cnt = (float*)d_ws;
        float* ssum = cnt + N;
        float* tsum = ssum + 3 * (size_t)N;
        float* Mm = tsum + 3 * (size_t)N;
        int* nz = (int*)(Mm + 9 * (size_t)N);
        size_t ws_bytes = (size_t)16 * N * sizeof(float) + 16;
        hipMemsetAsync(d_ws, 0, ws_bytes, stream);
        k_detect<<<1, 256, 0, stream>>>((const int*)ei, E, nz);
        k_accum1<<<eb, 256, 0, stream>>>(ei, src, tgt, cnt, ssum, tsum, nz, E, N);
        k_centers<<<nb, 256, 0, stream>>>(cnt, ssum, tsum, N);
        k_accum2<<<eb, 256, 0, stream>>>(ei, src, tgt, ew, ssum, tsum, Mm, nz, E, N);
        k_kabsch<<<nb, 256, 0, stream>>>(Mm, ssum, tsum, Rout, Tout, N);
        k_weights<<<eb, 256, 0, stream>>>(ei, src, tgt, Rout, Tout, Wout, nz, E, N);
    }
}

// Round 4
// 506.753 us; speedup vs baseline: 1.3530x; 1.3530x over previous
//
#include <hip/hip_runtime.h>
#include <math.h>

static constexpr float kSigma2 = 0.05f * 0.05f;
static constexpr int kCap = 5120;  // max edges per 128-node bucket in LDS sort

__device__ __forceinline__ int load_idx(const void* ei, long long j, int is64) {
    if (is64) return (int)(((const long long*)ei)[j]);
    return ((const int*)ei)[j];
}

// Detect whether edge_index is int64 (all odd int32 words zero) or int32.
__global__ void k_detect(const int* __restrict__ ei32, int E, int* __restrict__ nz) {
    int t = threadIdx.x;
    int lim = E < 2048 ? E : 2048;
    int acc = 0;
    for (int k = t; k < lim; k += blockDim.x) acc |= ei32[2 * k + 1];
    if (acc) atomicOr(nz, 1);
}

// ---------------- shared Kabsch core (fp64, Jacobi on M^T M) ----------------
__device__ void kabsch_from_M(const double M[3][3], double Rm[3][3]) {
    Rm[0][0] = 1; Rm[0][1] = 0; Rm[0][2] = 0;
    Rm[1][0] = 0; Rm[1][1] = 1; Rm[1][2] = 0;
    Rm[2][0] = 0; Rm[2][1] = 0; Rm[2][2] = 1;

    double frob2 = 0.0;
#pragma unroll
    for (int r = 0; r < 3; ++r)
#pragma unroll
        for (int c = 0; c < 3; ++c) frob2 += M[r][c] * M[r][c];
    if (frob2 <= 1e-80) return;

    double A[3][3];
#pragma unroll
    for (int r = 0; r < 3; ++r)
#pragma unroll
        for (int c = 0; c < 3; ++c) {
            double s = 0.0;
#pragma unroll
            for (int k = 0; k < 3; ++k) s += M[k][r] * M[k][c];
            A[r][c] = s;
        }
    double V[3][3] = {{1, 0, 0}, {0, 1, 0}, {0, 0, 1}};
    const int PL[3] = {0, 0, 1};
    const int QL[3] = {1, 2, 2};
    for (int sweep = 0; sweep < 15; ++sweep) {
        double off = fabs(A[0][1]) + fabs(A[0][2]) + fabs(A[1][2]);
        if (off == 0.0) break;
        for (int pi = 0; pi < 3; ++pi) {
            int p = PL[pi], q = QL[pi], r3 = 3 - p - q;
            double apq = A[p][q];
            if (apq == 0.0) continue;
            double theta = (A[q][q] - A[p][p]) / (2.0 * apq);
            double t = copysign(1.0, theta) / (fabs(theta) + sqrt(theta * theta + 1.0));
            double c = 1.0 / sqrt(t * t + 1.0);
            double s = t * c;
            A[p][p] -= t * apq;
            A[q][q] += t * apq;
            A[p][q] = 0.0; A[q][p] = 0.0;
            double arp = A[r3][p], arq = A[r3][q];
            A[r3][p] = c * arp - s * arq; A[p][r3] = A[r3][p];
            A[r3][q] = s * arp + c * arq; A[q][r3] = A[r3][q];
#pragma unroll
            for (int k = 0; k < 3; ++k) {
                double vp = V[k][p], vq = V[k][q];
                V[k][p] = c * vp - s * vq;
                V[k][q] = s * vp + c * vq;
            }
        }
    }
    double lam[3] = {A[0][0], A[1][1], A[2][2]};
    int id0 = 0, id1 = 1, id2 = 2, tt;
    if (lam[id0] < lam[id1]) { tt = id0; id0 = id1; id1 = tt; }
    if (lam[id0] < lam[id2]) { tt = id0; id0 = id2; id2 = tt; }
    if (lam[id1] < lam[id2]) { tt = id1; id1 = id2; id2 = tt; }
    double v1[3] = {V[0][id0], V[1][id0], V[2][id0]};
    double v2[3] = {V[0][id1], V[1][id1], V[2][id1]};
    double v3[3] = {V[0][id2], V[1][id2], V[2][id2]};

    double b1[3], b2[3];
#pragma unroll
    for (int r = 0; r < 3; ++r) {
        b1[r] = M[r][0] * v1[0] + M[r][1] * v1[1] + M[r][2] * v1[2];
        b2[r] = M[r][0] * v2[0] + M[r][1] * v2[1] + M[r][2] * v2[2];
    }
    double n1 = sqrt(b1[0] * b1[0] + b1[1] * b1[1] + b1[2] * b1[2]);
    if (n1 <= 1e-150) return;
    double u1[3] = {b1[0] / n1, b1[1] / n1, b1[2] / n1};
    double dot = u1[0] * b2[0] + u1[1] * b2[1] + u1[2] * b2[2];
    double w2[3] = {b2[0] - dot * u1[0], b2[1] - dot * u1[1], b2[2] - dot * u1[2]};
    double n2 = sqrt(w2[0] * w2[0] + w2[1] * w2[1] + w2[2] * w2[2]);
    double u2[3];
    if (n2 > n1 * 1e-12) {
        u2[0] = w2[0] / n2; u2[1] = w2[1] / n2; u2[2] = w2[2] / n2;
    } else {
        double ex0 = (fabs(u1[0]) < 0.9) ? 1.0 : 0.0;
        double ex1 = 1.0 - ex0;
        double cx = u1[1] * 0.0 - u1[2] * ex1;
        double cy = u1[2] * ex0 - u1[0] * 0.0;
        double cz = u1[0] * ex1 - u1[1] * ex0;
        double cn = sqrt(cx * cx + cy * cy + cz * cz);
        u2[0] = cx / cn; u2[1] = cy / cn; u2[2] = cz / cn;
    }
    double u3[3] = {u1[1] * u2[2] - u1[2] * u2[1],
                    u1[2] * u2[0] - u1[0] * u2[2],
                    u1[0] * u2[1] - u1[1] * u2[0]};
    double dV = v1[0] * (v2[1] * v3[2] - v2[2] * v3[1])
              - v1[1] * (v2[0] * v3[2] - v2[2] * v3[0])
              + v1[2] * (v2[0] * v3[1] - v2[1] * v3[0]);
    dV = (dV >= 0.0) ? 1.0 : -1.0;
#pragma unroll
    for (int r = 0; r < 3; ++r)
#pragma unroll
        for (int c = 0; c < 3; ++c)
            Rm[r][c] = u1[r] * v1[c] + u2[r] * v2[c] + dV * u3[r] * v3[c];
}

// ---------------- bucketed counting-sort path ----------------
// bucket = dst >> 7 (128 nodes per bucket). payload: x = (nbr<<7)|(dst&127), y = weight bits.

__global__ void __launch_bounds__(256) k_bhist(const void* __restrict__ ei,
                                               int* __restrict__ btot16,
                                               const int* __restrict__ nz,
                                               int E, int N, int nbuckets) {
    __shared__ int lhist[1024];
    int t = threadIdx.x;
    long long base = (long long)blockIdx.x * 2048;
    long long rem = (long long)E - base;
    int cnt = (rem < 2048) ? (int)rem : 2048;
    int is64 = (*nz == 0);
    for (int i = t; i < 1024; i += 256) lhist[i] = 0;
    __syncthreads();
#pragma unroll
    for (int k = 0; k < 8; ++k) {
        int idx = (k << 8) + t;
        if (idx < cnt) {
            int d = load_idx(ei, base + idx, is64);
            if ((unsigned)d < (unsigned)N) atomicAdd(&lhist[d >> 7], 1);
        }
    }
    __syncthreads();
    for (int b = t; b < 1024; b += 256) {
        int c = lhist[b];
        if (c > 0 && b < nbuckets) atomicAdd(&btot16[b * 16], c);
    }
}

__global__ void k_scan(const int* __restrict__ btot16, int* __restrict__ boff,
                       int* __restrict__ cur16, int nbuckets) {
    __shared__ int sm[1024];
    int t = threadIdx.x;
    int v = (t < nbuckets) ? btot16[t * 16] : 0;
    sm[t] = v;
    __syncthreads();
    for (int s = 1; s < 1024; s <<= 1) {
        int x = (t >= s) ? sm[t - s] : 0;
        __syncthreads();
        sm[t] += x;
        __syncthreads();
    }
    if (t < nbuckets) {
        int excl = sm[t] - v;
        boff[t] = excl;
        cur16[t * 16] = excl;
    }
    if (t == nbuckets - 1) boff[nbuckets] = sm[t];
}

__global__ void __launch_bounds__(256) k_binscatter(const void* __restrict__ ei,
                                                    const float* __restrict__ ew,
                                                    int* __restrict__ cur16,
                                                    int2* __restrict__ sedge,
                                                    const int* __restrict__ nz,
                                                    int E, int N, int nbuckets) {
    __shared__ int2 stage[2048];
    __shared__ unsigned short binOf[2048];
    __shared__ int lhist[1024];
    __shared__ int lincl[1024];
    __shared__ int gbase[1024];
    int t = threadIdx.x;
    long long base = (long long)blockIdx.x * 2048;
    long long rem = (long long)E - base;
    int cnt = (rem < 2048) ? (int)rem : 2048;
    int is64 = (*nz == 0);
    for (int i = t; i < 1024; i += 256) lhist[i] = 0;
    __syncthreads();

    int mybin[8];
    int myrank[8];
    int2 mypay[8];
#pragma unroll
    for (int k = 0; k < 8; ++k) {
        mybin[k] = -1;
        int idx = (k << 8) + t;
        if (idx < cnt) {
            long long e = base + idx;
            int d = load_idx(ei, e, is64);
            int n = load_idx(ei, (long long)E + e, is64);
            if ((unsigned)d < (unsigned)N && (unsigned)n < (unsigned)N) {
                int bb = d >> 7;
                mybin[k] = bb;
                myrank[k] = atomicAdd(&lhist[bb], 1);
                mypay[k].x = (n << 7) | (d & 127);
                mypay[k].y = __float_as_int(ew[e]);
            }
        }
    }
    __syncthreads();
    for (int i = t; i < 1024; i += 256) lincl[i] = lhist[i];
    __syncthreads();
    for (int s = 1; s < 1024; s <<= 1) {
        int tmp[4];
#pragma unroll
        for (int j = 0; j < 4; ++j) {
            int i = (j << 8) + t;
            tmp[j] = (i >= s) ? lincl[i - s] : 0;
        }
        __syncthreads();
#pragma unroll
        for (int j = 0; j < 4; ++j) {
            int i = (j << 8) + t;
            lincl[i] += tmp[j];
        }
        __syncthreads();
    }
#pragma unroll
    for (int k = 0; k < 8; ++k) {
        if (mybin[k] >= 0) {
            int excl = lincl[mybin[k]] - lhist[mybin[k]];
            int lpos = excl + myrank[k];
            stage[lpos] = mypay[k];
            binOf[lpos] = (unsigned short)mybin[k];
        }
    }
    __syncthreads();
    for (int bb = t; bb < 1024; bb += 256) {
        int c = lhist[bb];
        gbase[bb] = (c > 0 && bb < nbuckets) ? atomicAdd(&cur16[bb * 16], c) : 0;
    }
    __syncthreads();
    int total = lincl[1023];
    for (int lpos = t; lpos < total; lpos += 256) {
        int bb = binOf[lpos];
        int excl = lincl[bb] - lhist[bb];
        sedge[gbase[bb] + (lpos - excl)] = stage[lpos];
    }
}

// One block per 128-node bucket: in-LDS counting sort to exact node order,
// then wave-per-node register reductions; fp64 Kabsch tail.
__global__ void __launch_bounds__(256) k_node(const int* __restrict__ boff,
                                              const int2* __restrict__ sedge,
                                              const float* __restrict__ src,
                                              const float* __restrict__ tgt,
                                              float* __restrict__ Rout,
                                              float* __restrict__ Tout, int N) {
    __shared__ int2 sorted[kCap];
    __shared__ int hist[128];
    __shared__ int scanbuf[128];
    __shared__ int offs[128];
    __shared__ int cur[128];
    __shared__ float mm[9][128];
    __shared__ float ctr[6][128];

    int b = blockIdx.x, t = threadIdx.x;
    int e0 = boff[b], e1 = boff[b + 1];
    int cnt = e1 - e0;

    if (t < 128) { hist[t] = 0; }
    __syncthreads();

    if (cnt <= kCap) {
        // phase 1: histogram of low-7 node ids
        for (int i = t; i < cnt; i += 256) {
            int x = ((const int*)sedge)[2 * (long long)(e0 + i)];
            atomicAdd(&hist[x & 127], 1);
        }
        __syncthreads();
        // phase 2: exclusive scan of 128 bins
        if (t < 128) scanbuf[t] = hist[t];
        __syncthreads();
        for (int s = 1; s < 128; s <<= 1) {
            int v = 0;
            if (t < 128 && t >= s) v = scanbuf[t - s];
            __syncthreads();
            if (t < 128) scanbuf[t] += v;
            __syncthreads();
        }
        if (t < 128) {
            int excl = scanbuf[t] - hist[t];
            offs[t] = excl;
            cur[t] = excl;
        }
        __syncthreads();
        // phase 3: scatter into sorted LDS
        for (int i = t; i < cnt; i += 256) {
            int2 p = sedge[e0 + i];
            int r = atomicAdd(&cur[p.x & 127], 1);
            sorted[r] = p;
        }
        __syncthreads();
        // phase 4: wave per node
        int w = t >> 6, lane = t & 63;
        for (int node = w; node < 128; node += 4) {
            int cn = hist[node];
            int base = offs[node];
            float sx = 0, sy = 0, sz = 0, tx = 0, ty = 0, tz = 0;
            for (int j = lane; j < cn; j += 64) {
                int n = ((unsigned)sorted[base + j].x) >> 7;
                sx += src[3 * n + 0]; sy += src[3 * n + 1]; sz += src[3 * n + 2];
                tx += tgt[3 * n + 0]; ty += tgt[3 * n + 1]; tz += tgt[3 * n + 2];
            }
#pragma unroll
            for (int m = 1; m < 64; m <<= 1) {
                sx += __shfl_xor(sx, m, 64); sy += __shfl_xor(sy, m, 64); sz += __shfl_xor(sz, m, 64);
                tx += __shfl_xor(tx, m, 64); ty += __shfl_xor(ty, m, 64); tz += __shfl_xor(tz, m, 64);
            }
            float inv = 1.0f / fmaxf((float)cn, 1.0f);
            float scx = sx * inv, scy = sy * inv, scz = sz * inv;
            float tcx = tx * inv, tcy = ty * inv, tcz = tz * inv;
            float m00 = 0, m01 = 0, m02 = 0, m10 = 0, m11 = 0, m12 = 0, m20 = 0, m21 = 0, m22 = 0;
            for (int j = lane; j < cn; j += 64) {
                int2 p = sorted[base + j];
                int n = ((unsigned)p.x) >> 7;
                float wgt = __int_as_float(p.y);
                float a0 = (src[3 * n + 0] - scx) * wgt;
                float a1 = (src[3 * n + 1] - scy) * wgt;
                float a2 = (src[3 * n + 2] - scz) * wgt;
                float b0 = tgt[3 * n + 0] - tcx;
                float b1 = tgt[3 * n + 1] - tcy;
                float b2 = tgt[3 * n + 2] - tcz;
                m00 += a0 * b0; m01 += a0 * b1; m02 += a0 * b2;
                m10 += a1 * b0; m11 += a1 * b1; m12 += a1 * b2;
                m20 += a2 * b0; m21 += a2 * b1; m22 += a2 * b2;
            }
#pragma unroll
            for (int m = 1; m < 64; m <<= 1) {
                m00 += __shfl_xor(m00, m, 64); m01 += __shfl_xor(m01, m, 64); m02 += __shfl_xor(m02, m, 64);
                m10 += __shfl_xor(m10, m, 64); m11 += __shfl_xor(m11, m, 64); m12 += __shfl_xor(m12, m, 64);
                m20 += __shfl_xor(m20, m, 64); m21 += __shfl_xor(m21, m, 64); m22 += __shfl_xor(m22, m, 64);
            }
            if (lane == 0) {
                ctr[0][node] = scx; ctr[1][node] = scy; ctr[2][node] = scz;
                ctr[3][node] = tcx; ctr[4][node] = tcy; ctr[5][node] = tcz;
                mm[0][node] = m00; mm[1][node] = m01; mm[2][node] = m02;
                mm[3][node] = m10; mm[4][node] = m11; mm[5][node] = m12;
                mm[6][node] = m20; mm[7][node] = m21; mm[8][node] = m22;
            }
        }
    } else {
        // fallback (bucket overflow; should not happen for random graphs):
        // thread t<128 serially scans the bucket for its node.
        if (t < 128) {
            float sx = 0, sy = 0, sz = 0, tx = 0, ty = 0, tz = 0;
            float c = 0;
            for (int j = e0; j < e1; ++j) {
                int2 p = sedge[j];
                if ((p.x & 127) == t) {
                    int n = ((unsigned)p.x) >> 7;
                    sx += src[3 * n + 0]; sy += src[3 * n + 1]; sz += src[3 * n + 2];
                    tx += tgt[3 * n + 0]; ty += tgt[3 * n + 1]; tz += tgt[3 * n + 2];
                    c += 1.0f;
                }
            }
            float inv = 1.0f / fmaxf(c, 1.0f);
            float scx = sx * inv, scy = sy * inv, scz = sz * inv;
            float tcx = tx * inv, tcy = ty * inv, tcz = tz * inv;
            float m00 = 0, m01 = 0, m02 = 0, m10 = 0, m11 = 0, m12 = 0, m20 = 0, m21 = 0, m22 = 0;
            for (int j = e0; j < e1; ++j) {
                int2 p = sedge[j];
                if ((p.x & 127) == t) {
                    int n = ((unsigned)p.x) >> 7;
                    float wgt = __int_as_float(p.y);
                    float a0 = (src[3 * n + 0] - scx) * wgt;
                    float a1 = (src[3 * n + 1] - scy) * wgt;
                    float a2 = (src[3 * n + 2] - scz) * wgt;
                    float b0 = tgt[3 * n + 0] - tcx;
                    float b1 = tgt[3 * n + 1] - tcy;
                    float b2 = tgt[3 * n + 2] - tcz;
                    m00 += a0 * b0; m01 += a0 * b1; m02 += a0 * b2;
                    m10 += a1 * b0; m11 += a1 * b1; m12 += a1 * b2;
                    m20 += a2 * b0; m21 += a2 * b1; m22 += a2 * b2;
                }
            }
            ctr[0][t] = scx; ctr[1][t] = scy; ctr[2][t] = scz;
            ctr[3][t] = tcx; ctr[4][t] = tcy; ctr[5][t] = tcz;
            mm[0][t] = m00; mm[1][t] = m01; mm[2][t] = m02;
            mm[3][t] = m10; mm[4][t] = m11; mm[5][t] = m12;
            mm[6][t] = m20; mm[7][t] = m21; mm[8][t] = m22;
        }
    }
    __syncthreads();
    // Kabsch tail: one thread per node
    if (t < 128) {
        long long i = (long long)b * 128 + t;
        if (i < N) {
            double M[3][3] = {{mm[0][t], mm[1][t], mm[2][t]},
                              {mm[3][t], mm[4][t], mm[5][t]},
                              {mm[6][t], mm[7][t], mm[8][t]}};
            double Rm[3][3];
            kabsch_from_M(M, Rm);
            double scx = ctr[0][t], scy = ctr[1][t], scz = ctr[2][t];
            double tcx = ctr[3][t], tcy = ctr[4][t], tcz = ctr[5][t];
#pragma unroll
            for (int r = 0; r < 3; ++r)
#pragma unroll
                for (int c = 0; c < 3; ++c)
                    Rout[9 * i + 3 * r + c] = (float)Rm[r][c];
            Tout[3 * i + 0] = (float)(tcx - (Rm[0][0] * scx + Rm[0][1] * scy + Rm[0][2] * scz));
            Tout[3 * i + 1] = (float)(tcy - (Rm[1][0] * scx + Rm[1][1] * scy + Rm[1][2] * scz));
            Tout[3 * i + 2] = (float)(tcz - (Rm[2][0] * scx + Rm[2][1] * scy + Rm[2][2] * scz));
        }
    }
}

__global__ void k_weights(const void* __restrict__ ei,
                          const float* __restrict__ src,
                          const float* __restrict__ tgt,
                          const float* __restrict__ R,
                          const float* __restrict__ T,
                          float* __restrict__ wout,
                          const int* __restrict__ nz, int E, int N) {
    int e = blockIdx.x * blockDim.x + threadIdx.x;
    if (e >= E) return;
    int is64 = (*nz == 0);
    int n = load_idx(ei, (long long)E + e, is64);
    float w = 1.0f;
    if ((unsigned)n < (unsigned)N) {
        float p0 = src[3 * n + 0], p1 = src[3 * n + 1], p2 = src[3 * n + 2];
        float q0 = tgt[3 * n + 0], q1 = tgt[3 * n + 1], q2 = tgt[3 * n + 2];
        const float* Rn = R + 9 * (long long)n;
        const float* Tn = T + 3 * (long long)n;
        float x0 = Rn[0] * p0 + Rn[1] * p1 + Rn[2] * p2 + Tn[0];
        float x1 = Rn[3] * p0 + Rn[4] * p1 + Rn[5] * p2 + Tn[1];
        float x2 = Rn[6] * p0 + Rn[7] * p1 + Rn[8] * p2 + Tn[2];
        float d0 = x0 - q0, d1 = x1 - q1, d2 = x2 - q2;
        float dd = d0 * d0 + d1 * d1 + d2 * d2;
        w = kSigma2 / (dd + kSigma2);
    }
    wout[e] = w;
}

// ---------------- fallback atomic path ----------------

__global__ void k_accum1(const void* __restrict__ ei, const float* __restrict__ src,
                         const float* __restrict__ tgt, float* __restrict__ cnt,
                         float* __restrict__ ssum, float* __restrict__ tsum,
                         const int* __restrict__ nz, int E, int N) {
    int e = blockIdx.x * blockDim.x + threadIdx.x;
    if (e >= E) return;
    int is64 = (*nz == 0);
    int d = load_idx(ei, e, is64);
    int n = load_idx(ei, (long long)E + e, is64);
    if ((unsigned)d >= (unsigned)N || (unsigned)n >= (unsigned)N) return;
    atomicAdd(&cnt[d], 1.0f);
    atomicAdd(&ssum[3 * d + 0], src[3 * n + 0]);
    atomicAdd(&ssum[3 * d + 1], src[3 * n + 1]);
    atomicAdd(&ssum[3 * d + 2], src[3 * n + 2]);
    atomicAdd(&tsum[3 * d + 0], tgt[3 * n + 0]);
    atomicAdd(&tsum[3 * d + 1], tgt[3 * n + 1]);
    atomicAdd(&tsum[3 * d + 2], tgt[3 * n + 2]);
}

__global__ void k_centers(float* __restrict__ cnt, float* __restrict__ ssum,
                          float* __restrict__ tsum, int N) {
    int i = blockIdx.x * blockDim.x + threadIdx.x;
    if (i >= N) return;
    float inv = 1.0f / fmaxf(cnt[i], 1.0f);
    ssum[3 * i + 0] *= inv; ssum[3 * i + 1] *= inv; ssum[3 * i + 2] *= inv;
    tsum[3 * i + 0] *= inv; tsum[3 * i + 1] *= inv; tsum[3 * i + 2] *= inv;
}

__global__ void k_accum2(const void* __restrict__ ei, const float* __restrict__ src,
                         const float* __restrict__ tgt, const float* __restrict__ ew,
                         const float* __restrict__ sc, const float* __restrict__ tc,
                         float* __restrict__ Mm, const int* __restrict__ nz, int E, int N) {
    int e = blockIdx.x * blockDim.x + threadIdx.x;
    if (e >= E) return;
    int is64 = (*nz == 0);
    int d = load_idx(ei, e, is64);
    int n = load_idx(ei, (long long)E + e, is64);
    if ((unsigned)d >= (unsigned)N || (unsigned)n >= (unsigned)N) return;
    float w = ew[e];
    float a0 = (src[3 * n + 0] - sc[3 * d + 0]) * w;
    float a1 = (src[3 * n + 1] - sc[3 * d + 1]) * w;
    float a2 = (src[3 * n + 2] - sc[3 * d + 2]) * w;
    float b0 = tgt[3 * n + 0] - tc[3 * d + 0];
    float b1 = tgt[3 * n + 1] - tc[3 * d + 1];
    float b2 = tgt[3 * n + 2] - tc[3 * d + 2];
    float* Md = Mm + 9 * (long long)d;
    atomicAdd(Md + 0, a0 * b0); atomicAdd(Md + 1, a0 * b1); atomicAdd(Md + 2, a0 * b2);
    atomicAdd(Md + 3, a1 * b0); atomicAdd(Md + 4, a1 * b1); atomicAdd(Md + 5, a1 * b2);
    atomicAdd(Md + 6, a2 * b0); atomicAdd(Md + 7, a2 * b1); atomicAdd(Md + 8, a2 * b2);
}

__global__ void k_kabsch(const float* __restrict__ Mm, const float* __restrict__ sc,
                         const float* __restrict__ tc, float* __restrict__ Rout,
                         float* __restrict__ Tout, int N) {
    int i = blockIdx.x * blockDim.x + threadIdx.x;
    if (i >= N) return;
    double M[3][3];
#pragma unroll
    for (int r = 0; r < 3; ++r)
#pragma unroll
        for (int c = 0; c < 3; ++c)
            M[r][c] = (double)Mm[9 * (long long)i + 3 * r + c];
    double Rm[3][3];
    kabsch_from_M(M, Rm);
    double s0 = sc[3 * i + 0], s1 = sc[3 * i + 1], s2 = sc[3 * i + 2];
    double t0 = tc[3 * i + 0], t1 = tc[3 * i + 1], t2 = tc[3 * i + 2];
#pragma unroll
    for (int r = 0; r < 3; ++r)
#pragma unroll
        for (int c = 0; c < 3; ++c)
            Rout[9 * (long long)i + 3 * r + c] = (float)Rm[r][c];
    Tout[3 * i + 0] = (float)(t0 - (Rm[0][0] * s0 + Rm[0][1] * s1 + Rm[0][2] * s2));
    Tout[3 * i + 1] = (float)(t1 - (Rm[1][0] * s0 + Rm[1][1] * s1 + Rm[1][2] * s2));
    Tout[3 * i + 2] = (float)(t2 - (Rm[2][0] * s0 + Rm[2][1] * s1 + Rm[2][2] * s2));
}

extern "C" void kernel_launch(void* const* d_in, const int* in_sizes, int n_in,
                              void* d_out, int out_size, void* d_ws, size_t ws_size,
                              hipStream_t stream) {
    const float* src = (const float*)d_in[0];
    const float* tgt = (const float*)d_in[1];
    const void* ei = d_in[2];
    const float* ew = (const float*)d_in[3];
    int N = in_sizes[0] / 3;
    int E = in_sizes[3];

    float* out = (float*)d_out;
    float* Rout = out;
    float* Tout = out + (size_t)9 * N;
    float* Wout = out + (size_t)12 * N;

    int eb = (E + 255) / 256;
    int nb = (N + 255) / 256;
    int nbuckets = (N + 127) / 128;
    int tiles = (int)(((long long)E + 2047) / 2048);

    // ws layout: [nz(16) | btot16(nbuckets*16) | cur16(nbuckets*16) | boff(nbuckets+1) | pad | sedge(E int2)]
    size_t ctrl_ints = 16 + (size_t)nbuckets * 16 * 2 + (nbuckets + 1);
    ctrl_ints = (ctrl_ints + 1) & ~(size_t)1;
    size_t need = ctrl_ints * sizeof(int) + (size_t)E * sizeof(int2);

    if (N <= 131072 && nbuckets <= 1024 && ws_size >= need) {
        int* nz = (int*)d_ws;
        int* btot16 = nz + 16;
        int* cur16 = btot16 + (size_t)nbuckets * 16;
        int* boff = cur16 + (size_t)nbuckets * 16;
        int2* sedge = (int2*)((int*)d_ws + ctrl_ints);

        hipMemsetAsync(d_ws, 0, ctrl_ints * sizeof(int), stream);

        k_detect<<<1, 256, 0, stream>>>((const int*)ei, E, nz);
        k_bhist<<<tiles, 256, 0, stream>>>(ei, btot16, nz, E, N, nbuckets);
        k_scan<<<1, 1024, 0, stream>>>(btot16, boff, cur16, nbuckets);
        k_binscatter<<<tiles, 256, 0, stream>>>(ei, ew, cur16, sedge, nz, E, N, nbuckets);
        k_node<<<nbuckets, 256, 0, stream>>>(boff, sedge, src, tgt, Rout, Tout, N);
        k_weights<<<eb, 256, 0, stream>>>(ei, src, tgt, Rout, Tout, Wout, nz, E, N);
    } else {
        // fallback: atomic path
        float* cnt = (float*)d_ws;
        float* ssum = cnt + N;
        float* tsum = ssum + 3 * (size_t)N;
        float* Mm = tsum + 3 * (size_t)N;
        int* nz = (int*)(Mm + 9 * (size_t)N);
        size_t ws_bytes = (size_t)16 * N * sizeof(float) + 16;
        hipMemsetAsync(d_ws, 0, ws_bytes, stream);
        k_detect<<<1, 256, 0, stream>>>((const int*)ei, E, nz);
        k_accum1<<<eb, 256, 0, stream>>>(ei, src, tgt, cnt, ssum, tsum, nz, E, N);
        k_centers<<<nb, 256, 0, stream>>>(cnt, ssum, tsum, N);
        k_accum2<<<eb, 256, 0, stream>>>(ei, src, tgt, ew, ssum, tsum, Mm, nz, E, N);
        k_kabsch<<<nb, 256, 0, stream>>>(Mm, ssum, tsum, Rout, Tout, N);
        k_weights<<<eb, 256, 0, stream>>>(ei, src, tgt, Rout, Tout, Wout, nz, E, N);
    }
}

// Round 5
// 449.199 us; speedup vs baseline: 1.5264x; 1.1281x over previous
//
#include <hip/hip_runtime.h>
#include <math.h>

static constexpr float kSigma2 = 0.05f * 0.05f;
static constexpr int kCap = 4864;  // max edges per 128-node bucket in LDS sort

__device__ __forceinline__ int load_idx(const void* ei, long long j, int is64) {
    if (is64) return (int)(((const long long*)ei)[j]);
    return ((const int*)ei)[j];
}

// Detect whether edge_index is int64 (all odd int32 words zero) or int32.
__global__ void k_detect(const int* __restrict__ ei32, int E, int* __restrict__ nz) {
    int t = threadIdx.x;
    int lim = E < 2048 ? E : 2048;
    int acc = 0;
    for (int k = t; k < lim; k += blockDim.x) acc |= ei32[2 * k + 1];
    if (acc) atomicOr(nz, 1);
}

// Pack points into float4 arrays for vector gathers.
__global__ void k_pack(const float* __restrict__ src, const float* __restrict__ tgt,
                       float4* __restrict__ s4, float4* __restrict__ t4, int N) {
    int i = blockIdx.x * blockDim.x + threadIdx.x;
    if (i >= N) return;
    s4[i] = make_float4(src[3 * i + 0], src[3 * i + 1], src[3 * i + 2], 0.0f);
    t4[i] = make_float4(tgt[3 * i + 0], tgt[3 * i + 1], tgt[3 * i + 2], 0.0f);
}

// ---------------- shared Kabsch core (fp64, Jacobi on M^T M) ----------------
__device__ void kabsch_from_M(const double M[3][3], double Rm[3][3]) {
    Rm[0][0] = 1; Rm[0][1] = 0; Rm[0][2] = 0;
    Rm[1][0] = 0; Rm[1][1] = 1; Rm[1][2] = 0;
    Rm[2][0] = 0; Rm[2][1] = 0; Rm[2][2] = 1;

    double frob2 = 0.0;
#pragma unroll
    for (int r = 0; r < 3; ++r)
#pragma unroll
        for (int c = 0; c < 3; ++c) frob2 += M[r][c] * M[r][c];
    if (frob2 <= 1e-80) return;

    double A[3][3];
#pragma unroll
    for (int r = 0; r < 3; ++r)
#pragma unroll
        for (int c = 0; c < 3; ++c) {
            double s = 0.0;
#pragma unroll
            for (int k = 0; k < 3; ++k) s += M[k][r] * M[k][c];
            A[r][c] = s;
        }
    double V[3][3] = {{1, 0, 0}, {0, 1, 0}, {0, 0, 1}};
    const int PL[3] = {0, 0, 1};
    const int QL[3] = {1, 2, 2};
    for (int sweep = 0; sweep < 15; ++sweep) {
        double off = fabs(A[0][1]) + fabs(A[0][2]) + fabs(A[1][2]);
        if (off == 0.0) break;
        for (int pi = 0; pi < 3; ++pi) {
            int p = PL[pi], q = QL[pi], r3 = 3 - p - q;
            double apq = A[p][q];
            if (apq == 0.0) continue;
            double theta = (A[q][q] - A[p][p]) / (2.0 * apq);
            double t = copysign(1.0, theta) / (fabs(theta) + sqrt(theta * theta + 1.0));
            double c = 1.0 / sqrt(t * t + 1.0);
            double s = t * c;
            A[p][p] -= t * apq;
            A[q][q] += t * apq;
            A[p][q] = 0.0; A[q][p] = 0.0;
            double arp = A[r3][p], arq = A[r3][q];
            A[r3][p] = c * arp - s * arq; A[p][r3] = A[r3][p];
            A[r3][q] = s * arp + c * arq; A[q][r3] = A[r3][q];
#pragma unroll
            for (int k = 0; k < 3; ++k) {
                double vp = V[k][p], vq = V[k][q];
                V[k][p] = c * vp - s * vq;
                V[k][q] = s * vp + c * vq;
            }
        }
    }
    double lam[3] = {A[0][0], A[1][1], A[2][2]};
    int id0 = 0, id1 = 1, id2 = 2, tt;
    if (lam[id0] < lam[id1]) { tt = id0; id0 = id1; id1 = tt; }
    if (lam[id0] < lam[id2]) { tt = id0; id0 = id2; id2 = tt; }
    if (lam[id1] < lam[id2]) { tt = id1; id1 = id2; id2 = tt; }
    double v1[3] = {V[0][id0], V[1][id0], V[2][id0]};
    double v2[3] = {V[0][id1], V[1][id1], V[2][id1]};
    double v3[3] = {V[0][id2], V[1][id2], V[2][id2]};

    double b1[3], b2[3];
#pragma unroll
    for (int r = 0; r < 3; ++r) {
        b1[r] = M[r][0] * v1[0] + M[r][1] * v1[1] + M[r][2] * v1[2];
        b2[r] = M[r][0] * v2[0] + M[r][1] * v2[1] + M[r][2] * v2[2];
    }
    double n1 = sqrt(b1[0] * b1[0] + b1[1] * b1[1] + b1[2] * b1[2]);
    if (n1 <= 1e-150) return;
    double u1[3] = {b1[0] / n1, b1[1] / n1, b1[2] / n1};
    double dot = u1[0] * b2[0] + u1[1] * b2[1] + u1[2] * b2[2];
    double w2[3] = {b2[0] - dot * u1[0], b2[1] - dot * u1[1], b2[2] - dot * u1[2]};
    double n2 = sqrt(w2[0] * w2[0] + w2[1] * w2[1] + w2[2] * w2[2]);
    double u2[3];
    if (n2 > n1 * 1e-12) {
        u2[0] = w2[0] / n2; u2[1] = w2[1] / n2; u2[2] = w2[2] / n2;
    } else {
        double ex0 = (fabs(u1[0]) < 0.9) ? 1.0 : 0.0;
        double ex1 = 1.0 - ex0;
        double cx = u1[1] * 0.0 - u1[2] * ex1;
        double cy = u1[2] * ex0 - u1[0] * 0.0;
        double cz = u1[0] * ex1 - u1[1] * ex0;
        double cn = sqrt(cx * cx + cy * cy + cz * cz);
        u2[0] = cx / cn; u2[1] = cy / cn; u2[2] = cz / cn;
    }
    double u3[3] = {u1[1] * u2[2] - u1[2] * u2[1],
                    u1[2] * u2[0] - u1[0] * u2[2],
                    u1[0] * u2[1] - u1[1] * u2[0]};
    double dV = v1[0] * (v2[1] * v3[2] - v2[2] * v3[1])
              - v1[1] * (v2[0] * v3[2] - v2[2] * v3[0])
              + v1[2] * (v2[0] * v3[1] - v2[1] * v3[0]);
    dV = (dV >= 0.0) ? 1.0 : -1.0;
#pragma unroll
    for (int r = 0; r < 3; ++r)
#pragma unroll
        for (int c = 0; c < 3; ++c)
            Rm[r][c] = u1[r] * v1[c] + u2[r] * v2[c] + dV * u3[r] * v3[c];
}

// ---------------- bucketed counting-sort path ----------------
// bucket = dst >> 7 (128 nodes per bucket). payload: x = (nbr<<7)|(dst&127), y = weight bits.

__global__ void __launch_bounds__(256) k_bhist(const void* __restrict__ ei,
                                               int* __restrict__ btot16,
                                               const int* __restrict__ nz,
                                               int E, int N, int nbuckets) {
    __shared__ int lhist[1024];
    int t = threadIdx.x;
    long long base = (long long)blockIdx.x * 2048;
    long long rem = (long long)E - base;
    int cnt = (rem < 2048) ? (int)rem : 2048;
    int is64 = (*nz == 0);
    for (int i = t; i < 1024; i += 256) lhist[i] = 0;
    __syncthreads();
#pragma unroll
    for (int k = 0; k < 8; ++k) {
        int idx = (k << 8) + t;
        if (idx < cnt) {
            int d = load_idx(ei, base + idx, is64);
            if ((unsigned)d < (unsigned)N) atomicAdd(&lhist[d >> 7], 1);
        }
    }
    __syncthreads();
    for (int b = t; b < 1024; b += 256) {
        int c = lhist[b];
        if (c > 0 && b < nbuckets) atomicAdd(&btot16[b * 16], c);
    }
}

__global__ void k_scan(const int* __restrict__ btot16, int* __restrict__ boff,
                       int* __restrict__ cur16, int nbuckets) {
    __shared__ int sm[1024];
    int t = threadIdx.x;
    int v = (t < nbuckets) ? btot16[t * 16] : 0;
    sm[t] = v;
    __syncthreads();
    for (int s = 1; s < 1024; s <<= 1) {
        int x = (t >= s) ? sm[t - s] : 0;
        __syncthreads();
        sm[t] += x;
        __syncthreads();
    }
    if (t < nbuckets) {
        int excl = sm[t] - v;
        boff[t] = excl;
        cur16[t * 16] = excl;
    }
    if (t == nbuckets - 1) boff[nbuckets] = sm[t];
}

__global__ void __launch_bounds__(256) k_binscatter(const void* __restrict__ ei,
                                                    const float* __restrict__ ew,
                                                    int* __restrict__ cur16,
                                                    int2* __restrict__ sedge,
                                                    const int* __restrict__ nz,
                                                    int E, int N, int nbuckets) {
    __shared__ int2 stage[2048];
    __shared__ unsigned short binOf[2048];
    __shared__ int lhist[1024];
    __shared__ int lincl[1024];
    __shared__ int gbase[1024];
    int t = threadIdx.x;
    long long base = (long long)blockIdx.x * 2048;
    long long rem = (long long)E - base;
    int cnt = (rem < 2048) ? (int)rem : 2048;
    int is64 = (*nz == 0);
    for (int i = t; i < 1024; i += 256) lhist[i] = 0;
    __syncthreads();

    int mybin[8];
    int myrank[8];
    int2 mypay[8];
#pragma unroll
    for (int k = 0; k < 8; ++k) {
        mybin[k] = -1;
        int idx = (k << 8) + t;
        if (idx < cnt) {
            long long e = base + idx;
            int d = load_idx(ei, e, is64);
            int n = load_idx(ei, (long long)E + e, is64);
            if ((unsigned)d < (unsigned)N && (unsigned)n < (unsigned)N) {
                int bb = d >> 7;
                mybin[k] = bb;
                myrank[k] = atomicAdd(&lhist[bb], 1);
                mypay[k].x = (n << 7) | (d & 127);
                mypay[k].y = __float_as_int(ew[e]);
            }
        }
    }
    __syncthreads();
    for (int i = t; i < 1024; i += 256) lincl[i] = lhist[i];
    __syncthreads();
    for (int s = 1; s < 1024; s <<= 1) {
        int tmp[4];
#pragma unroll
        for (int j = 0; j < 4; ++j) {
            int i = (j << 8) + t;
            tmp[j] = (i >= s) ? lincl[i - s] : 0;
        }
        __syncthreads();
#pragma unroll
        for (int j = 0; j < 4; ++j) {
            int i = (j << 8) + t;
            lincl[i] += tmp[j];
        }
        __syncthreads();
    }
#pragma unroll
    for (int k = 0; k < 8; ++k) {
        if (mybin[k] >= 0) {
            int excl = lincl[mybin[k]] - lhist[mybin[k]];
            int lpos = excl + myrank[k];
            stage[lpos] = mypay[k];
            binOf[lpos] = (unsigned short)mybin[k];
        }
    }
    __syncthreads();
    for (int bb = t; bb < 1024; bb += 256) {
        int c = lhist[bb];
        gbase[bb] = (c > 0 && bb < nbuckets) ? atomicAdd(&cur16[bb * 16], c) : 0;
    }
    __syncthreads();
    int total = lincl[1023];
    for (int lpos = t; lpos < total; lpos += 256) {
        int bb = binOf[lpos];
        int excl = lincl[bb] - lhist[bb];
        sedge[gbase[bb] + (lpos - excl)] = stage[lpos];
    }
}

// One block per 128-node bucket: LDS counting sort to node order, then
// half-wave-per-node single-pass 23-moment accumulation; fp64 Kabsch tail.
__global__ void __launch_bounds__(256) k_node(const int* __restrict__ boff,
                                              const int2* __restrict__ sedge,
                                              const float* __restrict__ src,
                                              const float* __restrict__ tgt,
                                              const float4* __restrict__ s4,
                                              const float4* __restrict__ t4,
                                              float* __restrict__ Rout,
                                              float* __restrict__ Tout,
                                              float* __restrict__ rt12,
                                              int packed, int N) {
    __shared__ int2 sorted[kCap];
    __shared__ int hist[128];
    __shared__ int scanbuf[128];
    __shared__ int offs[128];
    __shared__ int cur[128];
    __shared__ float acc[23][128];

    int b = blockIdx.x, t = threadIdx.x;
    int e0 = boff[b], e1 = boff[b + 1];
    int cnt = e1 - e0;

    if (t < 128) hist[t] = 0;
    __syncthreads();

    if (cnt <= kCap) {
        // phase 1: histogram of low-7 node ids
        for (int i = t; i < cnt; i += 256) {
            int x = ((const int*)sedge)[2 * (long long)(e0 + i)];
            atomicAdd(&hist[x & 127], 1);
        }
        __syncthreads();
        // phase 2: exclusive scan of 128 bins
        if (t < 128) scanbuf[t] = hist[t];
        __syncthreads();
        for (int s = 1; s < 128; s <<= 1) {
            int v = 0;
            if (t < 128 && t >= s) v = scanbuf[t - s];
            __syncthreads();
            if (t < 128) scanbuf[t] += v;
            __syncthreads();
        }
        if (t < 128) {
            int excl = scanbuf[t] - hist[t];
            offs[t] = excl;
            cur[t] = excl;
        }
        __syncthreads();
        // phase 3: scatter into sorted LDS
        for (int i = t; i < cnt; i += 256) {
            int2 p = sedge[e0 + i];
            int r = atomicAdd(&cur[p.x & 127], 1);
            sorted[r] = p;
        }
        __syncthreads();
        // phase 4: half-wave (32 lanes) per node, single fused pass
        int hw = t >> 5, lane = t & 31;
        for (int node = hw; node < 128; node += 8) {
            int cn = hist[node];
            int base = offs[node];
            float v[23];
#pragma unroll
            for (int i = 0; i < 23; ++i) v[i] = 0.0f;
            for (int j = lane; j < cn; j += 32) {
                int2 p = sorted[base + j];
                int n = ((unsigned)p.x) >> 7;
                float w = __int_as_float(p.y);
                float sx, sy, sz, tx, ty, tz;
                if (packed) {
                    float4 a = s4[n];
                    float4 bb = t4[n];
                    sx = a.x; sy = a.y; sz = a.z;
                    tx = bb.x; ty = bb.y; tz = bb.z;
                } else {
                    sx = src[3 * n + 0]; sy = src[3 * n + 1]; sz = src[3 * n + 2];
                    tx = tgt[3 * n + 0]; ty = tgt[3 * n + 1]; tz = tgt[3 * n + 2];
                }
                v[0] += 1.0f;
                v[1] += sx; v[2] += sy; v[3] += sz;
                v[4] += tx; v[5] += ty; v[6] += tz;
                v[7] += w;
                float wsx = w * sx, wsy = w * sy, wsz = w * sz;
                v[8] += wsx; v[9] += wsy; v[10] += wsz;
                v[11] += w * tx; v[12] += w * ty; v[13] += w * tz;
                v[14] += wsx * tx; v[15] += wsx * ty; v[16] += wsx * tz;
                v[17] += wsy * tx; v[18] += wsy * ty; v[19] += wsy * tz;
                v[20] += wsz * tx; v[21] += wsz * ty; v[22] += wsz * tz;
            }
#pragma unroll
            for (int m = 1; m < 32; m <<= 1) {
#pragma unroll
                for (int i = 0; i < 23; ++i) v[i] += __shfl_xor(v[i], m, 64);
            }
            if (lane == 0) {
#pragma unroll
                for (int i = 0; i < 23; ++i) acc[i][node] = v[i];
            }
        }
    } else {
        // overflow fallback: thread t<128 serially scans the bucket for its node
        if (t < 128) {
            float v[23];
#pragma unroll
            for (int i = 0; i < 23; ++i) v[i] = 0.0f;
            for (int j = e0; j < e1; ++j) {
                int2 p = sedge[j];
                if ((p.x & 127) != t) continue;
                int n = ((unsigned)p.x) >> 7;
                float w = __int_as_float(p.y);
                float sx = src[3 * n + 0], sy = src[3 * n + 1], sz = src[3 * n + 2];
                float tx = tgt[3 * n + 0], ty = tgt[3 * n + 1], tz = tgt[3 * n + 2];
                v[0] += 1.0f;
                v[1] += sx; v[2] += sy; v[3] += sz;
                v[4] += tx; v[5] += ty; v[6] += tz;
                v[7] += w;
                float wsx = w * sx, wsy = w * sy, wsz = w * sz;
                v[8] += wsx; v[9] += wsy; v[10] += wsz;
                v[11] += w * tx; v[12] += w * ty; v[13] += w * tz;
                v[14] += wsx * tx; v[15] += wsx * ty; v[16] += wsx * tz;
                v[17] += wsy * tx; v[18] += wsy * ty; v[19] += wsy * tz;
                v[20] += wsz * tx; v[21] += wsz * ty; v[22] += wsz * tz;
            }
#pragma unroll
            for (int i = 0; i < 23; ++i) acc[i][t] = v[i];
        }
    }
    __syncthreads();
    // Kabsch tail: one thread per node
    if (t < 128) {
        long long i = (long long)b * 128 + t;
        if (i < N) {
            double cntv = (double)acc[0][t];
            double inv = 1.0 / fmax(cntv, 1.0);
            double sb0 = acc[1][t] * inv, sb1 = acc[2][t] * inv, sb2 = acc[3][t] * inv;
            double tb0 = acc[4][t] * inv, tb1 = acc[5][t] * inv, tb2 = acc[6][t] * inv;
            double Sw = acc[7][t];
            double Sws[3] = {acc[8][t], acc[9][t], acc[10][t]};
            double Swt[3] = {acc[11][t], acc[12][t], acc[13][t]};
            double sb[3] = {sb0, sb1, sb2}, tb[3] = {tb0, tb1, tb2};
            double M[3][3];
#pragma unroll
            for (int r = 0; r < 3; ++r)
#pragma unroll
                for (int c = 0; c < 3; ++c)
                    M[r][c] = (double)acc[14 + 3 * r + c][t]
                            - sb[r] * Swt[c] - Sws[r] * tb[c] + Sw * sb[r] * tb[c];
            double Rm[3][3];
            kabsch_from_M(M, Rm);
            double T0 = tb0 - (Rm[0][0] * sb0 + Rm[0][1] * sb1 + Rm[0][2] * sb2);
            double T1 = tb1 - (Rm[1][0] * sb0 + Rm[1][1] * sb1 + Rm[1][2] * sb2);
            double T2 = tb2 - (Rm[2][0] * sb0 + Rm[2][1] * sb1 + Rm[2][2] * sb2);
#pragma unroll
            for (int r = 0; r < 3; ++r)
#pragma unroll
                for (int c = 0; c < 3; ++c)
                    Rout[9 * i + 3 * r + c] = (float)Rm[r][c];
            Tout[3 * i + 0] = (float)T0;
            Tout[3 * i + 1] = (float)T1;
            Tout[3 * i + 2] = (float)T2;
            if (packed) {
                float4* rt4 = (float4*)rt12;
                rt4[3 * i + 0] = make_float4((float)Rm[0][0], (float)Rm[0][1], (float)Rm[0][2], (float)Rm[1][0]);
                rt4[3 * i + 1] = make_float4((float)Rm[1][1], (float)Rm[1][2], (float)Rm[2][0], (float)Rm[2][1]);
                rt4[3 * i + 2] = make_float4((float)Rm[2][2], (float)T0, (float)T1, (float)T2);
            }
        }
    }
}

__global__ void k_weights_packed(const void* __restrict__ ei,
                                 const float4* __restrict__ s4,
                                 const float4* __restrict__ t4,
                                 const float4* __restrict__ rt4,
                                 float* __restrict__ wout,
                                 const int* __restrict__ nz, int E, int N) {
    int e = blockIdx.x * blockDim.x + threadIdx.x;
    if (e >= E) return;
    int is64 = (*nz == 0);
    int n = load_idx(ei, (long long)E + e, is64);
    float w = 1.0f;
    if ((unsigned)n < (unsigned)N) {
        float4 a = s4[n];
        float4 q = t4[n];
        float4 r0 = rt4[3 * (long long)n + 0];
        float4 r1 = rt4[3 * (long long)n + 1];
        float4 r2 = rt4[3 * (long long)n + 2];
        float x0 = r0.x * a.x + r0.y * a.y + r0.z * a.z + r2.y;
        float x1 = r0.w * a.x + r1.x * a.y + r1.y * a.z + r2.z;
        float x2 = r1.z * a.x + r1.w * a.y + r2.x * a.z + r2.w;
        float d0 = x0 - q.x, d1 = x1 - q.y, d2 = x2 - q.z;
        float dd = d0 * d0 + d1 * d1 + d2 * d2;
        w = kSigma2 / (dd + kSigma2);
    }
    wout[e] = w;
}

__global__ void k_weights_plain(const void* __restrict__ ei,
                                const float* __restrict__ src,
                                const float* __restrict__ tgt,
                                const float* __restrict__ R,
                                const float* __restrict__ T,
                                float* __restrict__ wout,
                                const int* __restrict__ nz, int E, int N) {
    int e = blockIdx.x * blockDim.x + threadIdx.x;
    if (e >= E) return;
    int is64 = (*nz == 0);
    int n = load_idx(ei, (long long)E + e, is64);
    float w = 1.0f;
    if ((unsigned)n < (unsigned)N) {
        float p0 = src[3 * n + 0], p1 = src[3 * n + 1], p2 = src[3 * n + 2];
        float q0 = tgt[3 * n + 0], q1 = tgt[3 * n + 1], q2 = tgt[3 * n + 2];
        const float* Rn = R + 9 * (long long)n;
        const float* Tn = T + 3 * (long long)n;
        float x0 = Rn[0] * p0 + Rn[1] * p1 + Rn[2] * p2 + Tn[0];
        float x1 = Rn[3] * p0 + Rn[4] * p1 + Rn[5] * p2 + Tn[1];
        float x2 = Rn[6] * p0 + Rn[7] * p1 + Rn[8] * p2 + Tn[2];
        float d0 = x0 - q0, d1 = x1 - q1, d2 = x2 - q2;
        float dd = d0 * d0 + d1 * d1 + d2 * d2;
        w = kSigma2 / (dd + kSigma2);
    }
    wout[e] = w;
}

// ---------------- fallback atomic path ----------------

__global__ void k_accum1(const void* __restrict__ ei, const float* __restrict__ src,
                         const float* __restrict__ tgt, float* __restrict__ cnt,
                         float* __restrict__ ssum, float* __restrict__ tsum,
                         const int* __restrict__ nz, int E, int N) {
    int e = blockIdx.x * blockDim.x + threadIdx.x;
    if (e >= E) return;
    int is64 = (*nz == 0);
    int d = load_idx(ei, e, is64);
    int n = load_idx(ei, (long long)E + e, is64);
    if ((unsigned)d >= (unsigned)N || (unsigned)n >= (unsigned)N) return;
    atomicAdd(&cnt[d], 1.0f);
    atomicAdd(&ssum[3 * d + 0], src[3 * n + 0]);
    atomicAdd(&ssum[3 * d + 1], src[3 * n + 1]);
    atomicAdd(&ssum[3 * d + 2], src[3 * n + 2]);
    atomicAdd(&tsum[3 * d + 0], tgt[3 * n + 0]);
    atomicAdd(&tsum[3 * d + 1], tgt[3 * n + 1]);
    atomicAdd(&tsum[3 * d + 2], tgt[3 * n + 2]);
}

__global__ void k_centers(float* __restrict__ cnt, float* __restrict__ ssum,
                          float* __restrict__ tsum, int N) {
    int i = blockIdx.x * blockDim.x + threadIdx.x;
    if (i >= N) return;
    float inv = 1.0f / fmaxf(cnt[i], 1.0f);
    ssum[3 * i + 0] *= inv; ssum[3 * i + 1] *= inv; ssum[3 * i + 2] *= inv;
    tsum[3 * i + 0] *= inv; tsum[3 * i + 1] *= inv; tsum[3 * i + 2] *= inv;
}

__global__ void k_accum2(const void* __restrict__ ei, const float* __restrict__ src,
                         const float* __restrict__ tgt, const float* __restrict__ ew,
                         const float* __restrict__ sc, const float* __restrict__ tc,
                         float* __restrict__ Mm, const int* __restrict__ nz, int E, int N) {
    int e = blockIdx.x * blockDim.x + threadIdx.x;
    if (e >= E) return;
    int is64 = (*nz == 0);
    int d = load_idx(ei, e, is64);
    int n = load_idx(ei, (long long)E + e, is64);
    if ((unsigned)d >= (unsigned)N || (unsigned)n >= (unsigned)N) return;
    float w = ew[e];
    float a0 = (src[3 * n + 0] - sc[3 * d + 0]) * w;
    float a1 = (src[3 * n + 1] - sc[3 * d + 1]) * w;
    float a2 = (src[3 * n + 2] - sc[3 * d + 2]) * w;
    float b0 = tgt[3 * n + 0] - tc[3 * d + 0];
    float b1 = tgt[3 * n + 1] - tc[3 * d + 1];
    float b2 = tgt[3 * n + 2] - tc[3 * d + 2];
    float* Md = Mm + 9 * (long long)d;
    atomicAdd(Md + 0, a0 * b0); atomicAdd(Md + 1, a0 * b1); atomicAdd(Md + 2, a0 * b2);
    atomicAdd(Md + 3, a1 * b0); atomicAdd(Md + 4, a1 * b1); atomicAdd(Md + 5, a1 * b2);
    atomicAdd(Md + 6, a2 * b0); atomicAdd(Md + 7, a2 * b1); atomicAdd(Md + 8, a2 * b2);
}

__global__ void k_kabsch(const float* __restrict__ Mm, const float* __restrict__ sc,
                         const float* __restrict__ tc, float* __restrict__ Rout,
                         float* __restrict__ Tout, int N) {
    int i = blockIdx.x * blockDim.x + threadIdx.x;
    if (i >= N) return;
    double M[3][3];
#pragma unroll
    for (int r = 0; r < 3; ++r)
#pragma unroll
        for (int c = 0; c < 3; ++c)
            M[r][c] = (double)Mm[9 * (long long)i + 3 * r + c];
    double Rm[3][3];
    kabsch_from_M(M, Rm);
    double s0 = sc[3 * i + 0], s1 = sc[3 * i + 1], s2 = sc[3 * i + 2];
    double t0 = tc[3 * i + 0], t1 = tc[3 * i + 1], t2 = tc[3 * i + 2];
#pragma unroll
    for (int r = 0; r < 3; ++r)
#pragma unroll
        for (int c = 0; c < 3; ++c)
            Rout[9 * (long long)i + 3 * r + c] = (float)Rm[r][c];
    Tout[3 * i + 0] = (float)(t0 - (Rm[0][0] * s0 + Rm[0][1] * s1 + Rm[0][2] * s2));
    Tout[3 * i + 1] = (float)(t1 - (Rm[1][0] * s0 + Rm[1][1] * s1 + Rm[1][2] * s2));
    Tout[3 * i + 2] = (float)(t2 - (Rm[2][0] * s0 + Rm[2][1] * s1 + Rm[2][2] * s2));
}

extern "C" void kernel_launch(void* const* d_in, const int* in_sizes, int n_in,
                              void* d_out, int out_size, void* d_ws, size_t ws_size,
                              hipStream_t stream) {
    const float* src = (const float*)d_in[0];
    const float* tgt = (const float*)d_in[1];
    const void* ei = d_in[2];
    const float* ew = (const float*)d_in[3];
    int N = in_sizes[0] / 3;
    int E = in_sizes[3];

    float* out = (float*)d_out;
    float* Rout = out;
    float* Tout = out + (size_t)9 * N;
    float* Wout = out + (size_t)12 * N;

    int eb = (E + 255) / 256;
    int nb = (N + 255) / 256;
    int nbuckets = (N + 127) / 128;
    int tiles = (int)(((long long)E + 2047) / 2048);

    // ws layout: [nz(16) | btot16 | cur16 | boff | pad4 | sedge (E int2) | pad4 | s4 | t4 | rt12]
    size_t ctrl_ints = 16 + (size_t)nbuckets * 16 * 2 + (nbuckets + 1);
    ctrl_ints = (ctrl_ints + 3) & ~(size_t)3;
    size_t need_B = ctrl_ints * sizeof(int) + (size_t)E * sizeof(int2);
    size_t pack_off_ints = ctrl_ints + 2 * (size_t)E;
    pack_off_ints = (pack_off_ints + 3) & ~(size_t)3;
    size_t need_A = (pack_off_ints + 8 * (size_t)N + 12 * (size_t)N) * sizeof(int);

    if (N <= 131072 && nbuckets <= 1024 && ws_size >= need_B) {
        int packed = (ws_size >= need_A) ? 1 : 0;
        int* nz = (int*)d_ws;
        int* btot16 = nz + 16;
        int* cur16 = btot16 + (size_t)nbuckets * 16;
        int* boff = cur16 + (size_t)nbuckets * 16;
        int2* sedge = (int2*)((int*)d_ws + ctrl_ints);
        float4* s4 = (float4*)((int*)d_ws + pack_off_ints);
        float4* t4 = s4 + N;
        float* rt12 = (float*)(t4 + N);

        hipMemsetAsync(d_ws, 0, ctrl_ints * sizeof(int), stream);

        k_detect<<<1, 256, 0, stream>>>((const int*)ei, E, nz);
        if (packed) k_pack<<<nb, 256, 0, stream>>>(src, tgt, s4, t4, N);
        k_bhist<<<tiles, 256, 0, stream>>>(ei, btot16, nz, E, N, nbuckets);
        k_scan<<<1, 1024, 0, stream>>>(btot16, boff, cur16, nbuckets);
        k_binscatter<<<tiles, 256, 0, stream>>>(ei, ew, cur16, sedge, nz, E, N, nbuckets);
        k_node<<<nbuckets, 256, 0, stream>>>(boff, sedge, src, tgt, s4, t4,
                                             Rout, Tout, rt12, packed, N);
        if (packed)
            k_weights_packed<<<eb, 256, 0, stream>>>(ei, s4, t4, (const float4*)rt12,
                                                     Wout, nz, E, N);
        else
            k_weights_plain<<<eb, 256, 0, stream>>>(ei, src, tgt, Rout, Tout, Wout, nz, E, N);
    } else {
        // fallback: atomic path
        float* cnt = (float*)d_ws;
        float* ssum = cnt + N;
        float* tsum = ssum + 3 * (size_t)N;
        float* Mm = tsum + 3 * (size_t)N;
        int* nz = (int*)(Mm + 9 * (size_t)N);
        size_t ws_bytes = (size_t)16 * N * sizeof(float) + 16;
        hipMemsetAsync(d_ws, 0, ws_bytes, stream);
        k_detect<<<1, 256, 0, stream>>>((const int*)ei, E, nz);
        k_accum1<<<eb, 256, 0, stream>>>(ei, src, tgt, cnt, ssum, tsum, nz, E, N);
        k_centers<<<nb, 256, 0, stream>>>(cnt, ssum, tsum, N);
        k_accum2<<<eb, 256, 0, stream>>>(ei, src, tgt, ew, ssum, tsum, Mm, nz, E, N);
        k_kabsch<<<nb, 256, 0, stream>>>(Mm, ssum, tsum, Rout, Tout, N);
        k_weights_plain<<<eb, 256, 0, stream>>>(ei, src, tgt, Rout, Tout, Wout, nz, E, N);
    }
}

// Round 6
// 412.323 us; speedup vs baseline: 1.6629x; 1.0894x over previous
//
#include <hip/hip_runtime.h>
#include <math.h>

static constexpr float kSigma2 = 0.05f * 0.05f;
static constexpr int kCap = 6400;  // max edges per 128-node bucket in LDS sort

__device__ __forceinline__ int load_idx(const void* ei, long long j, int is64) {
    if (is64) return (int)(((const long long*)ei)[j]);
    return ((const int*)ei)[j];
}

// Detect whether edge_index is int64 (all odd int32 words zero) or int32.
__global__ void k_detect(const int* __restrict__ ei32, int E, int* __restrict__ nz) {
    int t = threadIdx.x;
    int lim = E < 2048 ? E : 2048;
    int acc = 0;
    for (int k = t; k < lim; k += blockDim.x) acc |= ei32[2 * k + 1];
    if (acc) atomicOr(nz, 1);
}

// Pack points into float4 arrays for vector gathers.
__global__ void k_pack(const float* __restrict__ src, const float* __restrict__ tgt,
                       float4* __restrict__ s4, float4* __restrict__ t4, int N) {
    int i = blockIdx.x * blockDim.x + threadIdx.x;
    if (i >= N) return;
    s4[i] = make_float4(src[3 * i + 0], src[3 * i + 1], src[3 * i + 2], 0.0f);
    t4[i] = make_float4(tgt[3 * i + 0], tgt[3 * i + 1], tgt[3 * i + 2], 0.0f);
}

// ---------------- shared Kabsch core (fp64, Jacobi on M^T M) ----------------
__device__ void kabsch_from_M(const double M[3][3], double Rm[3][3]) {
    Rm[0][0] = 1; Rm[0][1] = 0; Rm[0][2] = 0;
    Rm[1][0] = 0; Rm[1][1] = 1; Rm[1][2] = 0;
    Rm[2][0] = 0; Rm[2][1] = 0; Rm[2][2] = 1;

    double frob2 = 0.0;
#pragma unroll
    for (int r = 0; r < 3; ++r)
#pragma unroll
        for (int c = 0; c < 3; ++c) frob2 += M[r][c] * M[r][c];
    if (frob2 <= 1e-80) return;

    double A[3][3];
#pragma unroll
    for (int r = 0; r < 3; ++r)
#pragma unroll
        for (int c = 0; c < 3; ++c) {
            double s = 0.0;
#pragma unroll
            for (int k = 0; k < 3; ++k) s += M[k][r] * M[k][c];
            A[r][c] = s;
        }
    double V[3][3] = {{1, 0, 0}, {0, 1, 0}, {0, 0, 1}};
    const int PL[3] = {0, 0, 1};
    const int QL[3] = {1, 2, 2};
    for (int sweep = 0; sweep < 15; ++sweep) {
        double off = fabs(A[0][1]) + fabs(A[0][2]) + fabs(A[1][2]);
        if (off == 0.0) break;
        for (int pi = 0; pi < 3; ++pi) {
            int p = PL[pi], q = QL[pi], r3 = 3 - p - q;
            double apq = A[p][q];
            if (apq == 0.0) continue;
            double theta = (A[q][q] - A[p][p]) / (2.0 * apq);
            double t = copysign(1.0, theta) / (fabs(theta) + sqrt(theta * theta + 1.0));
            double c = 1.0 / sqrt(t * t + 1.0);
            double s = t * c;
            A[p][p] -= t * apq;
            A[q][q] += t * apq;
            A[p][q] = 0.0; A[q][p] = 0.0;
            double arp = A[r3][p], arq = A[r3][q];
            A[r3][p] = c * arp - s * arq; A[p][r3] = A[r3][p];
            A[r3][q] = s * arp + c * arq; A[q][r3] = A[r3][q];
#pragma unroll
            for (int k = 0; k < 3; ++k) {
                double vp = V[k][p], vq = V[k][q];
                V[k][p] = c * vp - s * vq;
                V[k][q] = s * vp + c * vq;
            }
        }
    }
    double lam[3] = {A[0][0], A[1][1], A[2][2]};
    int id0 = 0, id1 = 1, id2 = 2, tt;
    if (lam[id0] < lam[id1]) { tt = id0; id0 = id1; id1 = tt; }
    if (lam[id0] < lam[id2]) { tt = id0; id0 = id2; id2 = tt; }
    if (lam[id1] < lam[id2]) { tt = id1; id1 = id2; id2 = tt; }
    double v1[3] = {V[0][id0], V[1][id0], V[2][id0]};
    double v2[3] = {V[0][id1], V[1][id1], V[2][id1]};
    double v3[3] = {V[0][id2], V[1][id2], V[2][id2]};

    double b1[3], b2[3];
#pragma unroll
    for (int r = 0; r < 3; ++r) {
        b1[r] = M[r][0] * v1[0] + M[r][1] * v1[1] + M[r][2] * v1[2];
        b2[r] = M[r][0] * v2[0] + M[r][1] * v2[1] + M[r][2] * v2[2];
    }
    double n1 = sqrt(b1[0] * b1[0] + b1[1] * b1[1] + b1[2] * b1[2]);
    if (n1 <= 1e-150) return;
    double u1[3] = {b1[0] / n1, b1[1] / n1, b1[2] / n1};
    double dot = u1[0] * b2[0] + u1[1] * b2[1] + u1[2] * b2[2];
    double w2[3] = {b2[0] - dot * u1[0], b2[1] - dot * u1[1], b2[2] - dot * u1[2]};
    double n2 = sqrt(w2[0] * w2[0] + w2[1] * w2[1] + w2[2] * w2[2]);
    double u2[3];
    if (n2 > n1 * 1e-12) {
        u2[0] = w2[0] / n2; u2[1] = w2[1] / n2; u2[2] = w2[2] / n2;
    } else {
        double ex0 = (fabs(u1[0]) < 0.9) ? 1.0 : 0.0;
        double ex1 = 1.0 - ex0;
        double cx = u1[1] * 0.0 - u1[2] * ex1;
        double cy = u1[2] * ex0 - u1[0] * 0.0;
        double cz = u1[0] * ex1 - u1[1] * ex0;
        double cn = sqrt(cx * cx + cy * cy + cz * cz);
        u2[0] = cx / cn; u2[1] = cy / cn; u2[2] = cz / cn;
    }
    double u3[3] = {u1[1] * u2[2] - u1[2] * u2[1],
                    u1[2] * u2[0] - u1[0] * u2[2],
                    u1[0] * u2[1] - u1[1] * u2[0]};
    double dV = v1[0] * (v2[1] * v3[2] - v2[2] * v3[1])
              - v1[1] * (v2[0] * v3[2] - v2[2] * v3[0])
              + v1[2] * (v2[0] * v3[1] - v2[1] * v3[0]);
    dV = (dV >= 0.0) ? 1.0 : -1.0;
#pragma unroll
    for (int r = 0; r < 3; ++r)
#pragma unroll
        for (int c = 0; c < 3; ++c)
            Rm[r][c] = u1[r] * v1[c] + u2[r] * v2[c] + dV * u3[r] * v3[c];
}

// ---------------- bucketed counting-sort path ----------------
// bucket = dst >> 7 (128 nodes per bucket). payload: x = (nbr<<7)|(dst&127), y = weight bits.

__global__ void __launch_bounds__(256) k_bhist(const void* __restrict__ ei,
                                               int* __restrict__ btot16,
                                               const int* __restrict__ nz,
                                               int E, int N, int nbuckets) {
    __shared__ int lhist[1024];
    int t = threadIdx.x;
    long long tile = (long long)blockIdx.x * 2048;
    long long remll = (long long)E - tile;
    int rem = (remll < 2048) ? (int)remll : 2048;
    int is64 = (*nz == 0);
    for (int i = t; i < 1024; i += 256) lhist[i] = 0;
    __syncthreads();
    int d[8];
    int cnt8 = 0;
    if (rem == 2048) {
        if (is64) {
            const long long* p = (const long long*)ei + tile + (long long)t * 8;
#pragma unroll
            for (int k = 0; k < 4; ++k) {
                longlong2 v = ((const longlong2*)p)[k];
                d[2 * k] = (int)v.x;
                d[2 * k + 1] = (int)v.y;
            }
        } else {
            const int* p = (const int*)ei + tile + (long long)t * 8;
            int4 a = ((const int4*)p)[0];
            int4 bb = ((const int4*)p)[1];
            d[0] = a.x; d[1] = a.y; d[2] = a.z; d[3] = a.w;
            d[4] = bb.x; d[5] = bb.y; d[6] = bb.z; d[7] = bb.w;
        }
        cnt8 = 8;
    } else {
        int base = t * 8;
#pragma unroll
        for (int k = 0; k < 8; ++k) {
            int idx = base + k;
            if (idx < rem) d[cnt8++] = load_idx(ei, tile + idx, is64);
        }
    }
    for (int k = 0; k < cnt8; ++k)
        if ((unsigned)d[k] < (unsigned)N) atomicAdd(&lhist[d[k] >> 7], 1);
    __syncthreads();
    for (int b = t; b < 1024; b += 256) {
        int c = lhist[b];
        if (c > 0 && b < nbuckets) atomicAdd(&btot16[b * 16], c);
    }
}

__global__ void k_scan(const int* __restrict__ btot16, int* __restrict__ boff,
                       int* __restrict__ cur16, int nbuckets) {
    __shared__ int sm[1024];
    int t = threadIdx.x;
    int v = (t < nbuckets) ? btot16[t * 16] : 0;
    sm[t] = v;
    __syncthreads();
    for (int s = 1; s < 1024; s <<= 1) {
        int x = (t >= s) ? sm[t - s] : 0;
        __syncthreads();
        sm[t] += x;
        __syncthreads();
    }
    if (t < nbuckets) {
        int excl = sm[t] - v;
        boff[t] = excl;
        cur16[t * 16] = excl;
    }
    if (t == nbuckets - 1) boff[nbuckets] = sm[t];
}

__global__ void __launch_bounds__(256) k_binscatter(const void* __restrict__ ei,
                                                    const float* __restrict__ ew,
                                                    int* __restrict__ cur16,
                                                    int2* __restrict__ sedge,
                                                    const int* __restrict__ nz,
                                                    int E, int N, int nbuckets) {
    __shared__ int2 stage[2048];
    __shared__ unsigned short binOf[2048];
    __shared__ int lhist[1024];
    __shared__ int lincl[1024];
    __shared__ int gbase[1024];
    int t = threadIdx.x;
    long long tile = (long long)blockIdx.x * 2048;
    long long remll = (long long)E - tile;
    int rem = (remll < 2048) ? (int)remll : 2048;
    int is64 = (*nz == 0);
    for (int i = t; i < 1024; i += 256) lhist[i] = 0;
    __syncthreads();

    int dd[8], nn[8];
    float ww[8];
    int cnt8 = 0;
    if (rem == 2048) {
        if (is64) {
            const long long* pd = (const long long*)ei + tile + (long long)t * 8;
            const long long* pn = (const long long*)ei + (long long)E + tile + (long long)t * 8;
#pragma unroll
            for (int k = 0; k < 4; ++k) {
                longlong2 vd = ((const longlong2*)pd)[k];
                longlong2 vn = ((const longlong2*)pn)[k];
                dd[2 * k] = (int)vd.x; dd[2 * k + 1] = (int)vd.y;
                nn[2 * k] = (int)vn.x; nn[2 * k + 1] = (int)vn.y;
            }
        } else {
            const int* pd = (const int*)ei + tile + (long long)t * 8;
            const int* pn = (const int*)ei + (long long)E + tile + (long long)t * 8;
            int4 a = ((const int4*)pd)[0], b = ((const int4*)pd)[1];
            int4 c = ((const int4*)pn)[0], d = ((const int4*)pn)[1];
            dd[0] = a.x; dd[1] = a.y; dd[2] = a.z; dd[3] = a.w;
            dd[4] = b.x; dd[5] = b.y; dd[6] = b.z; dd[7] = b.w;
            nn[0] = c.x; nn[1] = c.y; nn[2] = c.z; nn[3] = c.w;
            nn[4] = d.x; nn[5] = d.y; nn[6] = d.z; nn[7] = d.w;
        }
        const float* pw = ew + tile + (long long)t * 8;
        float4 wa = ((const float4*)pw)[0], wb = ((const float4*)pw)[1];
        ww[0] = wa.x; ww[1] = wa.y; ww[2] = wa.z; ww[3] = wa.w;
        ww[4] = wb.x; ww[5] = wb.y; ww[6] = wb.z; ww[7] = wb.w;
        cnt8 = 8;
    } else {
        int base = t * 8;
#pragma unroll
        for (int k = 0; k < 8; ++k) {
            int idx = base + k;
            if (idx < rem) {
                long long e = tile + idx;
                dd[cnt8] = load_idx(ei, e, is64);
                nn[cnt8] = load_idx(ei, (long long)E + e, is64);
                ww[cnt8] = ew[e];
                ++cnt8;
            }
        }
    }

    int mybin[8];
    int myrank[8];
    int2 mypay[8];
#pragma unroll
    for (int k = 0; k < 8; ++k) {
        mybin[k] = -1;
        if (k < cnt8) {
            int d = dd[k], n = nn[k];
            if ((unsigned)d < (unsigned)N && (unsigned)n < (unsigned)N) {
                int bb = d >> 7;
                mybin[k] = bb;
                myrank[k] = atomicAdd(&lhist[bb], 1);
                mypay[k].x = (n << 7) | (d & 127);
                mypay[k].y = __float_as_int(ww[k]);
            }
        }
    }
    __syncthreads();
    for (int i = t; i < 1024; i += 256) lincl[i] = lhist[i];
    __syncthreads();
    for (int s = 1; s < 1024; s <<= 1) {
        int tmp[4];
#pragma unroll
        for (int j = 0; j < 4; ++j) {
            int i = (j << 8) + t;
            tmp[j] = (i >= s) ? lincl[i - s] : 0;
        }
        __syncthreads();
#pragma unroll
        for (int j = 0; j < 4; ++j) {
            int i = (j << 8) + t;
            lincl[i] += tmp[j];
        }
        __syncthreads();
    }
#pragma unroll
    for (int k = 0; k < 8; ++k) {
        if (mybin[k] >= 0) {
            int excl = lincl[mybin[k]] - lhist[mybin[k]];
            int lpos = excl + myrank[k];
            stage[lpos] = mypay[k];
            binOf[lpos] = (unsigned short)mybin[k];
        }
    }
    __syncthreads();
    for (int bb = t; bb < 1024; bb += 256) {
        int c = lhist[bb];
        gbase[bb] = (c > 0 && bb < nbuckets) ? atomicAdd(&cur16[bb * 16], c) : 0;
    }
    __syncthreads();
    int total = lincl[1023];
    for (int lpos = t; lpos < total; lpos += 256) {
        int bb = binOf[lpos];
        int excl = lincl[bb] - lhist[bb];
        sedge[gbase[bb] + (lpos - excl)] = stage[lpos];
    }
}

// Per-bucket in-LDS counting sort to exact node order; writes node-sorted
// edges back IN PLACE and emits per-node (start,count) segments.
__global__ void __launch_bounds__(256) k_sort(const int* __restrict__ boff,
                                              int2* __restrict__ sedge,
                                              int2* __restrict__ nseg) {
    __shared__ int2 sorted[kCap];
    __shared__ int hist[128];
    __shared__ int scanbuf[128];
    __shared__ int offs[128];
    __shared__ int cur[128];
    int b = blockIdx.x, t = threadIdx.x;
    int e0 = boff[b], e1 = boff[b + 1];
    int cnt = e1 - e0;
    if (t < 128) hist[t] = 0;
    __syncthreads();
    if (cnt <= kCap) {
        for (int i = t; i < cnt; i += 256)
            atomicAdd(&hist[sedge[e0 + i].x & 127], 1);
        __syncthreads();
        if (t < 128) scanbuf[t] = hist[t];
        __syncthreads();
        for (int s = 1; s < 128; s <<= 1) {
            int v = 0;
            if (t < 128 && t >= s) v = scanbuf[t - s];
            __syncthreads();
            if (t < 128) scanbuf[t] += v;
            __syncthreads();
        }
        if (t < 128) {
            int excl = scanbuf[t] - hist[t];
            offs[t] = excl;
            cur[t] = excl;
        }
        __syncthreads();
        for (int i = t; i < cnt; i += 256) {
            int2 p = sedge[e0 + i];
            int r = atomicAdd(&cur[p.x & 127], 1);
            sorted[r] = p;
        }
        __syncthreads();
        for (int i = t; i < cnt; i += 256) sedge[e0 + i] = sorted[i];
        if (t < 128) nseg[b * 128 + t] = make_int2(e0 + offs[t], hist[t]);
    } else {
        // overflow: leave bucket unsorted; negative count => filter-scan mode
        if (t < 128) nseg[b * 128 + t] = make_int2(e0, -cnt);
    }
}

// 8 lanes per node; single fused 23-moment pass over the node's contiguous
// segment; 3-level butterfly; fp64 Kabsch tail.
__global__ void __launch_bounds__(256) k_moment(const int2* __restrict__ nseg,
                                                const int2* __restrict__ sedge,
                                                const float4* __restrict__ s4,
                                                const float4* __restrict__ t4,
                                                float* __restrict__ Rout,
                                                float* __restrict__ Tout,
                                                float* __restrict__ rt12, int N) {
    __shared__ float acc[23][128];
    int b = blockIdx.x, t = threadIdx.x;
    int oct = t >> 3, lane8 = t & 7;
    for (int node = oct; node < 128; node += 32) {
        int2 seg = nseg[b * 128 + node];
        float v[23];
#pragma unroll
        for (int i = 0; i < 23; ++i) v[i] = 0.0f;
        int start = seg.x;
        int cn = seg.y;
        int total = (cn >= 0) ? cn : -cn;
        int filter = (cn < 0);
        for (int j = lane8; j < total; j += 8) {
            int2 p = sedge[start + j];
            if (filter && (p.x & 127) != node) continue;
            int n = ((unsigned)p.x) >> 7;
            float w = __int_as_float(p.y);
            float4 a = s4[n];
            float4 bb = t4[n];
            float sx = a.x, sy = a.y, sz = a.z;
            float tx = bb.x, ty = bb.y, tz = bb.z;
            v[0] += 1.0f;
            v[1] += sx; v[2] += sy; v[3] += sz;
            v[4] += tx; v[5] += ty; v[6] += tz;
            v[7] += w;
            float wsx = w * sx, wsy = w * sy, wsz = w * sz;
            v[8] += wsx; v[9] += wsy; v[10] += wsz;
            v[11] += w * tx; v[12] += w * ty; v[13] += w * tz;
            v[14] += wsx * tx; v[15] += wsx * ty; v[16] += wsx * tz;
            v[17] += wsy * tx; v[18] += wsy * ty; v[19] += wsy * tz;
            v[20] += wsz * tx; v[21] += wsz * ty; v[22] += wsz * tz;
        }
#pragma unroll
        for (int m = 1; m < 8; m <<= 1) {
#pragma unroll
            for (int i = 0; i < 23; ++i) v[i] += __shfl_xor(v[i], m, 64);
        }
        if (lane8 == 0) {
#pragma unroll
            for (int i = 0; i < 23; ++i) acc[i][node] = v[i];
        }
    }
    __syncthreads();
    if (t < 128) {
        long long i = (long long)b * 128 + t;
        if (i < N) {
            double cntv = (double)acc[0][t];
            double inv = 1.0 / fmax(cntv, 1.0);
            double sb0 = acc[1][t] * inv, sb1 = acc[2][t] * inv, sb2 = acc[3][t] * inv;
            double tb0 = acc[4][t] * inv, tb1 = acc[5][t] * inv, tb2 = acc[6][t] * inv;
            double Sw = acc[7][t];
            double Sws[3] = {acc[8][t], acc[9][t], acc[10][t]};
            double Swt[3] = {acc[11][t], acc[12][t], acc[13][t]};
            double sb[3] = {sb0, sb1, sb2}, tb[3] = {tb0, tb1, tb2};
            double M[3][3];
#pragma unroll
            for (int r = 0; r < 3; ++r)
#pragma unroll
                for (int c = 0; c < 3; ++c)
                    M[r][c] = (double)acc[14 + 3 * r + c][t]
                            - sb[r] * Swt[c] - Sws[r] * tb[c] + Sw * sb[r] * tb[c];
            double Rm[3][3];
            kabsch_from_M(M, Rm);
            double T0 = tb0 - (Rm[0][0] * sb0 + Rm[0][1] * sb1 + Rm[0][2] * sb2);
            double T1 = tb1 - (Rm[1][0] * sb0 + Rm[1][1] * sb1 + Rm[1][2] * sb2);
            double T2 = tb2 - (Rm[2][0] * sb0 + Rm[2][1] * sb1 + Rm[2][2] * sb2);
#pragma unroll
            for (int r = 0; r < 3; ++r)
#pragma unroll
                for (int c = 0; c < 3; ++c)
                    Rout[9 * i + 3 * r + c] = (float)Rm[r][c];
            Tout[3 * i + 0] = (float)T0;
            Tout[3 * i + 1] = (float)T1;
            Tout[3 * i + 2] = (float)T2;
            float4* rt4 = (float4*)rt12;
            rt4[3 * i + 0] = make_float4((float)Rm[0][0], (float)Rm[0][1], (float)Rm[0][2], (float)Rm[1][0]);
            rt4[3 * i + 1] = make_float4((float)Rm[1][1], (float)Rm[1][2], (float)Rm[2][0], (float)Rm[2][1]);
            rt4[3 * i + 2] = make_float4((float)Rm[2][2], (float)T0, (float)T1, (float)T2);
        }
    }
}

// 4 edges per thread, vector index loads, float4 output.
__global__ void __launch_bounds__(256) k_weights4(const void* __restrict__ ei,
                                                  const float4* __restrict__ s4,
                                                  const float4* __restrict__ t4,
                                                  const float4* __restrict__ rt4,
                                                  float* __restrict__ wout,
                                                  const int* __restrict__ nz,
                                                  int E, int N) {
    int gid = blockIdx.x * blockDim.x + threadIdx.x;
    long long base = (long long)gid * 4;
    if (base >= E) return;
    int is64 = (*nz == 0);
    int n_[4];
    int full = (base + 4 <= (long long)E);
    if (full) {
        if (is64) {
            const long long* p = (const long long*)ei + (long long)E + base;
            longlong2 a = ((const longlong2*)p)[0];
            longlong2 b = ((const longlong2*)p)[1];
            n_[0] = (int)a.x; n_[1] = (int)a.y; n_[2] = (int)b.x; n_[3] = (int)b.y;
        } else {
            int4 a = *(const int4*)((const int*)ei + (long long)E + base);
            n_[0] = a.x; n_[1] = a.y; n_[2] = a.z; n_[3] = a.w;
        }
    } else {
#pragma unroll
        for (int k = 0; k < 4; ++k) {
            long long e = base + k;
            n_[k] = (e < E) ? load_idx(ei, (long long)E + e, is64) : 0;
        }
    }
    float w[4];
#pragma unroll
    for (int k = 0; k < 4; ++k) {
        int n = n_[k];
        float wv = 1.0f;
        if ((unsigned)n < (unsigned)N) {
            float4 a = s4[n];
            float4 q = t4[n];
            float4 r0 = rt4[3 * (long long)n + 0];
            float4 r1 = rt4[3 * (long long)n + 1];
            float4 r2 = rt4[3 * (long long)n + 2];
            float x0 = r0.x * a.x + r0.y * a.y + r0.z * a.z + r2.y;
            float x1 = r0.w * a.x + r1.x * a.y + r1.y * a.z + r2.z;
            float x2 = r1.z * a.x + r1.w * a.y + r2.x * a.z + r2.w;
            float d0 = x0 - q.x, d1 = x1 - q.y, d2 = x2 - q.z;
            float dd = d0 * d0 + d1 * d1 + d2 * d2;
            wv = kSigma2 / (dd + kSigma2);
        }
        w[k] = wv;
    }
    if (full) {
        *(float4*)(wout + base) = make_float4(w[0], w[1], w[2], w[3]);
    } else {
#pragma unroll
        for (int k = 0; k < 4; ++k)
            if (base + k < E) wout[base + k] = w[k];
    }
}

// ---------------- fallback atomic path ----------------

__global__ void k_accum1(const void* __restrict__ ei, const float* __restrict__ src,
                         const float* __restrict__ tgt, float* __restrict__ cnt,
                         float* __restrict__ ssum, float* __restrict__ tsum,
                         const int* __restrict__ nz, int E, int N) {
    int e = blockIdx.x * blockDim.x + threadIdx.x;
    if (e >= E) return;
    int is64 = (*nz == 0);
    int d = load_idx(ei, e, is64);
    int n = load_idx(ei, (long long)E + e, is64);
    if ((unsigned)d >= (unsigned)N || (unsigned)n >= (unsigned)N) return;
    atomicAdd(&cnt[d], 1.0f);
    atomicAdd(&ssum[3 * d + 0], src[3 * n + 0]);
    atomicAdd(&ssum[3 * d + 1], src[3 * n + 1]);
    atomicAdd(&ssum[3 * d + 2], src[3 * n + 2]);
    atomicAdd(&tsum[3 * d + 0], tgt[3 * n + 0]);
    atomicAdd(&tsum[3 * d + 1], tgt[3 * n + 1]);
    atomicAdd(&tsum[3 * d + 2], tgt[3 * n + 2]);
}

__global__ void k_centers(float* __restrict__ cnt, float* __restrict__ ssum,
                          float* __restrict__ tsum, int N) {
    int i = blockIdx.x * blockDim.x + threadIdx.x;
    if (i >= N) return;
    float inv = 1.0f / fmaxf(cnt[i], 1.0f);
    ssum[3 * i + 0] *= inv; ssum[3 * i + 1] *= inv; ssum[3 * i + 2] *= inv;
    tsum[3 * i + 0] *= inv; tsum[3 * i + 1] *= inv; tsum[3 * i + 2] *= inv;
}

__global__ void k_accum2(const void* __restrict__ ei, const float* __restrict__ src,
                         const float* __restrict__ tgt, const float* __restrict__ ew,
                         const float* __restrict__ sc, const float* __restrict__ tc,
                         float* __restrict__ Mm, const int* __restrict__ nz, int E, int N) {
    int e = blockIdx.x * blockDim.x + threadIdx.x;
    if (e >= E) return;
    int is64 = (*nz == 0);
    int d = load_idx(ei, e, is64);
    int n = load_idx(ei, (long long)E + e, is64);
    if ((unsigned)d >= (unsigned)N || (unsigned)n >= (unsigned)N) return;
    float w = ew[e];
    float a0 = (src[3 * n + 0] - sc[3 * d + 0]) * w;
    float a1 = (src[3 * n + 1] - sc[3 * d + 1]) * w;
    float a2 = (src[3 * n + 2] - sc[3 * d + 2]) * w;
    float b0 = tgt[3 * n + 0] - tc[3 * d + 0];
    float b1 = tgt[3 * n + 1] - tc[3 * d + 1];
    float b2 = tgt[3 * n + 2] - tc[3 * d + 2];
    float* Md = Mm + 9 * (long long)d;
    atomicAdd(Md + 0, a0 * b0); atomicAdd(Md + 1, a0 * b1); atomicAdd(Md + 2, a0 * b2);
    atomicAdd(Md + 3, a1 * b0); atomicAdd(Md + 4, a1 * b1); atomicAdd(Md + 5, a1 * b2);
    atomicAdd(Md + 6, a2 * b0); atomicAdd(Md + 7, a2 * b1); atomicAdd(Md + 8, a2 * b2);
}

__global__ void k_kabsch(const float* __restrict__ Mm, const float* __restrict__ sc,
                         const float* __restrict__ tc, float* __restrict__ Rout,
                         float* __restrict__ Tout, int N) {
    int i = blockIdx.x * blockDim.x + threadIdx.x;
    if (i >= N) return;
    double M[3][3];
#pragma unroll
    for (int r = 0; r < 3; ++r)
#pragma unroll
        for (int c = 0; c < 3; ++c)
            M[r][c] = (double)Mm[9 * (long long)i + 3 * r + c];
    double Rm[3][3];
    kabsch_from_M(M, Rm);
    double s0 = sc[3 * i + 0], s1 = sc[3 * i + 1], s2 = sc[3 * i + 2];
    double t0 = tc[3 * i + 0], t1 = tc[3 * i + 1], t2 = tc[3 * i + 2];
#pragma unroll
    for (int r = 0; r < 3; ++r)
#pragma unroll
        for (int c = 0; c < 3; ++c)
            Rout[9 * (long long)i + 3 * r + c] = (float)Rm[r][c];
    Tout[3 * i + 0] = (float)(t0 - (Rm[0][0] * s0 + Rm[0][1] * s1 + Rm[0][2] * s2));
    Tout[3 * i + 1] = (float)(t1 - (Rm[1][0] * s0 + Rm[1][1] * s1 + Rm[1][2] * s2));
    Tout[3 * i + 2] = (float)(t2 - (Rm[2][0] * s0 + Rm[2][1] * s1 + Rm[2][2] * s2));
}

__global__ void k_weights_plain(const void* __restrict__ ei,
                                const float* __restrict__ src,
                                const float* __restrict__ tgt,
                                const float* __restrict__ R,
                                const float* __restrict__ T,
                                float* __restrict__ wout,
                                const int* __restrict__ nz, int E, int N) {
    int e = blockIdx.x * blockDim.x + threadIdx.x;
    if (e >= E) return;
    int is64 = (*nz == 0);
    int n = load_idx(ei, (long long)E + e, is64);
    float w = 1.0f;
    if ((unsigned)n < (unsigned)N) {
        float p0 = src[3 * n + 0], p1 = src[3 * n + 1], p2 = src[3 * n + 2];
        float q0 = tgt[3 * n + 0], q1 = tgt[3 * n + 1], q2 = tgt[3 * n + 2];
        const float* Rn = R + 9 * (long long)n;
        const float* Tn = T + 3 * (long long)n;
        float x0 = Rn[0] * p0 + Rn[1] * p1 + Rn[2] * p2 + Tn[0];
        float x1 = Rn[3] * p0 + Rn[4] * p1 + Rn[5] * p2 + Tn[1];
        float x2 = Rn[6] * p0 + Rn[7] * p1 + Rn[8] * p2 + Tn[2];
        float d0 = x0 - q0, d1 = x1 - q1, d2 = x2 - q2;
        float dd = d0 * d0 + d1 * d1 + d2 * d2;
        w = kSigma2 / (dd + kSigma2);
    }
    wout[e] = w;
}

extern "C" void kernel_launch(void* const* d_in, const int* in_sizes, int n_in,
                              void* d_out, int out_size, void* d_ws, size_t ws_size,
                              hipStream_t stream) {
    const float* src = (const float*)d_in[0];
    const float* tgt = (const float*)d_in[1];
    const void* ei = d_in[2];
    const float* ew = (const float*)d_in[3];
    int N = in_sizes[0] / 3;
    int E = in_sizes[3];

    float* out = (float*)d_out;
    float* Rout = out;
    float* Tout = out + (size_t)9 * N;
    float* Wout = out + (size_t)12 * N;

    int eb = (E + 255) / 256;
    int nb = (N + 255) / 256;
    int nbuckets = (N + 127) / 128;
    int tiles = (int)(((long long)E + 2047) / 2048);
    int wb4 = (int)(((long long)E + 1023) / 1024);

    // ws layout: [nz(16) | btot16 | cur16 | boff | pad4 | sedge (E int2) | pad4 |
    //             s4 (4N f) | t4 (4N f) | rt12 (12N f) | nseg (128*nbuckets int2)]
    size_t ctrl_ints = 16 + (size_t)nbuckets * 16 * 2 + (nbuckets + 1);
    ctrl_ints = (ctrl_ints + 3) & ~(size_t)3;
    size_t pack_off_ints = ctrl_ints + 2 * (size_t)E;
    pack_off_ints = (pack_off_ints + 3) & ~(size_t)3;
    size_t need = (pack_off_ints + 8 * (size_t)N + 12 * (size_t)N
                   + 2 * (size_t)128 * nbuckets) * sizeof(int);

    if (N <= 131072 && nbuckets <= 1024 && ws_size >= need) {
        int* nz = (int*)d_ws;
        int* btot16 = nz + 16;
        int* cur16 = btot16 + (size_t)nbuckets * 16;
        int* boff = cur16 + (size_t)nbuckets * 16;
        int2* sedge = (int2*)((int*)d_ws + ctrl_ints);
        float4* s4 = (float4*)((int*)d_ws + pack_off_ints);
        float4* t4 = s4 + N;
        float* rt12 = (float*)(t4 + N);
        int2* nseg = (int2*)(rt12 + 12 * (size_t)N);

        hipMemsetAsync(d_ws, 0, ctrl_ints * sizeof(int), stream);

        k_detect<<<1, 256, 0, stream>>>((const int*)ei, E, nz);
        k_pack<<<nb, 256, 0, stream>>>(src, tgt, s4, t4, N);
        k_bhist<<<tiles, 256, 0, stream>>>(ei, btot16, nz, E, N, nbuckets);
        k_scan<<<1, 1024, 0, stream>>>(btot16, boff, cur16, nbuckets);
        k_binscatter<<<tiles, 256, 0, stream>>>(ei, ew, cur16, sedge, nz, E, N, nbuckets);
        k_sort<<<nbuckets, 256, 0, stream>>>(boff, sedge, nseg);
        k_moment<<<nbuckets, 256, 0, stream>>>(nseg, sedge, s4, t4, Rout, Tout, rt12, N);
        k_weights4<<<wb4, 256, 0, stream>>>(ei, s4, t4, (const float4*)rt12, Wout, nz, E, N);
    } else {
        // fallback: atomic path
        float* cnt = (float*)d_ws;
        float* ssum = cnt + N;
        float* tsum = ssum + 3 * (size_t)N;
        float* Mm = tsum + 3 * (size_t)N;
        int* nz = (int*)(Mm + 9 * (size_t)N);
        size_t ws_bytes = (size_t)16 * N * sizeof(float) + 16;
        hipMemsetAsync(d_ws, 0, ws_bytes, stream);
        k_detect<<<1, 256, 0, stream>>>((const int*)ei, E, nz);
        k_accum1<<<eb, 256, 0, stream>>>(ei, src, tgt, cnt, ssum, tsum, nz, E, N);
        k_centers<<<nb, 256, 0, stream>>>(cnt, ssum, tsum, N);
        k_accum2<<<eb, 256, 0, stream>>>(ei, src, tgt, ew, ssum, tsum, Mm, nz, E, N);
        k_kabsch<<<nb, 256, 0, stream>>>(Mm, ssum, tsum, Rout, Tout, N);
        k_weights_plain<<<eb, 256, 0, stream>>>(ei, src, tgt, Rout, Tout, Wout, nz, E, N);
    }
}

// Round 7
// 324.965 us; speedup vs baseline: 2.1099x; 1.2688x over previous
//
#include <hip/hip_runtime.h>
#include <math.h>

static constexpr float kSigma2 = 0.05f * 0.05f;
static constexpr int kCap = 6400;  // max edges per 128-node bucket in LDS sort

__device__ __forceinline__ int load_idx(const void* ei, long long j, int is64) {
    if (is64) return (int)(((const long long*)ei)[j]);
    return ((const int*)ei)[j];
}

// Detect whether edge_index is int64 (all odd int32 words zero) or int32.
__global__ void k_detect(const int* __restrict__ ei32, int E, int* __restrict__ nz) {
    int t = threadIdx.x;
    int lim = E < 2048 ? E : 2048;
    int acc = 0;
    for (int k = t; k < lim; k += blockDim.x) acc |= ei32[2 * k + 1];
    if (acc) atomicOr(nz, 1);
}

// Pack points into float4 arrays for vector gathers.
__global__ void k_pack(const float* __restrict__ src, const float* __restrict__ tgt,
                       float4* __restrict__ s4, float4* __restrict__ t4, int N) {
    int i = blockIdx.x * blockDim.x + threadIdx.x;
    if (i >= N) return;
    s4[i] = make_float4(src[3 * i + 0], src[3 * i + 1], src[3 * i + 2], 0.0f);
    t4[i] = make_float4(tgt[3 * i + 0], tgt[3 * i + 1], tgt[3 * i + 2], 0.0f);
}

// ---------------- shared Kabsch core (fp64, Jacobi on M^T M) ----------------
__device__ void kabsch_from_M(const double M[3][3], double Rm[3][3]) {
    Rm[0][0] = 1; Rm[0][1] = 0; Rm[0][2] = 0;
    Rm[1][0] = 0; Rm[1][1] = 1; Rm[1][2] = 0;
    Rm[2][0] = 0; Rm[2][1] = 0; Rm[2][2] = 1;

    double frob2 = 0.0;
#pragma unroll
    for (int r = 0; r < 3; ++r)
#pragma unroll
        for (int c = 0; c < 3; ++c) frob2 += M[r][c] * M[r][c];
    if (frob2 <= 1e-80) return;

    double A[3][3];
#pragma unroll
    for (int r = 0; r < 3; ++r)
#pragma unroll
        for (int c = 0; c < 3; ++c) {
            double s = 0.0;
#pragma unroll
            for (int k = 0; k < 3; ++k) s += M[k][r] * M[k][c];
            A[r][c] = s;
        }
    double V[3][3] = {{1, 0, 0}, {0, 1, 0}, {0, 0, 1}};
    const int PL[3] = {0, 0, 1};
    const int QL[3] = {1, 2, 2};
    for (int sweep = 0; sweep < 15; ++sweep) {
        double off = fabs(A[0][1]) + fabs(A[0][2]) + fabs(A[1][2]);
        if (off == 0.0) break;
        for (int pi = 0; pi < 3; ++pi) {
            int p = PL[pi], q = QL[pi], r3 = 3 - p - q;
            double apq = A[p][q];
            if (apq == 0.0) continue;
            double theta = (A[q][q] - A[p][p]) / (2.0 * apq);
            double t = copysign(1.0, theta) / (fabs(theta) + sqrt(theta * theta + 1.0));
            double c = 1.0 / sqrt(t * t + 1.0);
            double s = t * c;
            A[p][p] -= t * apq;
            A[q][q] += t * apq;
            A[p][q] = 0.0; A[q][p] = 0.0;
            double arp = A[r3][p], arq = A[r3][q];
            A[r3][p] = c * arp - s * arq; A[p][r3] = A[r3][p];
            A[r3][q] = s * arp + c * arq; A[q][r3] = A[r3][q];
#pragma unroll
            for (int k = 0; k < 3; ++k) {
                double vp = V[k][p], vq = V[k][q];
                V[k][p] = c * vp - s * vq;
                V[k][q] = s * vp + c * vq;
            }
        }
    }
    double lam[3] = {A[0][0], A[1][1], A[2][2]};
    int id0 = 0, id1 = 1, id2 = 2, tt;
    if (lam[id0] < lam[id1]) { tt = id0; id0 = id1; id1 = tt; }
    if (lam[id0] < lam[id2]) { tt = id0; id0 = id2; id2 = tt; }
    if (lam[id1] < lam[id2]) { tt = id1; id1 = id2; id2 = tt; }
    double v1[3] = {V[0][id0], V[1][id0], V[2][id0]};
    double v2[3] = {V[0][id1], V[1][id1], V[2][id1]};
    double v3[3] = {V[0][id2], V[1][id2], V[2][id2]};

    double b1[3], b2[3];
#pragma unroll
    for (int r = 0; r < 3; ++r) {
        b1[r] = M[r][0] * v1[0] + M[r][1] * v1[1] + M[r][2] * v1[2];
        b2[r] = M[r][0] * v2[0] + M[r][1] * v2[1] + M[r][2] * v2[2];
    }
    double n1 = sqrt(b1[0] * b1[0] + b1[1] * b1[1] + b1[2] * b1[2]);
    if (n1 <= 1e-150) return;
    double u1[3] = {b1[0] / n1, b1[1] / n1, b1[2] / n1};
    double dot = u1[0] * b2[0] + u1[1] * b2[1] + u1[2] * b2[2];
    double w2[3] = {b2[0] - dot * u1[0], b2[1] - dot * u1[1], b2[2] - dot * u1[2]};
    double n2 = sqrt(w2[0] * w2[0] + w2[1] * w2[1] + w2[2] * w2[2]);
    double u2[3];
    if (n2 > n1 * 1e-12) {
        u2[0] = w2[0] / n2; u2[1] = w2[1] / n2; u2[2] = w2[2] / n2;
    } else {
        double ex0 = (fabs(u1[0]) < 0.9) ? 1.0 : 0.0;
        double ex1 = 1.0 - ex0;
        double cx = u1[1] * 0.0 - u1[2] * ex1;
        double cy = u1[2] * ex0 - u1[0] * 0.0;
        double cz = u1[0] * ex1 - u1[1] * ex0;
        double cn = sqrt(cx * cx + cy * cy + cz * cz);
        u2[0] = cx / cn; u2[1] = cy / cn; u2[2] = cz / cn;
    }
    double u3[3] = {u1[1] * u2[2] - u1[2] * u2[1],
                    u1[2] * u2[0] - u1[0] * u2[2],
                    u1[0] * u2[1] - u1[1] * u2[0]};
    double dV = v1[0] * (v2[1] * v3[2] - v2[2] * v3[1])
              - v1[1] * (v2[0] * v3[2] - v2[2] * v3[0])
              + v1[2] * (v2[0] * v3[1] - v2[1] * v3[0]);
    dV = (dV >= 0.0) ? 1.0 : -1.0;
#pragma unroll
    for (int r = 0; r < 3; ++r)
#pragma unroll
        for (int c = 0; c < 3; ++c)
            Rm[r][c] = u1[r] * v1[c] + u2[r] * v2[c] + dV * u3[r] * v3[c];
}

// ---------------- bucketed counting-sort path ----------------
// fine bucket = dst >> 7 (128 nodes). final payload: x = (nbr<<7)|(dst&127), y = w bits.
// coarse bucket = dst >> 13 (64 fine buckets). intermediate payload:
//   x = (nbr<<13)|(dst&8191), y = w bits.

__global__ void __launch_bounds__(256) k_bhist(const void* __restrict__ ei,
                                               int* __restrict__ btot16,
                                               const int* __restrict__ nz,
                                               int E, int N, int nbuckets) {
    __shared__ int lhist[1024];
    int t = threadIdx.x;
    long long tile = (long long)blockIdx.x * 2048;
    long long remll = (long long)E - tile;
    int rem = (remll < 2048) ? (int)remll : 2048;
    int is64 = (*nz == 0);
    for (int i = t; i < 1024; i += 256) lhist[i] = 0;
    __syncthreads();
    int d[8];
    int cnt8 = 0;
    if (rem == 2048) {
        if (is64) {
            const long long* p = (const long long*)ei + tile + (long long)t * 8;
#pragma unroll
            for (int k = 0; k < 4; ++k) {
                longlong2 v = ((const longlong2*)p)[k];
                d[2 * k] = (int)v.x;
                d[2 * k + 1] = (int)v.y;
            }
        } else {
            const int* p = (const int*)ei + tile + (long long)t * 8;
            int4 a = ((const int4*)p)[0];
            int4 bb = ((const int4*)p)[1];
            d[0] = a.x; d[1] = a.y; d[2] = a.z; d[3] = a.w;
            d[4] = bb.x; d[5] = bb.y; d[6] = bb.z; d[7] = bb.w;
        }
        cnt8 = 8;
    } else {
        int base = t * 8;
#pragma unroll
        for (int k = 0; k < 8; ++k) {
            int idx = base + k;
            if (idx < rem) d[cnt8++] = load_idx(ei, tile + idx, is64);
        }
    }
    for (int k = 0; k < cnt8; ++k)
        if ((unsigned)d[k] < (unsigned)N) atomicAdd(&lhist[d[k] >> 7], 1);
    __syncthreads();
    for (int b = t; b < 1024; b += 256) {
        int c = lhist[b];
        if (c > 0 && b < nbuckets) atomicAdd(&btot16[b * 16], c);
    }
}

// fine exclusive scan -> boff, cur16; also coarse cursor init curC16.
__global__ void k_scan(const int* __restrict__ btot16, int* __restrict__ boff,
                       int* __restrict__ cur16, int* __restrict__ curC16, int nbuckets) {
    __shared__ int sm[1024];
    int t = threadIdx.x;
    int v = (t < nbuckets) ? btot16[t * 16] : 0;
    sm[t] = v;
    __syncthreads();
    for (int s = 1; s < 1024; s <<= 1) {
        int x = (t >= s) ? sm[t - s] : 0;
        __syncthreads();
        sm[t] += x;
        __syncthreads();
    }
    if (t < nbuckets) {
        int excl = sm[t] - v;
        boff[t] = excl;
        cur16[t * 16] = excl;
        if ((t & 63) == 0) curC16[(t >> 6) * 16] = excl;
    }
    if (t == nbuckets - 1) boff[nbuckets] = sm[t];
}

// Level-1 scatter: raw edges -> coarse-sorted sedge1 (<=16 bins, long runs).
__global__ void __launch_bounds__(256) k_cscatter(const void* __restrict__ ei,
                                                  const float* __restrict__ ew,
                                                  int* __restrict__ curC16,
                                                  int2* __restrict__ sedge1,
                                                  const int* __restrict__ nz,
                                                  int E, int N, int ncoarse) {
    __shared__ int2 stage[2048];
    __shared__ unsigned char binOf[2048];
    __shared__ int hist[16];
    __shared__ int excl[16];
    __shared__ int gbase[16];
    int t = threadIdx.x;
    long long tile = (long long)blockIdx.x * 2048;
    long long remll = (long long)E - tile;
    int rem = (remll < 2048) ? (int)remll : 2048;
    int is64 = (*nz == 0);
    if (t < 16) hist[t] = 0;
    __syncthreads();

    int dd[8], nn[8];
    float ww[8];
    int cnt8 = 0;
    if (rem == 2048) {
        if (is64) {
            const long long* pd = (const long long*)ei + tile + (long long)t * 8;
            const long long* pn = (const long long*)ei + (long long)E + tile + (long long)t * 8;
#pragma unroll
            for (int k = 0; k < 4; ++k) {
                longlong2 vd = ((const longlong2*)pd)[k];
                longlong2 vn = ((const longlong2*)pn)[k];
                dd[2 * k] = (int)vd.x; dd[2 * k + 1] = (int)vd.y;
                nn[2 * k] = (int)vn.x; nn[2 * k + 1] = (int)vn.y;
            }
        } else {
            const int* pd = (const int*)ei + tile + (long long)t * 8;
            const int* pn = (const int*)ei + (long long)E + tile + (long long)t * 8;
            int4 a = ((const int4*)pd)[0], b = ((const int4*)pd)[1];
            int4 c = ((const int4*)pn)[0], d = ((const int4*)pn)[1];
            dd[0] = a.x; dd[1] = a.y; dd[2] = a.z; dd[3] = a.w;
            dd[4] = b.x; dd[5] = b.y; dd[6] = b.z; dd[7] = b.w;
            nn[0] = c.x; nn[1] = c.y; nn[2] = c.z; nn[3] = c.w;
            nn[4] = d.x; nn[5] = d.y; nn[6] = d.z; nn[7] = d.w;
        }
        const float* pw = ew + tile + (long long)t * 8;
        float4 wa = ((const float4*)pw)[0], wb = ((const float4*)pw)[1];
        ww[0] = wa.x; ww[1] = wa.y; ww[2] = wa.z; ww[3] = wa.w;
        ww[4] = wb.x; ww[5] = wb.y; ww[6] = wb.z; ww[7] = wb.w;
        cnt8 = 8;
    } else {
        int base = t * 8;
#pragma unroll
        for (int k = 0; k < 8; ++k) {
            int idx = base + k;
            if (idx < rem) {
                long long e = tile + idx;
                dd[cnt8] = load_idx(ei, e, is64);
                nn[cnt8] = load_idx(ei, (long long)E + e, is64);
                ww[cnt8] = ew[e];
                ++cnt8;
            }
        }
    }

    int mybin[8], myrank[8];
    int2 mypay[8];
#pragma unroll
    for (int k = 0; k < 8; ++k) {
        mybin[k] = -1;
        if (k < cnt8) {
            int d = dd[k];
            if ((unsigned)d < (unsigned)N) {
                int n = nn[k];
                if ((unsigned)n >= (unsigned)N) n = N;  // sentinel; filtered later
                int cb = d >> 13;
                mybin[k] = cb;
                myrank[k] = atomicAdd(&hist[cb], 1);
                mypay[k].x = (n << 13) | (d & 8191);
                mypay[k].y = __float_as_int(ww[k]);
            }
        }
    }
    __syncthreads();
    if (t == 0) {
        int run = 0;
#pragma unroll
        for (int c = 0; c < 16; ++c) { excl[c] = run; run += hist[c]; }
    }
    __syncthreads();
#pragma unroll
    for (int k = 0; k < 8; ++k) {
        if (mybin[k] >= 0) {
            int lpos = excl[mybin[k]] + myrank[k];
            stage[lpos] = mypay[k];
            binOf[lpos] = (unsigned char)mybin[k];
        }
    }
    if (t < 16) {
        int c = hist[t];
        gbase[t] = (c > 0 && t < ncoarse) ? atomicAdd(&curC16[t * 16], c) : 0;
    }
    __syncthreads();
    int total = excl[15] + hist[15];
    for (int lpos = t; lpos < total; lpos += 256) {
        int c = binOf[lpos];
        sedge1[gbase[c] + (lpos - excl[c])] = stage[lpos];
    }
}

// Level-2 scatter: coarse-sorted sedge1 -> fine-sorted sedge2 (repacks payload).
__global__ void __launch_bounds__(256) k_fscatter(const int2* __restrict__ sedge1,
                                                  int* __restrict__ cur16,
                                                  const int* __restrict__ boff,
                                                  int2* __restrict__ sedge2,
                                                  int E, int nbuckets, int ncoarse) {
    __shared__ int2 stage[2048];
    __shared__ unsigned short binOf[2048];
    __shared__ int lhist[1024];
    __shared__ int lincl[1024];
    __shared__ int gbase[1024];
    __shared__ int co[17];
    int t = threadIdx.x;
    if (t <= ncoarse) {
        int f = t * 64;
        if (f > nbuckets) f = nbuckets;
        co[t] = boff[f];
    }
    for (int i = t; i < 1024; i += 256) lhist[i] = 0;
    __syncthreads();
    int Ev = co[ncoarse];
    long long tile = (long long)blockIdx.x * 2048;
    if (tile >= Ev) return;
    long long remll = (long long)Ev - tile;
    int rem = (remll < 2048) ? (int)remll : 2048;

    int2 pay[8];
    int cnt8 = 0;
    if (rem == 2048) {
        const int4* p4 = (const int4*)(sedge1 + tile + (long long)t * 8);
#pragma unroll
        for (int k = 0; k < 4; ++k) {
            int4 v = p4[k];
            pay[2 * k].x = v.x; pay[2 * k].y = v.y;
            pay[2 * k + 1].x = v.z; pay[2 * k + 1].y = v.w;
        }
        cnt8 = 8;
    } else {
        int base = t * 8;
#pragma unroll
        for (int k = 0; k < 8; ++k) {
            int idx = base + k;
            if (idx < rem) pay[cnt8++] = sedge1[tile + idx];
        }
    }

    int mybin[8], myrank[8];
    int2 mypay[8];
#pragma unroll
    for (int k = 0; k < 8; ++k) {
        mybin[k] = -1;
        if (k < cnt8) {
            long long pos = tile + t * 8 + k;
            // find coarse bucket containing pos (<=16 entries)
            int c = 0;
            while (c + 1 < ncoarse && pos >= co[c + 1]) ++c;
            int x1 = pay[k].x;
            unsigned nbr = ((unsigned)x1) >> 13;
            int fin = c * 64 + ((x1 & 8191) >> 7);
            mybin[k] = fin;
            myrank[k] = atomicAdd(&lhist[fin], 1);
            mypay[k].x = (int)((nbr << 7) | (unsigned)(x1 & 127));
            mypay[k].y = pay[k].y;
        }
    }
    __syncthreads();
    for (int i = t; i < 1024; i += 256) lincl[i] = lhist[i];
    __syncthreads();
    for (int s = 1; s < 1024; s <<= 1) {
        int tmp[4];
#pragma unroll
        for (int j = 0; j < 4; ++j) {
            int i = (j << 8) + t;
            tmp[j] = (i >= s) ? lincl[i - s] : 0;
        }
        __syncthreads();
#pragma unroll
        for (int j = 0; j < 4; ++j) {
            int i = (j << 8) + t;
            lincl[i] += tmp[j];
        }
        __syncthreads();
    }
#pragma unroll
    for (int k = 0; k < 8; ++k) {
        if (mybin[k] >= 0) {
            int ex = lincl[mybin[k]] - lhist[mybin[k]];
            int lpos = ex + myrank[k];
            stage[lpos] = mypay[k];
            binOf[lpos] = (unsigned short)mybin[k];
        }
    }
    __syncthreads();
    for (int bb = t; bb < 1024; bb += 256) {
        int c = lhist[bb];
        gbase[bb] = (c > 0 && bb < nbuckets) ? atomicAdd(&cur16[bb * 16], c) : 0;
    }
    __syncthreads();
    int total = lincl[1023];
    for (int lpos = t; lpos < total; lpos += 256) {
        int bb = binOf[lpos];
        int ex = lincl[bb] - lhist[bb];
        sedge2[gbase[bb] + (lpos - ex)] = stage[lpos];
    }
}

// Single-level scatter (fallback when ws can't hold two edge buffers).
__global__ void __launch_bounds__(256) k_binscatter(const void* __restrict__ ei,
                                                    const float* __restrict__ ew,
                                                    int* __restrict__ cur16,
                                                    int2* __restrict__ sedge,
                                                    const int* __restrict__ nz,
                                                    int E, int N, int nbuckets) {
    __shared__ int2 stage[2048];
    __shared__ unsigned short binOf[2048];
    __shared__ int lhist[1024];
    __shared__ int lincl[1024];
    __shared__ int gbase[1024];
    int t = threadIdx.x;
    long long tile = (long long)blockIdx.x * 2048;
    long long remll = (long long)E - tile;
    int rem = (remll < 2048) ? (int)remll : 2048;
    int is64 = (*nz == 0);
    for (int i = t; i < 1024; i += 256) lhist[i] = 0;
    __syncthreads();

    int dd[8], nn[8];
    float ww[8];
    int cnt8 = 0;
    if (rem == 2048) {
        if (is64) {
            const long long* pd = (const long long*)ei + tile + (long long)t * 8;
            const long long* pn = (const long long*)ei + (long long)E + tile + (long long)t * 8;
#pragma unroll
            for (int k = 0; k < 4; ++k) {
                longlong2 vd = ((const longlong2*)pd)[k];
                longlong2 vn = ((const longlong2*)pn)[k];
                dd[2 * k] = (int)vd.x; dd[2 * k + 1] = (int)vd.y;
                nn[2 * k] = (int)vn.x; nn[2 * k + 1] = (int)vn.y;
            }
        } else {
            const int* pd = (const int*)ei + tile + (long long)t * 8;
            const int* pn = (const int*)ei + (long long)E + tile + (long long)t * 8;
            int4 a = ((const int4*)pd)[0], b = ((const int4*)pd)[1];
            int4 c = ((const int4*)pn)[0], d = ((const int4*)pn)[1];
            dd[0] = a.x; dd[1] = a.y; dd[2] = a.z; dd[3] = a.w;
            dd[4] = b.x; dd[5] = b.y; dd[6] = b.z; dd[7] = b.w;
            nn[0] = c.x; nn[1] = c.y; nn[2] = c.z; nn[3] = c.w;
            nn[4] = d.x; nn[5] = d.y; nn[6] = d.z; nn[7] = d.w;
        }
        const float* pw = ew + tile + (long long)t * 8;
        float4 wa = ((const float4*)pw)[0], wb = ((const float4*)pw)[1];
        ww[0] = wa.x; ww[1] = wa.y; ww[2] = wa.z; ww[3] = wa.w;
        ww[4] = wb.x; ww[5] = wb.y; ww[6] = wb.z; ww[7] = wb.w;
        cnt8 = 8;
    } else {
        int base = t * 8;
#pragma unroll
        for (int k = 0; k < 8; ++k) {
            int idx = base + k;
            if (idx < rem) {
                long long e = tile + idx;
                dd[cnt8] = load_idx(ei, e, is64);
                nn[cnt8] = load_idx(ei, (long long)E + e, is64);
                ww[cnt8] = ew[e];
                ++cnt8;
            }
        }
    }

    int mybin[8];
    int myrank[8];
    int2 mypay[8];
#pragma unroll
    for (int k = 0; k < 8; ++k) {
        mybin[k] = -1;
        if (k < cnt8) {
            int d = dd[k];
            if ((unsigned)d < (unsigned)N) {
                int n = nn[k];
                if ((unsigned)n >= (unsigned)N) n = N;  // sentinel
                int bb = d >> 7;
                mybin[k] = bb;
                myrank[k] = atomicAdd(&lhist[bb], 1);
                mypay[k].x = (n << 7) | (d & 127);
                mypay[k].y = __float_as_int(ww[k]);
            }
        }
    }
    __syncthreads();
    for (int i = t; i < 1024; i += 256) lincl[i] = lhist[i];
    __syncthreads();
    for (int s = 1; s < 1024; s <<= 1) {
        int tmp[4];
#pragma unroll
        for (int j = 0; j < 4; ++j) {
            int i = (j << 8) + t;
            tmp[j] = (i >= s) ? lincl[i - s] : 0;
        }
        __syncthreads();
#pragma unroll
        for (int j = 0; j < 4; ++j) {
            int i = (j << 8) + t;
            lincl[i] += tmp[j];
        }
        __syncthreads();
    }
#pragma unroll
    for (int k = 0; k < 8; ++k) {
        if (mybin[k] >= 0) {
            int ex = lincl[mybin[k]] - lhist[mybin[k]];
            int lpos = ex + myrank[k];
            stage[lpos] = mypay[k];
            binOf[lpos] = (unsigned short)mybin[k];
        }
    }
    __syncthreads();
    for (int bb = t; bb < 1024; bb += 256) {
        int c = lhist[bb];
        gbase[bb] = (c > 0 && bb < nbuckets) ? atomicAdd(&cur16[bb * 16], c) : 0;
    }
    __syncthreads();
    int total = lincl[1023];
    for (int lpos = t; lpos < total; lpos += 256) {
        int bb = binOf[lpos];
        int ex = lincl[bb] - lhist[bb];
        sedge[gbase[bb] + (lpos - ex)] = stage[lpos];
    }
}

// Per-bucket in-LDS counting sort to exact node order; writes node-sorted
// edges back IN PLACE and emits per-node (start,count) segments.
__global__ void __launch_bounds__(256) k_sort(const int* __restrict__ boff,
                                              int2* __restrict__ sedge,
                                              int2* __restrict__ nseg) {
    __shared__ int2 sorted[kCap];
    __shared__ int hist[128];
    __shared__ int scanbuf[128];
    __shared__ int offs[128];
    __shared__ int cur[128];
    int b = blockIdx.x, t = threadIdx.x;
    int e0 = boff[b], e1 = boff[b + 1];
    int cnt = e1 - e0;
    if (t < 128) hist[t] = 0;
    __syncthreads();
    if (cnt <= kCap) {
        for (int i = t; i < cnt; i += 256)
            atomicAdd(&hist[sedge[e0 + i].x & 127], 1);
        __syncthreads();
        if (t < 128) scanbuf[t] = hist[t];
        __syncthreads();
        for (int s = 1; s < 128; s <<= 1) {
            int v = 0;
            if (t < 128 && t >= s) v = scanbuf[t - s];
            __syncthreads();
            if (t < 128) scanbuf[t] += v;
            __syncthreads();
        }
        if (t < 128) {
            int ex = scanbuf[t] - hist[t];
            offs[t] = ex;
            cur[t] = ex;
        }
        __syncthreads();
        for (int i = t; i < cnt; i += 256) {
            int2 p = sedge[e0 + i];
            int r = atomicAdd(&cur[p.x & 127], 1);
            sorted[r] = p;
        }
        __syncthreads();
        for (int i = t; i < cnt; i += 256) sedge[e0 + i] = sorted[i];
        if (t < 128) nseg[b * 128 + t] = make_int2(e0 + offs[t], hist[t]);
    } else {
        if (t < 128) nseg[b * 128 + t] = make_int2(e0, -cnt);
    }
}

// 8 lanes per node; single fused 23-moment pass; fp64 Kabsch tail + per-node
// robust weight wnode = sigma2/(||R s + T - t||^2 + sigma2).
__global__ void __launch_bounds__(256) k_moment(const int2* __restrict__ nseg,
                                                const int2* __restrict__ sedge,
                                                const float4* __restrict__ s4,
                                                const float4* __restrict__ t4,
                                                float* __restrict__ Rout,
                                                float* __restrict__ Tout,
                                                float* __restrict__ wnode, int N) {
    __shared__ float acc[23][128];
    int b = blockIdx.x, t = threadIdx.x;
    int oct = t >> 3, lane8 = t & 7;
    for (int node = oct; node < 128; node += 32) {
        int2 seg = nseg[b * 128 + node];
        float v[23];
#pragma unroll
        for (int i = 0; i < 23; ++i) v[i] = 0.0f;
        int start = seg.x;
        int cn = seg.y;
        int total = (cn >= 0) ? cn : -cn;
        int filter = (cn < 0);
        for (int j = lane8; j < total; j += 8) {
            int2 p = sedge[start + j];
            if (filter && (p.x & 127) != node) continue;
            unsigned n = ((unsigned)p.x) >> 7;
            if (n >= (unsigned)N) continue;
            float w = __int_as_float(p.y);
            float4 a = s4[n];
            float4 bb = t4[n];
            float sx = a.x, sy = a.y, sz = a.z;
            float tx = bb.x, ty = bb.y, tz = bb.z;
            v[0] += 1.0f;
            v[1] += sx; v[2] += sy; v[3] += sz;
            v[4] += tx; v[5] += ty; v[6] += tz;
            v[7] += w;
            float wsx = w * sx, wsy = w * sy, wsz = w * sz;
            v[8] += wsx; v[9] += wsy; v[10] += wsz;
            v[11] += w * tx; v[12] += w * ty; v[13] += w * tz;
            v[14] += wsx * tx; v[15] += wsx * ty; v[16] += wsx * tz;
            v[17] += wsy * tx; v[18] += wsy * ty; v[19] += wsy * tz;
            v[20] += wsz * tx; v[21] += wsz * ty; v[22] += wsz * tz;
        }
#pragma unroll
        for (int m = 1; m < 8; m <<= 1) {
#pragma unroll
            for (int i = 0; i < 23; ++i) v[i] += __shfl_xor(v[i], m, 64);
        }
        if (lane8 == 0) {
#pragma unroll
            for (int i = 0; i < 23; ++i) acc[i][node] = v[i];
        }
    }
    __syncthreads();
    if (t < 128) {
        long long i = (long long)b * 128 + t;
        if (i < N) {
            double cntv = (double)acc[0][t];
            double inv = 1.0 / fmax(cntv, 1.0);
            double sb0 = acc[1][t] * inv, sb1 = acc[2][t] * inv, sb2 = acc[3][t] * inv;
            double tb0 = acc[4][t] * inv, tb1 = acc[5][t] * inv, tb2 = acc[6][t] * inv;
            double Sw = acc[7][t];
            double Sws[3] = {acc[8][t], acc[9][t], acc[10][t]};
            double Swt[3] = {acc[11][t], acc[12][t], acc[13][t]};
            double sb[3] = {sb0, sb1, sb2}, tb[3] = {tb0, tb1, tb2};
            double M[3][3];
#pragma unroll
            for (int r = 0; r < 3; ++r)
#pragma unroll
                for (int c = 0; c < 3; ++c)
                    M[r][c] = (double)acc[14 + 3 * r + c][t]
                            - sb[r] * Swt[c] - Sws[r] * tb[c] + Sw * sb[r] * tb[c];
            double Rm[3][3];
            kabsch_from_M(M, Rm);
            double T0 = tb0 - (Rm[0][0] * sb0 + Rm[0][1] * sb1 + Rm[0][2] * sb2);
            double T1 = tb1 - (Rm[1][0] * sb0 + Rm[1][1] * sb1 + Rm[1][2] * sb2);
            double T2 = tb2 - (Rm[2][0] * sb0 + Rm[2][1] * sb1 + Rm[2][2] * sb2);
#pragma unroll
            for (int r = 0; r < 3; ++r)
#pragma unroll
                for (int c = 0; c < 3; ++c)
                    Rout[9 * i + 3 * r + c] = (float)Rm[r][c];
            Tout[3 * i + 0] = (float)T0;
            Tout[3 * i + 1] = (float)T1;
            Tout[3 * i + 2] = (float)T2;
            // per-node robust weight
            float4 a = s4[(int)i];
            float4 q = t4[(int)i];
            double x0 = Rm[0][0] * a.x + Rm[0][1] * a.y + Rm[0][2] * a.z + T0;
            double x1 = Rm[1][0] * a.x + Rm[1][1] * a.y + Rm[1][2] * a.z + T1;
            double x2 = Rm[2][0] * a.x + Rm[2][1] * a.y + Rm[2][2] * a.z + T2;
            double d0 = x0 - q.x, d1 = x1 - q.y, d2 = x2 - q.z;
            double dd = d0 * d0 + d1 * d1 + d2 * d2;
            wnode[i] = (float)((double)kSigma2 / (dd + (double)kSigma2));
        }
    }
}

// wout[e] = wnode[nbr[e]] (4 edges/thread, vector loads, float4 store).
__global__ void __launch_bounds__(256) k_wgather(const void* __restrict__ ei,
                                                 const float* __restrict__ wnode,
                                                 float* __restrict__ wout,
                                                 const int* __restrict__ nz,
                                                 int E, int N) {
    int gid = blockIdx.x * blockDim.x + threadIdx.x;
    long long base = (long long)gid * 4;
    if (base >= E) return;
    int is64 = (*nz == 0);
    int n_[4];
    int full = (base + 4 <= (long long)E);
    if (full) {
        if (is64) {
            const long long* p = (const long long*)ei + (long long)E + base;
            longlong2 a = ((const longlong2*)p)[0];
            longlong2 b = ((const longlong2*)p)[1];
            n_[0] = (int)a.x; n_[1] = (int)a.y; n_[2] = (int)b.x; n_[3] = (int)b.y;
        } else {
            int4 a = *(const int4*)((const int*)ei + (long long)E + base);
            n_[0] = a.x; n_[1] = a.y; n_[2] = a.z; n_[3] = a.w;
        }
    } else {
#pragma unroll
        for (int k = 0; k < 4; ++k) {
            long long e = base + k;
            n_[k] = (e < E) ? load_idx(ei, (long long)E + e, is64) : 0;
        }
    }
    float w[4];
#pragma unroll
    for (int k = 0; k < 4; ++k)
        w[k] = ((unsigned)n_[k] < (unsigned)N) ? wnode[n_[k]] : 1.0f;
    if (full) {
        *(float4*)(wout + base) = make_float4(w[0], w[1], w[2], w[3]);
    } else {
#pragma unroll
        for (int k = 0; k < 4; ++k)
            if (base + k < E) wout[base + k] = w[k];
    }
}

// ---------------- fallback atomic path ----------------

__global__ void k_accum1(const void* __restrict__ ei, const float* __restrict__ src,
                         const float* __restrict__ tgt, float* __restrict__ cnt,
                         float* __restrict__ ssum, float* __restrict__ tsum,
                         const int* __restrict__ nz, int E, int N) {
    int e = blockIdx.x * blockDim.x + threadIdx.x;
    if (e >= E) return;
    int is64 = (*nz == 0);
    int d = load_idx(ei, e, is64);
    int n = load_idx(ei, (long long)E + e, is64);
    if ((unsigned)d >= (unsigned)N || (unsigned)n >= (unsigned)N) return;
    atomicAdd(&cnt[d], 1.0f);
    atomicAdd(&ssum[3 * d + 0], src[3 * n + 0]);
    atomicAdd(&ssum[3 * d + 1], src[3 * n + 1]);
    atomicAdd(&ssum[3 * d + 2], src[3 * n + 2]);
    atomicAdd(&tsum[3 * d + 0], tgt[3 * n + 0]);
    atomicAdd(&tsum[3 * d + 1], tgt[3 * n + 1]);
    atomicAdd(&tsum[3 * d + 2], tgt[3 * n + 2]);
}

__global__ void k_centers(float* __restrict__ cnt, float* __restrict__ ssum,
                          float* __restrict__ tsum, int N) {
    int i = blockIdx.x * blockDim.x + threadIdx.x;
    if (i >= N) return;
    float inv = 1.0f / fmaxf(cnt[i], 1.0f);
    ssum[3 * i + 0] *= inv; ssum[3 * i + 1] *= inv; ssum[3 * i + 2] *= inv;
    tsum[3 * i + 0] *= inv; tsum[3 * i + 1] *= inv; tsum[3 * i + 2] *= inv;
}

__global__ void k_accum2(const void* __restrict__ ei, const float* __restrict__ src,
                         const float* __restrict__ tgt, const float* __restrict__ ew,
                         const float* __restrict__ sc, const float* __restrict__ tc,
                         float* __restrict__ Mm, const int* __restrict__ nz, int E, int N) {
    int e = blockIdx.x * blockDim.x + threadIdx.x;
    if (e >= E) return;
    int is64 = (*nz == 0);
    int d = load_idx(ei, e, is64);
    int n = load_idx(ei, (long long)E + e, is64);
    if ((unsigned)d >= (unsigned)N || (unsigned)n >= (unsigned)N) return;
    float w = ew[e];
    float a0 = (src[3 * n + 0] - sc[3 * d + 0]) * w;
    float a1 = (src[3 * n + 1] - sc[3 * d + 1]) * w;
    float a2 = (src[3 * n + 2] - sc[3 * d + 2]) * w;
    float b0 = tgt[3 * n + 0] - tc[3 * d + 0];
    float b1 = tgt[3 * n + 1] - tc[3 * d + 1];
    float b2 = tgt[3 * n + 2] - tc[3 * d + 2];
    float* Md = Mm + 9 * (long long)d;
    atomicAdd(Md + 0, a0 * b0); atomicAdd(Md + 1, a0 * b1); atomicAdd(Md + 2, a0 * b2);
    atomicAdd(Md + 3, a1 * b0); atomicAdd(Md + 4, a1 * b1); atomicAdd(Md + 5, a1 * b2);
    atomicAdd(Md + 6, a2 * b0); atomicAdd(Md + 7, a2 * b1); atomicAdd(Md + 8, a2 * b2);
}

__global__ void k_kabsch(const float* __restrict__ Mm, const float* __restrict__ sc,
                         const float* __restrict__ tc, float* __restrict__ Rout,
                         float* __restrict__ Tout, int N) {
    int i = blockIdx.x * blockDim.x + threadIdx.x;
    if (i >= N) return;
    double M[3][3];
#pragma unroll
    for (int r = 0; r < 3; ++r)
#pragma unroll
        for (int c = 0; c < 3; ++c)
            M[r][c] = (double)Mm[9 * (long long)i + 3 * r + c];
    double Rm[3][3];
    kabsch_from_M(M, Rm);
    double s0 = sc[3 * i + 0], s1 = sc[3 * i + 1], s2 = sc[3 * i + 2];
    double t0 = tc[3 * i + 0], t1 = tc[3 * i + 1], t2 = tc[3 * i + 2];
#pragma unroll
    for (int r = 0; r < 3; ++r)
#pragma unroll
        for (int c = 0; c < 3; ++c)
            Rout[9 * (long long)i + 3 * r + c] = (float)Rm[r][c];
    Tout[3 * i + 0] = (float)(t0 - (Rm[0][0] * s0 + Rm[0][1] * s1 + Rm[0][2] * s2));
    Tout[3 * i + 1] = (float)(t1 - (Rm[1][0] * s0 + Rm[1][1] * s1 + Rm[1][2] * s2));
    Tout[3 * i + 2] = (float)(t2 - (Rm[2][0] * s0 + Rm[2][1] * s1 + Rm[2][2] * s2));
}

__global__ void k_weights_plain(const void* __restrict__ ei,
                                const float* __restrict__ src,
                                const float* __restrict__ tgt,
                                const float* __restrict__ R,
                                const float* __restrict__ T,
                                float* __restrict__ wout,
                                const int* __restrict__ nz, int E, int N) {
    int e = blockIdx.x * blockDim.x + threadIdx.x;
    if (e >= E) return;
    int is64 = (*nz == 0);
    int n = load_idx(ei, (long long)E + e, is64);
    float w = 1.0f;
    if ((unsigned)n < (unsigned)N) {
        float p0 = src[3 * n + 0], p1 = src[3 * n + 1], p2 = src[3 * n + 2];
        float q0 = tgt[3 * n + 0], q1 = tgt[3 * n + 1], q2 = tgt[3 * n + 2];
        const float* Rn = R + 9 * (long long)n;
        const float* Tn = T + 3 * (long long)n;
        float x0 = Rn[0] * p0 + Rn[1] * p1 + Rn[2] * p2 + Tn[0];
        float x1 = Rn[3] * p0 + Rn[4] * p1 + Rn[5] * p2 + Tn[1];
        float x2 = Rn[6] * p0 + Rn[7] * p1 + Rn[8] * p2 + Tn[2];
        float d0 = x0 - q0, d1 = x1 - q1, d2 = x2 - q2;
        float dd = d0 * d0 + d1 * d1 + d2 * d2;
        w = kSigma2 / (dd + kSigma2);
    }
    wout[e] = w;
}

extern "C" void kernel_launch(void* const* d_in, const int* in_sizes, int n_in,
                              void* d_out, int out_size, void* d_ws, size_t ws_size,
                              hipStream_t stream) {
    const float* src = (const float*)d_in[0];
    const float* tgt = (const float*)d_in[1];
    const void* ei = d_in[2];
    const float* ew = (const float*)d_in[3];
    int N = in_sizes[0] / 3;
    int E = in_sizes[3];

    float* out = (float*)d_out;
    float* Rout = out;
    float* Tout = out + (size_t)9 * N;
    float* Wout = out + (size_t)12 * N;

    int eb = (E + 255) / 256;
    int nb = (N + 255) / 256;
    int nbuckets = (N + 127) / 128;
    int ncoarse = (nbuckets + 63) / 64;
    int tiles = (int)(((long long)E + 2047) / 2048);
    int wb4 = (int)(((long long)E + 1023) / 1024);

    // ws layout: [nz(16) | btot16 | cur16 | curC16(256) | boff | pad4 |
    //             sedge1 (E int2) | [sedge2 (E int2)] | s4 | t4 | wnode(N) | nseg]
    size_t ctrl_ints = 16 + (size_t)nbuckets * 16 * 2 + 256 + (nbuckets + 1);
    ctrl_ints = (ctrl_ints + 3) & ~(size_t)3;
    size_t after1 = ctrl_ints + 2 * (size_t)E;             // after sedge1
    after1 = (after1 + 3) & ~(size_t)3;
    size_t after2 = after1 + 2 * (size_t)E;                // after sedge2 (path A)
    after2 = (after2 + 3) & ~(size_t)3;
    size_t tail_ints = 8 * (size_t)N + (size_t)N + 2 * (size_t)128 * nbuckets;
    size_t needA = (after2 + tail_ints) * sizeof(int);
    size_t needB = (after1 + tail_ints) * sizeof(int);

    if (N <= 131072 && nbuckets <= 1024 && ws_size >= needB) {
        int twolevel = (ws_size >= needA) ? 1 : 0;
        int* nz = (int*)d_ws;
        int* btot16 = nz + 16;
        int* cur16 = btot16 + (size_t)nbuckets * 16;
        int* curC16 = cur16 + (size_t)nbuckets * 16;
        int* boff = curC16 + 256;
        int2* sedge1 = (int2*)((int*)d_ws + ctrl_ints);
        size_t tail_base = twolevel ? after2 : after1;
        int2* sedge2 = twolevel ? (int2*)((int*)d_ws + after1) : sedge1;
        float4* s4 = (float4*)((int*)d_ws + tail_base);
        float4* t4 = s4 + N;
        float* wnode = (float*)(t4 + N);
        int2* nseg = (int2*)(wnode + N);

        hipMemsetAsync(d_ws, 0, ctrl_ints * sizeof(int), stream);

        k_detect<<<1, 256, 0, stream>>>((const int*)ei, E, nz);
        k_pack<<<nb, 256, 0, stream>>>(src, tgt, s4, t4, N);
        k_bhist<<<tiles, 256, 0, stream>>>(ei, btot16, nz, E, N, nbuckets);
        k_scan<<<1, 1024, 0, stream>>>(btot16, boff, cur16, curC16, nbuckets);
        if (twolevel) {
            k_cscatter<<<tiles, 256, 0, stream>>>(ei, ew, curC16, sedge1, nz, E, N, ncoarse);
            k_fscatter<<<tiles, 256, 0, stream>>>(sedge1, cur16, boff, sedge2, E, nbuckets, ncoarse);
        } else {
            k_binscatter<<<tiles, 256, 0, stream>>>(ei, ew, cur16, sedge2, nz, E, N, nbuckets);
        }
        k_sort<<<nbuckets, 256, 0, stream>>>(boff, sedge2, nseg);
        k_moment<<<nbuckets, 256, 0, stream>>>(nseg, sedge2, s4, t4, Rout, Tout, wnode, N);
        k_wgather<<<wb4, 256, 0, stream>>>(ei, wnode, Wout, nz, E, N);
    } else {
        // fallback: atomic path
        float* cnt = (float*)d_ws;
        float* ssum = cnt + N;
        float* tsum = ssum + 3 * (size_t)N;
        float* Mm = tsum + 3 * (size_t)N;
        int* nz = (int*)(Mm + 9 * (size_t)N);
        size_t ws_bytes = (size_t)16 * N * sizeof(float) + 16;
        hipMemsetAsync(d_ws, 0, ws_bytes, stream);
        k_detect<<<1, 256, 0, stream>>>((const int*)ei, E, nz);
        k_accum1<<<eb, 256, 0, stream>>>(ei, src, tgt, cnt, ssum, tsum, nz, E, N);
        k_centers<<<nb, 256, 0, stream>>>(cnt, ssum, tsum, N);
        k_accum2<<<eb, 256, 0, stream>>>(ei, src, tgt, ew, ssum, tsum, Mm, nz, E, N);
        k_kabsch<<<nb, 256, 0, stream>>>(Mm, ssum, tsum, Rout, Tout, N);
        k_weights_plain<<<eb, 256, 0, stream>>>(ei, src, tgt, Rout, Tout, Wout, nz, E, N);
    }
}

// Round 8
// 279.272 us; speedup vs baseline: 2.4551x; 1.1636x over previous
//
#include <hip/hip_runtime.h>
#include <math.h>

static constexpr float kSigma2 = 0.05f * 0.05f;
static constexpr int kCap = 6400;  // max edges per 128-node bucket in LDS sort

__device__ __forceinline__ int load_idx(const void* ei, long long j, int is64) {
    if (is64) return (int)(((const long long*)ei)[j]);
    return ((const int*)ei)[j];
}

// Detect whether edge_index is int64 (all odd int32 words zero) or int32.
__global__ void k_detect(const int* __restrict__ ei32, int E, int* __restrict__ nz) {
    int t = threadIdx.x;
    int lim = E < 2048 ? E : 2048;
    int acc = 0;
    for (int k = t; k < lim; k += blockDim.x) acc |= ei32[2 * k + 1];
    if (acc) atomicOr(nz, 1);
}

// Pack points into float4 arrays for vector gathers.
__global__ void k_pack(const float* __restrict__ src, const float* __restrict__ tgt,
                       float4* __restrict__ s4, float4* __restrict__ t4, int N) {
    int i = blockIdx.x * blockDim.x + threadIdx.x;
    if (i >= N) return;
    s4[i] = make_float4(src[3 * i + 0], src[3 * i + 1], src[3 * i + 2], 0.0f);
    t4[i] = make_float4(tgt[3 * i + 0], tgt[3 * i + 1], tgt[3 * i + 2], 0.0f);
}

// ---------------- shared Kabsch core (fp64, Jacobi on M^T M) ----------------
__device__ void kabsch_from_M(const double M[3][3], double Rm[3][3]) {
    Rm[0][0] = 1; Rm[0][1] = 0; Rm[0][2] = 0;
    Rm[1][0] = 0; Rm[1][1] = 1; Rm[1][2] = 0;
    Rm[2][0] = 0; Rm[2][1] = 0; Rm[2][2] = 1;

    double frob2 = 0.0;
#pragma unroll
    for (int r = 0; r < 3; ++r)
#pragma unroll
        for (int c = 0; c < 3; ++c) frob2 += M[r][c] * M[r][c];
    if (frob2 <= 1e-80) return;

    double A[3][3];
#pragma unroll
    for (int r = 0; r < 3; ++r)
#pragma unroll
        for (int c = 0; c < 3; ++c) {
            double s = 0.0;
#pragma unroll
            for (int k = 0; k < 3; ++k) s += M[k][r] * M[k][c];
            A[r][c] = s;
        }
    double V[3][3] = {{1, 0, 0}, {0, 1, 0}, {0, 0, 1}};
    const int PL[3] = {0, 0, 1};
    const int QL[3] = {1, 2, 2};
    for (int sweep = 0; sweep < 15; ++sweep) {
        double off = fabs(A[0][1]) + fabs(A[0][2]) + fabs(A[1][2]);
        if (off == 0.0) break;
        for (int pi = 0; pi < 3; ++pi) {
            int p = PL[pi], q = QL[pi], r3 = 3 - p - q;
            double apq = A[p][q];
            if (apq == 0.0) continue;
            double theta = (A[q][q] - A[p][p]) / (2.0 * apq);
            double t = copysign(1.0, theta) / (fabs(theta) + sqrt(theta * theta + 1.0));
            double c = 1.0 / sqrt(t * t + 1.0);
            double s = t * c;
            A[p][p] -= t * apq;
            A[q][q] += t * apq;
            A[p][q] = 0.0; A[q][p] = 0.0;
            double arp = A[r3][p], arq = A[r3][q];
            A[r3][p] = c * arp - s * arq; A[p][r3] = A[r3][p];
            A[r3][q] = s * arp + c * arq; A[q][r3] = A[r3][q];
#pragma unroll
            for (int k = 0; k < 3; ++k) {
                double vp = V[k][p], vq = V[k][q];
                V[k][p] = c * vp - s * vq;
                V[k][q] = s * vp + c * vq;
            }
        }
    }
    double lam[3] = {A[0][0], A[1][1], A[2][2]};
    int id0 = 0, id1 = 1, id2 = 2, tt;
    if (lam[id0] < lam[id1]) { tt = id0; id0 = id1; id1 = tt; }
    if (lam[id0] < lam[id2]) { tt = id0; id0 = id2; id2 = tt; }
    if (lam[id1] < lam[id2]) { tt = id1; id1 = id2; id2 = tt; }
    double v1[3] = {V[0][id0], V[1][id0], V[2][id0]};
    double v2[3] = {V[0][id1], V[1][id1], V[2][id1]};
    double v3[3] = {V[0][id2], V[1][id2], V[2][id2]};

    double b1[3], b2[3];
#pragma unroll
    for (int r = 0; r < 3; ++r) {
        b1[r] = M[r][0] * v1[0] + M[r][1] * v1[1] + M[r][2] * v1[2];
        b2[r] = M[r][0] * v2[0] + M[r][1] * v2[1] + M[r][2] * v2[2];
    }
    double n1 = sqrt(b1[0] * b1[0] + b1[1] * b1[1] + b1[2] * b1[2]);
    if (n1 <= 1e-150) return;
    double u1[3] = {b1[0] / n1, b1[1] / n1, b1[2] / n1};
    double dot = u1[0] * b2[0] + u1[1] * b2[1] + u1[2] * b2[2];
    double w2[3] = {b2[0] - dot * u1[0], b2[1] - dot * u1[1], b2[2] - dot * u1[2]};
    double n2 = sqrt(w2[0] * w2[0] + w2[1] * w2[1] + w2[2] * w2[2]);
    double u2[3];
    if (n2 > n1 * 1e-12) {
        u2[0] = w2[0] / n2; u2[1] = w2[1] / n2; u2[2] = w2[2] / n2;
    } else {
        double ex0 = (fabs(u1[0]) < 0.9) ? 1.0 : 0.0;
        double ex1 = 1.0 - ex0;
        double cx = u1[1] * 0.0 - u1[2] * ex1;
        double cy = u1[2] * ex0 - u1[0] * 0.0;
        double cz = u1[0] * ex1 - u1[1] * ex0;
        double cn = sqrt(cx * cx + cy * cy + cz * cz);
        u2[0] = cx / cn; u2[1] = cy / cn; u2[2] = cz / cn;
    }
    double u3[3] = {u1[1] * u2[2] - u1[2] * u2[1],
                    u1[2] * u2[0] - u1[0] * u2[2],
                    u1[0] * u2[1] - u1[1] * u2[0]};
    double dV = v1[0] * (v2[1] * v3[2] - v2[2] * v3[1])
              - v1[1] * (v2[0] * v3[2] - v2[2] * v3[0])
              + v1[2] * (v2[0] * v3[1] - v2[1] * v3[0]);
    dV = (dV >= 0.0) ? 1.0 : -1.0;
#pragma unroll
    for (int r = 0; r < 3; ++r)
#pragma unroll
        for (int c = 0; c < 3; ++c)
            Rm[r][c] = u1[r] * v1[c] + u2[r] * v2[c] + dV * u3[r] * v3[c];
}

// ---------------- bucketed counting-sort path ----------------
// fine bucket = dst >> 7 (128 nodes). final payload: x = (nbr<<7)|(dst&127), y = w bits.
// coarse bucket = dst >> 13 (64 fine buckets). intermediate payload:
//   x = (nbr<<13)|(dst&8191), y = w bits.

// 16384 edges per block (64/thread): amortizes the global-atomic histogram flush.
__global__ void __launch_bounds__(256) k_bhist(const void* __restrict__ ei,
                                               int* __restrict__ btot16,
                                               const int* __restrict__ nz,
                                               int E, int N, int nbuckets) {
    __shared__ int lhist[1024];
    int t = threadIdx.x;
    long long tile = (long long)blockIdx.x * 16384;
    long long remll = (long long)E - tile;
    int rem = (remll < 16384) ? (int)remll : 16384;
    int is64 = (*nz == 0);
    for (int i = t; i < 1024; i += 256) lhist[i] = 0;
    __syncthreads();
    if (rem == 16384) {
        for (int it = 0; it < 8; ++it) {
            long long base = tile + (long long)it * 2048 + (long long)t * 8;
            int d[8];
            if (is64) {
                const long long* p = (const long long*)ei + base;
#pragma unroll
                for (int k = 0; k < 4; ++k) {
                    longlong2 v = ((const longlong2*)p)[k];
                    d[2 * k] = (int)v.x;
                    d[2 * k + 1] = (int)v.y;
                }
            } else {
                const int* p = (const int*)ei + base;
                int4 a = ((const int4*)p)[0];
                int4 bb = ((const int4*)p)[1];
                d[0] = a.x; d[1] = a.y; d[2] = a.z; d[3] = a.w;
                d[4] = bb.x; d[5] = bb.y; d[6] = bb.z; d[7] = bb.w;
            }
#pragma unroll
            for (int k = 0; k < 8; ++k)
                if ((unsigned)d[k] < (unsigned)N) atomicAdd(&lhist[d[k] >> 7], 1);
        }
    } else {
        for (int idx = t; idx < rem; idx += 256) {
            int d = load_idx(ei, tile + idx, is64);
            if ((unsigned)d < (unsigned)N) atomicAdd(&lhist[d >> 7], 1);
        }
    }
    __syncthreads();
    for (int b = t; b < 1024; b += 256) {
        int c = lhist[b];
        if (c > 0 && b < nbuckets) atomicAdd(&btot16[b * 16], c);
    }
}

// fine exclusive scan -> boff, cur16; also coarse cursor init curC16.
__global__ void k_scan(const int* __restrict__ btot16, int* __restrict__ boff,
                       int* __restrict__ cur16, int* __restrict__ curC16, int nbuckets) {
    __shared__ int sm[1024];
    int t = threadIdx.x;
    int v = (t < nbuckets) ? btot16[t * 16] : 0;
    sm[t] = v;
    __syncthreads();
    for (int s = 1; s < 1024; s <<= 1) {
        int x = (t >= s) ? sm[t - s] : 0;
        __syncthreads();
        sm[t] += x;
        __syncthreads();
    }
    if (t < nbuckets) {
        int excl = sm[t] - v;
        boff[t] = excl;
        cur16[t * 16] = excl;
        if ((t & 63) == 0) curC16[(t >> 6) * 16] = excl;
    }
    if (t == nbuckets - 1) boff[nbuckets] = sm[t];
}

// Level-1 scatter: raw edges -> coarse-sorted sedge1 (<=16 bins, long runs).
__global__ void __launch_bounds__(256) k_cscatter(const void* __restrict__ ei,
                                                  const float* __restrict__ ew,
                                                  int* __restrict__ curC16,
                                                  int2* __restrict__ sedge1,
                                                  const int* __restrict__ nz,
                                                  int E, int N, int ncoarse) {
    __shared__ int2 stage[2048];
    __shared__ unsigned char binOf[2048];
    __shared__ int hist[16];
    __shared__ int excl[16];
    __shared__ int gbase[16];
    int t = threadIdx.x;
    long long tile = (long long)blockIdx.x * 2048;
    long long remll = (long long)E - tile;
    int rem = (remll < 2048) ? (int)remll : 2048;
    int is64 = (*nz == 0);
    if (t < 16) hist[t] = 0;
    __syncthreads();

    int dd[8], nn[8];
    float ww[8];
    int cnt8 = 0;
    if (rem == 2048) {
        if (is64) {
            const long long* pd = (const long long*)ei + tile + (long long)t * 8;
            const long long* pn = (const long long*)ei + (long long)E + tile + (long long)t * 8;
#pragma unroll
            for (int k = 0; k < 4; ++k) {
                longlong2 vd = ((const longlong2*)pd)[k];
                longlong2 vn = ((const longlong2*)pn)[k];
                dd[2 * k] = (int)vd.x; dd[2 * k + 1] = (int)vd.y;
                nn[2 * k] = (int)vn.x; nn[2 * k + 1] = (int)vn.y;
            }
        } else {
            const int* pd = (const int*)ei + tile + (long long)t * 8;
            const int* pn = (const int*)ei + (long long)E + tile + (long long)t * 8;
            int4 a = ((const int4*)pd)[0], b = ((const int4*)pd)[1];
            int4 c = ((const int4*)pn)[0], d = ((const int4*)pn)[1];
            dd[0] = a.x; dd[1] = a.y; dd[2] = a.z; dd[3] = a.w;
            dd[4] = b.x; dd[5] = b.y; dd[6] = b.z; dd[7] = b.w;
            nn[0] = c.x; nn[1] = c.y; nn[2] = c.z; nn[3] = c.w;
            nn[4] = d.x; nn[5] = d.y; nn[6] = d.z; nn[7] = d.w;
        }
        const float* pw = ew + tile + (long long)t * 8;
        float4 wa = ((const float4*)pw)[0], wb = ((const float4*)pw)[1];
        ww[0] = wa.x; ww[1] = wa.y; ww[2] = wa.z; ww[3] = wa.w;
        ww[4] = wb.x; ww[5] = wb.y; ww[6] = wb.z; ww[7] = wb.w;
        cnt8 = 8;
    } else {
        int base = t * 8;
#pragma unroll
        for (int k = 0; k < 8; ++k) {
            int idx = base + k;
            if (idx < rem) {
                long long e = tile + idx;
                dd[cnt8] = load_idx(ei, e, is64);
                nn[cnt8] = load_idx(ei, (long long)E + e, is64);
                ww[cnt8] = ew[e];
                ++cnt8;
            }
        }
    }

    int mybin[8], myrank[8];
    int2 mypay[8];
#pragma unroll
    for (int k = 0; k < 8; ++k) {
        mybin[k] = -1;
        if (k < cnt8) {
            int d = dd[k];
            if ((unsigned)d < (unsigned)N) {
                int n = nn[k];
                if ((unsigned)n >= (unsigned)N) n = N;  // sentinel; filtered later
                int cb = d >> 13;
                mybin[k] = cb;
                myrank[k] = atomicAdd(&hist[cb], 1);
                mypay[k].x = (n << 13) | (d & 8191);
                mypay[k].y = __float_as_int(ww[k]);
            }
        }
    }
    __syncthreads();
    if (t == 0) {
        int run = 0;
#pragma unroll
        for (int c = 0; c < 16; ++c) { excl[c] = run; run += hist[c]; }
    }
    __syncthreads();
#pragma unroll
    for (int k = 0; k < 8; ++k) {
        if (mybin[k] >= 0) {
            int lpos = excl[mybin[k]] + myrank[k];
            stage[lpos] = mypay[k];
            binOf[lpos] = (unsigned char)mybin[k];
        }
    }
    if (t < 16) {
        int c = hist[t];
        gbase[t] = (c > 0 && t < ncoarse) ? atomicAdd(&curC16[t * 16], c) : 0;
    }
    __syncthreads();
    int total = excl[15] + hist[15];
    for (int lpos = t; lpos < total; lpos += 256) {
        int c = binOf[lpos];
        sedge1[gbase[c] + (lpos - excl[c])] = stage[lpos];
    }
}

// Level-2 scatter: coarse-sorted sedge1 -> fine-sorted sedge2 (repacks payload).
__global__ void __launch_bounds__(256) k_fscatter(const int2* __restrict__ sedge1,
                                                  int* __restrict__ cur16,
                                                  const int* __restrict__ boff,
                                                  int2* __restrict__ sedge2,
                                                  int E, int nbuckets, int ncoarse) {
    __shared__ int2 stage[2048];
    __shared__ unsigned short binOf[2048];
    __shared__ int lhist[1024];
    __shared__ int lincl[1024];
    __shared__ int gbase[1024];
    __shared__ int co[17];
    int t = threadIdx.x;
    if (t <= ncoarse) {
        int f = t * 64;
        if (f > nbuckets) f = nbuckets;
        co[t] = boff[f];
    }
    for (int i = t; i < 1024; i += 256) lhist[i] = 0;
    __syncthreads();
    int Ev = co[ncoarse];
    long long tile = (long long)blockIdx.x * 2048;
    if (tile >= Ev) return;
    long long remll = (long long)Ev - tile;
    int rem = (remll < 2048) ? (int)remll : 2048;

    int2 pay[8];
    int cnt8 = 0;
    if (rem == 2048) {
        const int4* p4 = (const int4*)(sedge1 + tile + (long long)t * 8);
#pragma unroll
        for (int k = 0; k < 4; ++k) {
            int4 v = p4[k];
            pay[2 * k].x = v.x; pay[2 * k].y = v.y;
            pay[2 * k + 1].x = v.z; pay[2 * k + 1].y = v.w;
        }
        cnt8 = 8;
    } else {
        int base = t * 8;
#pragma unroll
        for (int k = 0; k < 8; ++k) {
            int idx = base + k;
            if (idx < rem) pay[cnt8++] = sedge1[tile + idx];
        }
    }

    int mybin[8], myrank[8];
    int2 mypay[8];
#pragma unroll
    for (int k = 0; k < 8; ++k) {
        mybin[k] = -1;
        if (k < cnt8) {
            long long pos = tile + t * 8 + k;
            int c = 0;
            while (c + 1 < ncoarse && pos >= co[c + 1]) ++c;
            int x1 = pay[k].x;
            unsigned nbr = ((unsigned)x1) >> 13;
            int fin = c * 64 + ((x1 & 8191) >> 7);
            mybin[k] = fin;
            myrank[k] = atomicAdd(&lhist[fin], 1);
            mypay[k].x = (int)((nbr << 7) | (unsigned)(x1 & 127));
            mypay[k].y = pay[k].y;
        }
    }
    __syncthreads();
    for (int i = t; i < 1024; i += 256) lincl[i] = lhist[i];
    __syncthreads();
    for (int s = 1; s < 1024; s <<= 1) {
        int tmp[4];
#pragma unroll
        for (int j = 0; j < 4; ++j) {
            int i = (j << 8) + t;
            tmp[j] = (i >= s) ? lincl[i - s] : 0;
        }
        __syncthreads();
#pragma unroll
        for (int j = 0; j < 4; ++j) {
            int i = (j << 8) + t;
            lincl[i] += tmp[j];
        }
        __syncthreads();
    }
#pragma unroll
    for (int k = 0; k < 8; ++k) {
        if (mybin[k] >= 0) {
            int ex = lincl[mybin[k]] - lhist[mybin[k]];
            int lpos = ex + myrank[k];
            stage[lpos] = mypay[k];
            binOf[lpos] = (unsigned short)mybin[k];
        }
    }
    __syncthreads();
    for (int bb = t; bb < 1024; bb += 256) {
        int c = lhist[bb];
        gbase[bb] = (c > 0 && bb < nbuckets) ? atomicAdd(&cur16[bb * 16], c) : 0;
    }
    __syncthreads();
    int total = lincl[1023];
    for (int lpos = t; lpos < total; lpos += 256) {
        int bb = binOf[lpos];
        int ex = lincl[bb] - lhist[bb];
        sedge2[gbase[bb] + (lpos - ex)] = stage[lpos];
    }
}

// Single-level scatter (fallback when ws can't hold two edge buffers).
__global__ void __launch_bounds__(256) k_binscatter(const void* __restrict__ ei,
                                                    const float* __restrict__ ew,
                                                    int* __restrict__ cur16,
                                                    int2* __restrict__ sedge,
                                                    const int* __restrict__ nz,
                                                    int E, int N, int nbuckets) {
    __shared__ int2 stage[2048];
    __shared__ unsigned short binOf[2048];
    __shared__ int lhist[1024];
    __shared__ int lincl[1024];
    __shared__ int gbase[1024];
    int t = threadIdx.x;
    long long tile = (long long)blockIdx.x * 2048;
    long long remll = (long long)E - tile;
    int rem = (remll < 2048) ? (int)remll : 2048;
    int is64 = (*nz == 0);
    for (int i = t; i < 1024; i += 256) lhist[i] = 0;
    __syncthreads();

    int dd[8], nn[8];
    float ww[8];
    int cnt8 = 0;
    if (rem == 2048) {
        if (is64) {
            const long long* pd = (const long long*)ei + tile + (long long)t * 8;
            const long long* pn = (const long long*)ei + (long long)E + tile + (long long)t * 8;
#pragma unroll
            for (int k = 0; k < 4; ++k) {
                longlong2 vd = ((const longlong2*)pd)[k];
                longlong2 vn = ((const longlong2*)pn)[k];
                dd[2 * k] = (int)vd.x; dd[2 * k + 1] = (int)vd.y;
                nn[2 * k] = (int)vn.x; nn[2 * k + 1] = (int)vn.y;
            }
        } else {
            const int* pd = (const int*)ei + tile + (long long)t * 8;
            const int* pn = (const int*)ei + (long long)E + tile + (long long)t * 8;
            int4 a = ((const int4*)pd)[0], b = ((const int4*)pd)[1];
            int4 c = ((const int4*)pn)[0], d = ((const int4*)pn)[1];
            dd[0] = a.x; dd[1] = a.y; dd[2] = a.z; dd[3] = a.w;
            dd[4] = b.x; dd[5] = b.y; dd[6] = b.z; dd[7] = b.w;
            nn[0] = c.x; nn[1] = c.y; nn[2] = c.z; nn[3] = c.w;
            nn[4] = d.x; nn[5] = d.y; nn[6] = d.z; nn[7] = d.w;
        }
        const float* pw = ew + tile + (long long)t * 8;
        float4 wa = ((const float4*)pw)[0], wb = ((const float4*)pw)[1];
        ww[0] = wa.x; ww[1] = wa.y; ww[2] = wa.z; ww[3] = wa.w;
        ww[4] = wb.x; ww[5] = wb.y; ww[6] = wb.z; ww[7] = wb.w;
        cnt8 = 8;
    } else {
        int base = t * 8;
#pragma unroll
        for (int k = 0; k < 8; ++k) {
            int idx = base + k;
            if (idx < rem) {
                long long e = tile + idx;
                dd[cnt8] = load_idx(ei, e, is64);
                nn[cnt8] = load_idx(ei, (long long)E + e, is64);
                ww[cnt8] = ew[e];
                ++cnt8;
            }
        }
    }

    int mybin[8];
    int myrank[8];
    int2 mypay[8];
#pragma unroll
    for (int k = 0; k < 8; ++k) {
        mybin[k] = -1;
        if (k < cnt8) {
            int d = dd[k];
            if ((unsigned)d < (unsigned)N) {
                int n = nn[k];
                if ((unsigned)n >= (unsigned)N) n = N;  // sentinel
                int bb = d >> 7;
                mybin[k] = bb;
                myrank[k] = atomicAdd(&lhist[bb], 1);
                mypay[k].x = (n << 7) | (d & 127);
                mypay[k].y = __float_as_int(ww[k]);
            }
        }
    }
    __syncthreads();
    for (int i = t; i < 1024; i += 256) lincl[i] = lhist[i];
    __syncthreads();
    for (int s = 1; s < 1024; s <<= 1) {
        int tmp[4];
#pragma unroll
        for (int j = 0; j < 4; ++j) {
            int i = (j << 8) + t;
            tmp[j] = (i >= s) ? lincl[i - s] : 0;
        }
        __syncthreads();
#pragma unroll
        for (int j = 0; j < 4; ++j) {
            int i = (j << 8) + t;
            lincl[i] += tmp[j];
        }
        __syncthreads();
    }
#pragma unroll
    for (int k = 0; k < 8; ++k) {
        if (mybin[k] >= 0) {
            int ex = lincl[mybin[k]] - lhist[mybin[k]];
            int lpos = ex + myrank[k];
            stage[lpos] = mypay[k];
            binOf[lpos] = (unsigned short)mybin[k];
        }
    }
    __syncthreads();
    for (int bb = t; bb < 1024; bb += 256) {
        int c = lhist[bb];
        gbase[bb] = (c > 0 && bb < nbuckets) ? atomicAdd(&cur16[bb * 16], c) : 0;
    }
    __syncthreads();
    int total = lincl[1023];
    for (int lpos = t; lpos < total; lpos += 256) {
        int bb = binOf[lpos];
        int ex = lincl[bb] - lhist[bb];
        sedge[gbase[bb] + (lpos - ex)] = stage[lpos];
    }
}

// Per-bucket in-LDS counting sort to exact node order; writes node-sorted
// edges back IN PLACE and emits per-node (start,count) segments.
__global__ void __launch_bounds__(256) k_sort(const int* __restrict__ boff,
                                              int2* __restrict__ sedge,
                                              int2* __restrict__ nseg) {
    __shared__ int2 sorted[kCap];
    __shared__ int hist[128];
    __shared__ int scanbuf[128];
    __shared__ int offs[128];
    __shared__ int cur[128];
    int b = blockIdx.x, t = threadIdx.x;
    int e0 = boff[b], e1 = boff[b + 1];
    int cnt = e1 - e0;
    if (t < 128) hist[t] = 0;
    __syncthreads();
    if (cnt <= kCap) {
        for (int i = t; i < cnt; i += 256)
            atomicAdd(&hist[sedge[e0 + i].x & 127], 1);
        __syncthreads();
        if (t < 128) scanbuf[t] = hist[t];
        __syncthreads();
        for (int s = 1; s < 128; s <<= 1) {
            int v = 0;
            if (t < 128 && t >= s) v = scanbuf[t - s];
            __syncthreads();
            if (t < 128) scanbuf[t] += v;
            __syncthreads();
        }
        if (t < 128) {
            int ex = scanbuf[t] - hist[t];
            offs[t] = ex;
            cur[t] = ex;
        }
        __syncthreads();
        for (int i = t; i < cnt; i += 256) {
            int2 p = sedge[e0 + i];
            int r = atomicAdd(&cur[p.x & 127], 1);
            sorted[r] = p;
        }
        __syncthreads();
        for (int i = t; i < cnt; i += 256) sedge[e0 + i] = sorted[i];
        if (t < 128) nseg[b * 128 + t] = make_int2(e0 + offs[t], hist[t]);
    } else {
        if (t < 128) nseg[b * 128 + t] = make_int2(e0, -cnt);
    }
}

// 8 lanes per node; single fused 23-moment pass; fp64 Kabsch tail + per-node
// robust weight wnode = sigma2/(||R s + T - t||^2 + sigma2).
__global__ void __launch_bounds__(256) k_moment(const int2* __restrict__ nseg,
                                                const int2* __restrict__ sedge,
                                                const float4* __restrict__ s4,
                                                const float4* __restrict__ t4,
                                                float* __restrict__ Rout,
                                                float* __restrict__ Tout,
                                                float* __restrict__ wnode, int N) {
    __shared__ float acc[23][128];
    int b = blockIdx.x, t = threadIdx.x;
    int oct = t >> 3, lane8 = t & 7;
    for (int node = oct; node < 128; node += 32) {
        int2 seg = nseg[b * 128 + node];
        float v[23];
#pragma unroll
        for (int i = 0; i < 23; ++i) v[i] = 0.0f;
        int start = seg.x;
        int cn = seg.y;
        int total = (cn >= 0) ? cn : -cn;
        int filter = (cn < 0);
        for (int j = lane8; j < total; j += 8) {
            int2 p = sedge[start + j];
            if (filter && (p.x & 127) != node) continue;
            unsigned n = ((unsigned)p.x) >> 7;
            if (n >= (unsigned)N) continue;
            float w = __int_as_float(p.y);
            float4 a = s4[n];
            float4 bb = t4[n];
            float sx = a.x, sy = a.y, sz = a.z;
            float tx = bb.x, ty = bb.y, tz = bb.z;
            v[0] += 1.0f;
            v[1] += sx; v[2] += sy; v[3] += sz;
            v[4] += tx; v[5] += ty; v[6] += tz;
            v[7] += w;
            float wsx = w * sx, wsy = w * sy, wsz = w * sz;
            v[8] += wsx; v[9] += wsy; v[10] += wsz;
            v[11] += w * tx; v[12] += w * ty; v[13] += w * tz;
            v[14] += wsx * tx; v[15] += wsx * ty; v[16] += wsx * tz;
            v[17] += wsy * tx; v[18] += wsy * ty; v[19] += wsy * tz;
            v[20] += wsz * tx; v[21] += wsz * ty; v[22] += wsz * tz;
        }
#pragma unroll
        for (int m = 1; m < 8; m <<= 1) {
#pragma unroll
            for (int i = 0; i < 23; ++i) v[i] += __shfl_xor(v[i], m, 64);
        }
        if (lane8 == 0) {
#pragma unroll
            for (int i = 0; i < 23; ++i) acc[i][node] = v[i];
        }
    }
    __syncthreads();
    if (t < 128) {
        long long i = (long long)b * 128 + t;
        if (i < N) {
            double cntv = (double)acc[0][t];
            double inv = 1.0 / fmax(cntv, 1.0);
            double sb0 = acc[1][t] * inv, sb1 = acc[2][t] * inv, sb2 = acc[3][t] * inv;
            double tb0 = acc[4][t] * inv, tb1 = acc[5][t] * inv, tb2 = acc[6][t] * inv;
            double Sw = acc[7][t];
            double Sws[3] = {acc[8][t], acc[9][t], acc[10][t]};
            double Swt[3] = {acc[11][t], acc[12][t], acc[13][t]};
            double sb[3] = {sb0, sb1, sb2}, tb[3] = {tb0, tb1, tb2};
            double M[3][3];
#pragma unroll
            for (int r = 0; r < 3; ++r)
#pragma unroll
                for (int c = 0; c < 3; ++c)
                    M[r][c] = (double)acc[14 + 3 * r + c][t]
                            - sb[r] * Swt[c] - Sws[r] * tb[c] + Sw * sb[r] * tb[c];
            double Rm[3][3];
            kabsch_from_M(M, Rm);
            double T0 = tb0 - (Rm[0][0] * sb0 + Rm[0][1] * sb1 + Rm[0][2] * sb2);
            double T1 = tb1 - (Rm[1][0] * sb0 + Rm[1][1] * sb1 + Rm[1][2] * sb2);
            double T2 = tb2 - (Rm[2][0] * sb0 + Rm[2][1] * sb1 + Rm[2][2] * sb2);
#pragma unroll
            for (int r = 0; r < 3; ++r)
#pragma unroll
                for (int c = 0; c < 3; ++c)
                    Rout[9 * i + 3 * r + c] = (float)Rm[r][c];
            Tout[3 * i + 0] = (float)T0;
            Tout[3 * i + 1] = (float)T1;
            Tout[3 * i + 2] = (float)T2;
            // per-node robust weight
            float4 a = s4[(int)i];
            float4 q = t4[(int)i];
            double x0 = Rm[0][0] * a.x + Rm[0][1] * a.y + Rm[0][2] * a.z + T0;
            double x1 = Rm[1][0] * a.x + Rm[1][1] * a.y + Rm[1][2] * a.z + T1;
            double x2 = Rm[2][0] * a.x + Rm[2][1] * a.y + Rm[2][2] * a.z + T2;
            double d0 = x0 - q.x, d1 = x1 - q.y, d2 = x2 - q.z;
            double dd = d0 * d0 + d1 * d1 + d2 * d2;
            wnode[i] = (float)((double)kSigma2 / (dd + (double)kSigma2));
        }
    }
}

// wout[e] = wnode[nbr[e]] (8 edges/thread, vector loads, float4 stores).
__global__ void __launch_bounds__(256) k_wgather(const void* __restrict__ ei,
                                                 const float* __restrict__ wnode,
                                                 float* __restrict__ wout,
                                                 const int* __restrict__ nz,
                                                 int E, int N) {
    int gid = blockIdx.x * blockDim.x + threadIdx.x;
    long long base = (long long)gid * 8;
    if (base >= E) return;
    int is64 = (*nz == 0);
    int n_[8];
    int full = (base + 8 <= (long long)E);
    if (full) {
        if (is64) {
            const long long* p = (const long long*)ei + (long long)E + base;
#pragma unroll
            for (int k = 0; k < 4; ++k) {
                longlong2 a = ((const longlong2*)p)[k];
                n_[2 * k] = (int)a.x;
                n_[2 * k + 1] = (int)a.y;
            }
        } else {
            const int* p = (const int*)ei + (long long)E + base;
            int4 a = ((const int4*)p)[0];
            int4 b = ((const int4*)p)[1];
            n_[0] = a.x; n_[1] = a.y; n_[2] = a.z; n_[3] = a.w;
            n_[4] = b.x; n_[5] = b.y; n_[6] = b.z; n_[7] = b.w;
        }
        float w[8];
#pragma unroll
        for (int k = 0; k < 8; ++k)
            w[k] = ((unsigned)n_[k] < (unsigned)N) ? wnode[n_[k]] : 1.0f;
        *(float4*)(wout + base) = make_float4(w[0], w[1], w[2], w[3]);
        *(float4*)(wout + base + 4) = make_float4(w[4], w[5], w[6], w[7]);
    } else {
#pragma unroll
        for (int k = 0; k < 8; ++k) {
            long long e = base + k;
            if (e < E) {
                int n = load_idx(ei, (long long)E + e, is64);
                wout[e] = ((unsigned)n < (unsigned)N) ? wnode[n] : 1.0f;
            }
        }
    }
}

// ---------------- fallback atomic path ----------------

__global__ void k_accum1(const void* __restrict__ ei, const float* __restrict__ src,
                         const float* __restrict__ tgt, float* __restrict__ cnt,
                         float* __restrict__ ssum, float* __restrict__ tsum,
                         const int* __restrict__ nz, int E, int N) {
    int e = blockIdx.x * blockDim.x + threadIdx.x;
    if (e >= E) return;
    int is64 = (*nz == 0);
    int d = load_idx(ei, e, is64);
    int n = load_idx(ei, (long long)E + e, is64);
    if ((unsigned)d >= (unsigned)N || (unsigned)n >= (unsigned)N) return;
    atomicAdd(&cnt[d], 1.0f);
    atomicAdd(&ssum[3 * d + 0], src[3 * n + 0]);
    atomicAdd(&ssum[3 * d + 1], src[3 * n + 1]);
    atomicAdd(&ssum[3 * d + 2], src[3 * n + 2]);
    atomicAdd(&tsum[3 * d + 0], tgt[3 * n + 0]);
    atomicAdd(&tsum[3 * d + 1], tgt[3 * n + 1]);
    atomicAdd(&tsum[3 * d + 2], tgt[3 * n + 2]);
}

__global__ void k_centers(float* __restrict__ cnt, float* __restrict__ ssum,
                          float* __restrict__ tsum, int N) {
    int i = blockIdx.x * blockDim.x + threadIdx.x;
    if (i >= N) return;
    float inv = 1.0f / fmaxf(cnt[i], 1.0f);
    ssum[3 * i + 0] *= inv; ssum[3 * i + 1] *= inv; ssum[3 * i + 2] *= inv;
    tsum[3 * i + 0] *= inv; tsum[3 * i + 1] *= inv; tsum[3 * i + 2] *= inv;
}

__global__ void k_accum2(const void* __restrict__ ei, const float* __restrict__ src,
                         const float* __restrict__ tgt, const float* __restrict__ ew,
                         const float* __restrict__ sc, const float* __restrict__ tc,
                         float* __restrict__ Mm, const int* __restrict__ nz, int E, int N) {
    int e = blockIdx.x * blockDim.x + threadIdx.x;
    if (e >= E) return;
    int is64 = (*nz == 0);
    int d = load_idx(ei, e, is64);
    int n = load_idx(ei, (long long)E + e, is64);
    if ((unsigned)d >= (unsigned)N || (unsigned)n >= (unsigned)N) return;
    float w = ew[e];
    float a0 = (src[3 * n + 0] - sc[3 * d + 0]) * w;
    float a1 = (src[3 * n + 1] - sc[3 * d + 1]) * w;
    float a2 = (src[3 * n + 2] - sc[3 * d + 2]) * w;
    float b0 = tgt[3 * n + 0] - tc[3 * d + 0];
    float b1 = tgt[3 * n + 1] - tc[3 * d + 1];
    float b2 = tgt[3 * n + 2] - tc[3 * d + 2];
    float* Md = Mm + 9 * (long long)d;
    atomicAdd(Md + 0, a0 * b0); atomicAdd(Md + 1, a0 * b1); atomicAdd(Md + 2, a0 * b2);
    atomicAdd(Md + 3, a1 * b0); atomicAdd(Md + 4, a1 * b1); atomicAdd(Md + 5, a1 * b2);
    atomicAdd(Md + 6, a2 * b0); atomicAdd(Md + 7, a2 * b1); atomicAdd(Md + 8, a2 * b2);
}

__global__ void k_kabsch(const float* __restrict__ Mm, const float* __restrict__ sc,
                         const float* __restrict__ tc, float* __restrict__ Rout,
                         float* __restrict__ Tout, int N) {
    int i = blockIdx.x * blockDim.x + threadIdx.x;
    if (i >= N) return;
    double M[3][3];
#pragma unroll
    for (int r = 0; r < 3; ++r)
#pragma unroll
        for (int c = 0; c < 3; ++c)
            M[r][c] = (double)Mm[9 * (long long)i + 3 * r + c];
    double Rm[3][3];
    kabsch_from_M(M, Rm);
    double s0 = sc[3 * i + 0], s1 = sc[3 * i + 1], s2 = sc[3 * i + 2];
    double t0 = tc[3 * i + 0], t1 = tc[3 * i + 1], t2 = tc[3 * i + 2];
#pragma unroll
    for (int r = 0; r < 3; ++r)
#pragma unroll
        for (int c = 0; c < 3; ++c)
            Rout[9 * (long long)i + 3 * r + c] = (float)Rm[r][c];
    Tout[3 * i + 0] = (float)(t0 - (Rm[0][0] * s0 + Rm[0][1] * s1 + Rm[0][2] * s2));
    Tout[3 * i + 1] = (float)(t1 - (Rm[1][0] * s0 + Rm[1][1] * s1 + Rm[1][2] * s2));
    Tout[3 * i + 2] = (float)(t2 - (Rm[2][0] * s0 + Rm[2][1] * s1 + Rm[2][2] * s2));
}

__global__ void k_weights_plain(const void* __restrict__ ei,
                                const float* __restrict__ src,
                                const float* __restrict__ tgt,
                                const float* __restrict__ R,
                                const float* __restrict__ T,
                                float* __restrict__ wout,
                                const int* __restrict__ nz, int E, int N) {
    int e = blockIdx.x * blockDim.x + threadIdx.x;
    if (e >= E) return;
    int is64 = (*nz == 0);
    int n = load_idx(ei, (long long)E + e, is64);
    float w = 1.0f;
    if ((unsigned)n < (unsigned)N) {
        float p0 = src[3 * n + 0], p1 = src[3 * n + 1], p2 = src[3 * n + 2];
        float q0 = tgt[3 * n + 0], q1 = tgt[3 * n + 1], q2 = tgt[3 * n + 2];
        const float* Rn = R + 9 * (long long)n;
        const float* Tn = T + 3 * (long long)n;
        float x0 = Rn[0] * p0 + Rn[1] * p1 + Rn[2] * p2 + Tn[0];
        float x1 = Rn[3] * p0 + Rn[4] * p1 + Rn[5] * p2 + Tn[1];
        float x2 = Rn[6] * p0 + Rn[7] * p1 + Rn[8] * p2 + Tn[2];
        float d0 = x0 - q0, d1 = x1 - q1, d2 = x2 - q2;
        float dd = d0 * d0 + d1 * d1 + d2 * d2;
        w = kSigma2 / (dd + kSigma2);
    }
    wout[e] = w;
}

extern "C" void kernel_launch(void* const* d_in, const int* in_sizes, int n_in,
                              void* d_out, int out_size, void* d_ws, size_t ws_size,
                              hipStream_t stream) {
    const float* src = (const float*)d_in[0];
    const float* tgt = (const float*)d_in[1];
    const void* ei = d_in[2];
    const float* ew = (const float*)d_in[3];
    int N = in_sizes[0] / 3;
    int E = in_sizes[3];

    float* out = (float*)d_out;
    float* Rout = out;
    float* Tout = out + (size_t)9 * N;
    float* Wout = out + (size_t)12 * N;

    int eb = (E + 255) / 256;
    int nb = (N + 255) / 256;
    int nbuckets = (N + 127) / 128;
    int ncoarse = (nbuckets + 63) / 64;
    int tiles = (int)(((long long)E + 2047) / 2048);
    int tiles16 = (int)(((long long)E + 16383) / 16384);
    int wb8 = (int)(((long long)E + 2047) / 2048);

    // ws layout: [nz(16) | btot16 | cur16 | curC16(256) | boff | pad4 |
    //             sedge1 (E int2) | [sedge2 (E int2)] | s4 | t4 | wnode(N) | nseg]
    size_t ctrl_ints = 16 + (size_t)nbuckets * 16 * 2 + 256 + (nbuckets + 1);
    ctrl_ints = (ctrl_ints + 3) & ~(size_t)3;
    size_t after1 = ctrl_ints + 2 * (size_t)E;             // after sedge1
    after1 = (after1 + 3) & ~(size_t)3;
    size_t after2 = after1 + 2 * (size_t)E;                // after sedge2 (path A)
    after2 = (after2 + 3) & ~(size_t)3;
    size_t tail_ints = 8 * (size_t)N + (size_t)N + 2 * (size_t)128 * nbuckets;
    size_t needA = (after2 + tail_ints) * sizeof(int);
    size_t needB = (after1 + tail_ints) * sizeof(int);

    if (N <= 131072 && nbuckets <= 1024 && ws_size >= needB) {
        int twolevel = (ws_size >= needA) ? 1 : 0;
        int* nz = (int*)d_ws;
        int* btot16 = nz + 16;
        int* cur16 = btot16 + (size_t)nbuckets * 16;
        int* curC16 = cur16 + (size_t)nbuckets * 16;
        int* boff = curC16 + 256;
        int2* sedge1 = (int2*)((int*)d_ws + ctrl_ints);
        size_t tail_base = twolevel ? after2 : after1;
        int2* sedge2 = twolevel ? (int2*)((int*)d_ws + after1) : sedge1;
        float4* s4 = (float4*)((int*)d_ws + tail_base);
        float4* t4 = s4 + N;
        float* wnode = (float*)(t4 + N);
        int2* nseg = (int2*)(wnode + N);

        hipMemsetAsync(d_ws, 0, ctrl_ints * sizeof(int), stream);

        k_detect<<<1, 256, 0, stream>>>((const int*)ei, E, nz);
        k_pack<<<nb, 256, 0, stream>>>(src, tgt, s4, t4, N);
        k_bhist<<<tiles16, 256, 0, stream>>>(ei, btot16, nz, E, N, nbuckets);
        k_scan<<<1, 1024, 0, stream>>>(btot16, boff, cur16, curC16, nbuckets);
        if (twolevel) {
            k_cscatter<<<tiles, 256, 0, stream>>>(ei, ew, curC16, sedge1, nz, E, N, ncoarse);
            k_fscatter<<<tiles, 256, 0, stream>>>(sedge1, cur16, boff, sedge2, E, nbuckets, ncoarse);
        } else {
            k_binscatter<<<tiles, 256, 0, stream>>>(ei, ew, cur16, sedge2, nz, E, N, nbuckets);
        }
        k_sort<<<nbuckets, 256, 0, stream>>>(boff, sedge2, nseg);
        k_moment<<<nbuckets, 256, 0, stream>>>(nseg, sedge2, s4, t4, Rout, Tout, wnode, N);
        k_wgather<<<wb8, 256, 0, stream>>>(ei, wnode, Wout, nz, E, N);
    } else {
        // fallback: atomic path
        float* cnt = (float*)d_ws;
        float* ssum = cnt + N;
        float* tsum = ssum + 3 * (size_t)N;
        float* Mm = tsum + 3 * (size_t)N;
        int* nz = (int*)(Mm + 9 * (size_t)N);
        size_t ws_bytes = (size_t)16 * N * sizeof(float) + 16;
        hipMemsetAsync(d_ws, 0, ws_bytes, stream);
        k_detect<<<1, 256, 0, stream>>>((const int*)ei, E, nz);
        k_accum1<<<eb, 256, 0, stream>>>(ei, src, tgt, cnt, ssum, tsum, nz, E, N);
        k_centers<<<nb, 256, 0, stream>>>(cnt, ssum, tsum, N);
        k_accum2<<<eb, 256, 0, stream>>>(ei, src, tgt, ew, ssum, tsum, Mm, nz, E, N);
        k_kabsch<<<nb, 256, 0, stream>>>(Mm, ssum, tsum, Rout, Tout, N);
        k_weights_plain<<<eb, 256, 0, stream>>>(ei, src, tgt, Rout, Tout, Wout, nz, E, N);
    }
}

// Round 9
// 272.088 us; speedup vs baseline: 2.5199x; 1.0264x over previous
//
#include <hip/hip_runtime.h>
#include <math.h>

static constexpr float kSigma2 = 0.05f * 0.05f;
static constexpr int kCap = 6400;  // max edges per 128-node bucket in LDS sort

__device__ __forceinline__ int load_idx(const void* ei, long long j, int is64) {
    if (is64) return (int)(((const long long*)ei)[j]);
    return ((const int*)ei)[j];
}

// Detect whether edge_index is int64 (all odd int32 words zero) or int32.
__global__ void k_detect(const int* __restrict__ ei32, int E, int* __restrict__ nz) {
    int t = threadIdx.x;
    int lim = E < 2048 ? E : 2048;
    int acc = 0;
    for (int k = t; k < lim; k += blockDim.x) acc |= ei32[2 * k + 1];
    if (acc) atomicOr(nz, 1);
}

// Pack points into float4 arrays for vector gathers.
__global__ void k_pack(const float* __restrict__ src, const float* __restrict__ tgt,
                       float4* __restrict__ s4, float4* __restrict__ t4, int N) {
    int i = blockIdx.x * blockDim.x + threadIdx.x;
    if (i >= N) return;
    s4[i] = make_float4(src[3 * i + 0], src[3 * i + 1], src[3 * i + 2], 0.0f);
    t4[i] = make_float4(tgt[3 * i + 0], tgt[3 * i + 1], tgt[3 * i + 2], 0.0f);
}

// ---------------- shared Kabsch core (fp64, Jacobi on M^T M) ----------------
__device__ void kabsch_from_M(const double M[3][3], double Rm[3][3]) {
    Rm[0][0] = 1; Rm[0][1] = 0; Rm[0][2] = 0;
    Rm[1][0] = 0; Rm[1][1] = 1; Rm[1][2] = 0;
    Rm[2][0] = 0; Rm[2][1] = 0; Rm[2][2] = 1;

    double frob2 = 0.0;
#pragma unroll
    for (int r = 0; r < 3; ++r)
#pragma unroll
        for (int c = 0; c < 3; ++c) frob2 += M[r][c] * M[r][c];
    if (frob2 <= 1e-80) return;

    double A[3][3];
#pragma unroll
    for (int r = 0; r < 3; ++r)
#pragma unroll
        for (int c = 0; c < 3; ++c) {
            double s = 0.0;
#pragma unroll
            for (int k = 0; k < 3; ++k) s += M[k][r] * M[k][c];
            A[r][c] = s;
        }
    double V[3][3] = {{1, 0, 0}, {0, 1, 0}, {0, 0, 1}};
    const int PL[3] = {0, 0, 1};
    const int QL[3] = {1, 2, 2};
    for (int sweep = 0; sweep < 15; ++sweep) {
        double off = fabs(A[0][1]) + fabs(A[0][2]) + fabs(A[1][2]);
        if (off == 0.0) break;
        for (int pi = 0; pi < 3; ++pi) {
            int p = PL[pi], q = QL[pi], r3 = 3 - p - q;
            double apq = A[p][q];
            if (apq == 0.0) continue;
            double theta = (A[q][q] - A[p][p]) / (2.0 * apq);
            double t = copysign(1.0, theta) / (fabs(theta) + sqrt(theta * theta + 1.0));
            double c = 1.0 / sqrt(t * t + 1.0);
            double s = t * c;
            A[p][p] -= t * apq;
            A[q][q] += t * apq;
            A[p][q] = 0.0; A[q][p] = 0.0;
            double arp = A[r3][p], arq = A[r3][q];
            A[r3][p] = c * arp - s * arq; A[p][r3] = A[r3][p];
            A[r3][q] = s * arp + c * arq; A[q][r3] = A[r3][q];
#pragma unroll
            for (int k = 0; k < 3; ++k) {
                double vp = V[k][p], vq = V[k][q];
                V[k][p] = c * vp - s * vq;
                V[k][q] = s * vp + c * vq;
            }
        }
    }
    double lam[3] = {A[0][0], A[1][1], A[2][2]};
    int id0 = 0, id1 = 1, id2 = 2, tt;
    if (lam[id0] < lam[id1]) { tt = id0; id0 = id1; id1 = tt; }
    if (lam[id0] < lam[id2]) { tt = id0; id0 = id2; id2 = tt; }
    if (lam[id1] < lam[id2]) { tt = id1; id1 = id2; id2 = tt; }
    double v1[3] = {V[0][id0], V[1][id0], V[2][id0]};
    double v2[3] = {V[0][id1], V[1][id1], V[2][id1]};
    double v3[3] = {V[0][id2], V[1][id2], V[2][id2]};

    double b1[3], b2[3];
#pragma unroll
    for (int r = 0; r < 3; ++r) {
        b1[r] = M[r][0] * v1[0] + M[r][1] * v1[1] + M[r][2] * v1[2];
        b2[r] = M[r][0] * v2[0] + M[r][1] * v2[1] + M[r][2] * v2[2];
    }
    double n1 = sqrt(b1[0] * b1[0] + b1[1] * b1[1] + b1[2] * b1[2]);
    if (n1 <= 1e-150) return;
    double u1[3] = {b1[0] / n1, b1[1] / n1, b1[2] / n1};
    double dot = u1[0] * b2[0] + u1[1] * b2[1] + u1[2] * b2[2];
    double w2[3] = {b2[0] - dot * u1[0], b2[1] - dot * u1[1], b2[2] - dot * u1[2]};
    double n2 = sqrt(w2[0] * w2[0] + w2[1] * w2[1] + w2[2] * w2[2]);
    double u2[3];
    if (n2 > n1 * 1e-12) {
        u2[0] = w2[0] / n2; u2[1] = w2[1] / n2; u2[2] = w2[2] / n2;
    } else {
        double ex0 = (fabs(u1[0]) < 0.9) ? 1.0 : 0.0;
        double ex1 = 1.0 - ex0;
        double cx = u1[1] * 0.0 - u1[2] * ex1;
        double cy = u1[2] * ex0 - u1[0] * 0.0;
        double cz = u1[0] * ex1 - u1[1] * ex0;
        double cn = sqrt(cx * cx + cy * cy + cz * cz);
        u2[0] = cx / cn; u2[1] = cy / cn; u2[2] = cz / cn;
    }
    double u3[3] = {u1[1] * u2[2] - u1[2] * u2[1],
                    u1[2] * u2[0] - u1[0] * u2[2],
                    u1[0] * u2[1] - u1[1] * u2[0]};
    double dV = v1[0] * (v2[1] * v3[2] - v2[2] * v3[1])
              - v1[1] * (v2[0] * v3[2] - v2[2] * v3[0])
              + v1[2] * (v2[0] * v3[1] - v2[1] * v3[0]);
    dV = (dV >= 0.0) ? 1.0 : -1.0;
#pragma unroll
    for (int r = 0; r < 3; ++r)
#pragma unroll
        for (int c = 0; c < 3; ++c)
            Rm[r][c] = u1[r] * v1[c] + u2[r] * v2[c] + dV * u3[r] * v3[c];
}

// ---------------- bucketed counting-sort path ----------------
// fine bucket = dst >> 7 (128 nodes). final payload: x = (nbr<<7)|(dst&127), y = w bits.
// coarse bucket = dst >> 13 (64 fine buckets). intermediate payload:
//   x = (nbr<<13)|(dst&8191), y = w bits.

// 16384 edges per block (64/thread): amortizes the global-atomic histogram flush.
__global__ void __launch_bounds__(256) k_bhist(const void* __restrict__ ei,
                                               int* __restrict__ btot16,
                                               const int* __restrict__ nz,
                                               int E, int N, int nbuckets) {
    __shared__ int lhist[1024];
    int t = threadIdx.x;
    long long tile = (long long)blockIdx.x * 16384;
    long long remll = (long long)E - tile;
    int rem = (remll < 16384) ? (int)remll : 16384;
    int is64 = (*nz == 0);
    for (int i = t; i < 1024; i += 256) lhist[i] = 0;
    __syncthreads();
    if (rem == 16384) {
        for (int it = 0; it < 8; ++it) {
            long long base = tile + (long long)it * 2048 + (long long)t * 8;
            int d[8];
            if (is64) {
                const long long* p = (const long long*)ei + base;
#pragma unroll
                for (int k = 0; k < 4; ++k) {
                    longlong2 v = ((const longlong2*)p)[k];
                    d[2 * k] = (int)v.x;
                    d[2 * k + 1] = (int)v.y;
                }
            } else {
                const int* p = (const int*)ei + base;
                int4 a = ((const int4*)p)[0];
                int4 bb = ((const int4*)p)[1];
                d[0] = a.x; d[1] = a.y; d[2] = a.z; d[3] = a.w;
                d[4] = bb.x; d[5] = bb.y; d[6] = bb.z; d[7] = bb.w;
            }
#pragma unroll
            for (int k = 0; k < 8; ++k)
                if ((unsigned)d[k] < (unsigned)N) atomicAdd(&lhist[d[k] >> 7], 1);
        }
    } else {
        for (int idx = t; idx < rem; idx += 256) {
            int d = load_idx(ei, tile + idx, is64);
            if ((unsigned)d < (unsigned)N) atomicAdd(&lhist[d >> 7], 1);
        }
    }
    __syncthreads();
    for (int b = t; b < 1024; b += 256) {
        int c = lhist[b];
        if (c > 0 && b < nbuckets) atomicAdd(&btot16[b * 16], c);
    }
}

// fine exclusive scan -> boff, cur16; also coarse cursor init curC16.
__global__ void k_scan(const int* __restrict__ btot16, int* __restrict__ boff,
                       int* __restrict__ cur16, int* __restrict__ curC16, int nbuckets) {
    __shared__ int sm[1024];
    int t = threadIdx.x;
    int v = (t < nbuckets) ? btot16[t * 16] : 0;
    sm[t] = v;
    __syncthreads();
    for (int s = 1; s < 1024; s <<= 1) {
        int x = (t >= s) ? sm[t - s] : 0;
        __syncthreads();
        sm[t] += x;
        __syncthreads();
    }
    if (t < nbuckets) {
        int excl = sm[t] - v;
        boff[t] = excl;
        cur16[t * 16] = excl;
        if ((t & 63) == 0) curC16[(t >> 6) * 16] = excl;
    }
    if (t == nbuckets - 1) boff[nbuckets] = sm[t];
}

// Level-1 scatter: raw edges -> coarse-sorted sedge1 (<=16 bins, long runs).
__global__ void __launch_bounds__(256) k_cscatter(const void* __restrict__ ei,
                                                  const float* __restrict__ ew,
                                                  int* __restrict__ curC16,
                                                  int2* __restrict__ sedge1,
                                                  const int* __restrict__ nz,
                                                  int E, int N, int ncoarse) {
    __shared__ int2 stage[2048];
    __shared__ unsigned char binOf[2048];
    __shared__ int hist[16];
    __shared__ int excl[16];
    __shared__ int gbase[16];
    int t = threadIdx.x;
    long long tile = (long long)blockIdx.x * 2048;
    long long remll = (long long)E - tile;
    int rem = (remll < 2048) ? (int)remll : 2048;
    int is64 = (*nz == 0);
    if (t < 16) hist[t] = 0;
    __syncthreads();

    int dd[8], nn[8];
    float ww[8];
    int cnt8 = 0;
    if (rem == 2048) {
        if (is64) {
            const long long* pd = (const long long*)ei + tile + (long long)t * 8;
            const long long* pn = (const long long*)ei + (long long)E + tile + (long long)t * 8;
#pragma unroll
            for (int k = 0; k < 4; ++k) {
                longlong2 vd = ((const longlong2*)pd)[k];
                longlong2 vn = ((const longlong2*)pn)[k];
                dd[2 * k] = (int)vd.x; dd[2 * k + 1] = (int)vd.y;
                nn[2 * k] = (int)vn.x; nn[2 * k + 1] = (int)vn.y;
            }
        } else {
            const int* pd = (const int*)ei + tile + (long long)t * 8;
            const int* pn = (const int*)ei + (long long)E + tile + (long long)t * 8;
            int4 a = ((const int4*)pd)[0], b = ((const int4*)pd)[1];
            int4 c = ((const int4*)pn)[0], d = ((const int4*)pn)[1];
            dd[0] = a.x; dd[1] = a.y; dd[2] = a.z; dd[3] = a.w;
            dd[4] = b.x; dd[5] = b.y; dd[6] = b.z; dd[7] = b.w;
            nn[0] = c.x; nn[1] = c.y; nn[2] = c.z; nn[3] = c.w;
            nn[4] = d.x; nn[5] = d.y; nn[6] = d.z; nn[7] = d.w;
        }
        const float* pw = ew + tile + (long long)t * 8;
        float4 wa = ((const float4*)pw)[0], wb = ((const float4*)pw)[1];
        ww[0] = wa.x; ww[1] = wa.y; ww[2] = wa.z; ww[3] = wa.w;
        ww[4] = wb.x; ww[5] = wb.y; ww[6] = wb.z; ww[7] = wb.w;
        cnt8 = 8;
    } else {
        int base = t * 8;
#pragma unroll
        for (int k = 0; k < 8; ++k) {
            int idx = base + k;
            if (idx < rem) {
                long long e = tile + idx;
                dd[cnt8] = load_idx(ei, e, is64);
                nn[cnt8] = load_idx(ei, (long long)E + e, is64);
                ww[cnt8] = ew[e];
                ++cnt8;
            }
        }
    }

    int mybin[8], myrank[8];
    int2 mypay[8];
#pragma unroll
    for (int k = 0; k < 8; ++k) {
        mybin[k] = -1;
        if (k < cnt8) {
            int d = dd[k];
            if ((unsigned)d < (unsigned)N) {
                int n = nn[k];
                if ((unsigned)n >= (unsigned)N) n = N;  // sentinel; filtered later
                int cb = d >> 13;
                mybin[k] = cb;
                myrank[k] = atomicAdd(&hist[cb], 1);
                mypay[k].x = (n << 13) | (d & 8191);
                mypay[k].y = __float_as_int(ww[k]);
            }
        }
    }
    __syncthreads();
    if (t == 0) {
        int run = 0;
#pragma unroll
        for (int c = 0; c < 16; ++c) { excl[c] = run; run += hist[c]; }
    }
    __syncthreads();
#pragma unroll
    for (int k = 0; k < 8; ++k) {
        if (mybin[k] >= 0) {
            int lpos = excl[mybin[k]] + myrank[k];
            stage[lpos] = mypay[k];
            binOf[lpos] = (unsigned char)mybin[k];
        }
    }
    if (t < 16) {
        int c = hist[t];
        gbase[t] = (c > 0 && t < ncoarse) ? atomicAdd(&curC16[t * 16], c) : 0;
    }
    __syncthreads();
    int total = excl[15] + hist[15];
    for (int lpos = t; lpos < total; lpos += 256) {
        int c = binOf[lpos];
        sedge1[gbase[c] + (lpos - excl[c])] = stage[lpos];
    }
}

// Level-2 scatter: coarse-sorted sedge1 -> fine-sorted sedge2 (repacks payload).
// Windowed ranking: a tile spans few coarse buckets; rank bins relative to clo.
__global__ void __launch_bounds__(256) k_fscatter(const int2* __restrict__ sedge1,
                                                  int* __restrict__ cur16,
                                                  const int* __restrict__ boff,
                                                  int2* __restrict__ sedge2,
                                                  int E, int nbuckets, int ncoarse) {
    __shared__ int2 stage[2048];
    __shared__ unsigned short binOf[2048];
    __shared__ int lhist[1024];
    __shared__ int lincl[1024];
    __shared__ int gbase[1024];
    __shared__ int co[17];
    __shared__ int s_clo, s_W;
    int t = threadIdx.x;
    if (t <= ncoarse) {
        int f = t * 64;
        if (f > nbuckets) f = nbuckets;
        co[t] = boff[f];
    }
    __syncthreads();
    int Ev = co[ncoarse];
    long long tile = (long long)blockIdx.x * 2048;
    if (tile >= Ev) return;
    long long remll = (long long)Ev - tile;
    int rem = (remll < 2048) ? (int)remll : 2048;

    if (t == 0) {
        long long p0 = tile, p1 = tile + rem - 1;
        int c0 = 0;
        while (c0 + 1 < ncoarse && p0 >= co[c0 + 1]) ++c0;
        int c1 = c0;
        while (c1 + 1 < ncoarse && p1 >= co[c1 + 1]) ++c1;
        s_clo = c0;
        s_W = (c1 - c0 + 1) * 64;
    }
    __syncthreads();
    int clo = s_clo, W = s_W;
    for (int i = t; i < W; i += 256) lhist[i] = 0;
    __syncthreads();

    int2 pay[8];
    int cnt8 = 0;
    if (rem == 2048) {
        const int4* p4 = (const int4*)(sedge1 + tile + (long long)t * 8);
#pragma unroll
        for (int k = 0; k < 4; ++k) {
            int4 v = p4[k];
            pay[2 * k].x = v.x; pay[2 * k].y = v.y;
            pay[2 * k + 1].x = v.z; pay[2 * k + 1].y = v.w;
        }
        cnt8 = 8;
    } else {
        int base = t * 8;
#pragma unroll
        for (int k = 0; k < 8; ++k) {
            int idx = base + k;
            if (idx < rem) pay[cnt8++] = sedge1[tile + idx];
        }
    }

    int mybin[8], myrank[8];
    int2 mypay[8];
#pragma unroll
    for (int k = 0; k < 8; ++k) {
        mybin[k] = -1;
        if (k < cnt8) {
            long long pos = tile + t * 8 + k;
            int c = clo;
            while (c + 1 < ncoarse && pos >= co[c + 1]) ++c;
            int x1 = pay[k].x;
            unsigned nbr = ((unsigned)x1) >> 13;
            int rel = (c - clo) * 64 + ((x1 & 8191) >> 7);
            mybin[k] = rel;
            myrank[k] = atomicAdd(&lhist[rel], 1);
            mypay[k].x = (int)((nbr << 7) | (unsigned)(x1 & 127));
            mypay[k].y = pay[k].y;
        }
    }
    __syncthreads();
    for (int i = t; i < W; i += 256) lincl[i] = lhist[i];
    __syncthreads();
    for (int s = 1; s < W; s <<= 1) {
        int tmp[4];
        int cj = 0;
        for (int i = t; i < W; i += 256) tmp[cj++] = (i >= s) ? lincl[i - s] : 0;
        __syncthreads();
        cj = 0;
        for (int i = t; i < W; i += 256) lincl[i] += tmp[cj++];
        __syncthreads();
    }
#pragma unroll
    for (int k = 0; k < 8; ++k) {
        if (mybin[k] >= 0) {
            int ex = lincl[mybin[k]] - lhist[mybin[k]];
            int lpos = ex + myrank[k];
            stage[lpos] = mypay[k];
            binOf[lpos] = (unsigned short)mybin[k];
        }
    }
    __syncthreads();
    for (int rel = t; rel < W; rel += 256) {
        int c = lhist[rel];
        int fin = clo * 64 + rel;
        gbase[rel] = (c > 0 && fin < nbuckets) ? atomicAdd(&cur16[fin * 16], c) : 0;
    }
    __syncthreads();
    int total = lincl[W - 1];
    for (int lpos = t; lpos < total; lpos += 256) {
        int rel = binOf[lpos];
        int ex = lincl[rel] - lhist[rel];
        sedge2[gbase[rel] + (lpos - ex)] = stage[lpos];
    }
}

// Single-level scatter (fallback when ws can't hold two edge buffers).
__global__ void __launch_bounds__(256) k_binscatter(const void* __restrict__ ei,
                                                    const float* __restrict__ ew,
                                                    int* __restrict__ cur16,
                                                    int2* __restrict__ sedge,
                                                    const int* __restrict__ nz,
                                                    int E, int N, int nbuckets) {
    __shared__ int2 stage[2048];
    __shared__ unsigned short binOf[2048];
    __shared__ int lhist[1024];
    __shared__ int lincl[1024];
    __shared__ int gbase[1024];
    int t = threadIdx.x;
    long long tile = (long long)blockIdx.x * 2048;
    long long remll = (long long)E - tile;
    int rem = (remll < 2048) ? (int)remll : 2048;
    int is64 = (*nz == 0);
    for (int i = t; i < 1024; i += 256) lhist[i] = 0;
    __syncthreads();

    int dd[8], nn[8];
    float ww[8];
    int cnt8 = 0;
    if (rem == 2048) {
        if (is64) {
            const long long* pd = (const long long*)ei + tile + (long long)t * 8;
            const long long* pn = (const long long*)ei + (long long)E + tile + (long long)t * 8;
#pragma unroll
            for (int k = 0; k < 4; ++k) {
                longlong2 vd = ((const longlong2*)pd)[k];
                longlong2 vn = ((const longlong2*)pn)[k];
                dd[2 * k] = (int)vd.x; dd[2 * k + 1] = (int)vd.y;
                nn[2 * k] = (int)vn.x; nn[2 * k + 1] = (int)vn.y;
            }
        } else {
            const int* pd = (const int*)ei + tile + (long long)t * 8;
            const int* pn = (const int*)ei + (long long)E + tile + (long long)t * 8;
            int4 a = ((const int4*)pd)[0], b = ((const int4*)pd)[1];
            int4 c = ((const int4*)pn)[0], d = ((const int4*)pn)[1];
            dd[0] = a.x; dd[1] = a.y; dd[2] = a.z; dd[3] = a.w;
            dd[4] = b.x; dd[5] = b.y; dd[6] = b.z; dd[7] = b.w;
            nn[0] = c.x; nn[1] = c.y; nn[2] = c.z; nn[3] = c.w;
            nn[4] = d.x; nn[5] = d.y; nn[6] = d.z; nn[7] = d.w;
        }
        const float* pw = ew + tile + (long long)t * 8;
        float4 wa = ((const float4*)pw)[0], wb = ((const float4*)pw)[1];
        ww[0] = wa.x; ww[1] = wa.y; ww[2] = wa.z; ww[3] = wa.w;
        ww[4] = wb.x; ww[5] = wb.y; ww[6] = wb.z; ww[7] = wb.w;
        cnt8 = 8;
    } else {
        int base = t * 8;
#pragma unroll
        for (int k = 0; k < 8; ++k) {
            int idx = base + k;
            if (idx < rem) {
                long long e = tile + idx;
                dd[cnt8] = load_idx(ei, e, is64);
                nn[cnt8] = load_idx(ei, (long long)E + e, is64);
                ww[cnt8] = ew[e];
                ++cnt8;
            }
        }
    }

    int mybin[8];
    int myrank[8];
    int2 mypay[8];
#pragma unroll
    for (int k = 0; k < 8; ++k) {
        mybin[k] = -1;
        if (k < cnt8) {
            int d = dd[k];
            if ((unsigned)d < (unsigned)N) {
                int n = nn[k];
                if ((unsigned)n >= (unsigned)N) n = N;  // sentinel
                int bb = d >> 7;
                mybin[k] = bb;
                myrank[k] = atomicAdd(&lhist[bb], 1);
                mypay[k].x = (n << 7) | (d & 127);
                mypay[k].y = __float_as_int(ww[k]);
            }
        }
    }
    __syncthreads();
    for (int i = t; i < 1024; i += 256) lincl[i] = lhist[i];
    __syncthreads();
    for (int s = 1; s < 1024; s <<= 1) {
        int tmp[4];
#pragma unroll
        for (int j = 0; j < 4; ++j) {
            int i = (j << 8) + t;
            tmp[j] = (i >= s) ? lincl[i - s] : 0;
        }
        __syncthreads();
#pragma unroll
        for (int j = 0; j < 4; ++j) {
            int i = (j << 8) + t;
            lincl[i] += tmp[j];
        }
        __syncthreads();
    }
#pragma unroll
    for (int k = 0; k < 8; ++k) {
        if (mybin[k] >= 0) {
            int ex = lincl[mybin[k]] - lhist[mybin[k]];
            int lpos = ex + myrank[k];
            stage[lpos] = mypay[k];
            binOf[lpos] = (unsigned short)mybin[k];
        }
    }
    __syncthreads();
    for (int bb = t; bb < 1024; bb += 256) {
        int c = lhist[bb];
        gbase[bb] = (c > 0 && bb < nbuckets) ? atomicAdd(&cur16[bb * 16], c) : 0;
    }
    __syncthreads();
    int total = lincl[1023];
    for (int lpos = t; lpos < total; lpos += 256) {
        int bb = binOf[lpos];
        int ex = lincl[bb] - lhist[bb];
        sedge[gbase[bb] + (lpos - ex)] = stage[lpos];
    }
}

// Per-bucket in-LDS counting sort to exact node order; writes node-sorted
// edges back IN PLACE and emits per-node (start,count) segments.
__global__ void __launch_bounds__(256) k_sort(const int* __restrict__ boff,
                                              int2* __restrict__ sedge,
                                              int2* __restrict__ nseg) {
    __shared__ int2 sorted[kCap];
    __shared__ int hist[128];
    __shared__ int scanbuf[128];
    __shared__ int offs[128];
    __shared__ int cur[128];
    int b = blockIdx.x, t = threadIdx.x;
    int e0 = boff[b], e1 = boff[b + 1];
    int cnt = e1 - e0;
    if (t < 128) hist[t] = 0;
    __syncthreads();
    if (cnt <= kCap) {
        for (int i = t; i < cnt; i += 256)
            atomicAdd(&hist[sedge[e0 + i].x & 127], 1);
        __syncthreads();
        if (t < 128) scanbuf[t] = hist[t];
        __syncthreads();
        for (int s = 1; s < 128; s <<= 1) {
            int v = 0;
            if (t < 128 && t >= s) v = scanbuf[t - s];
            __syncthreads();
            if (t < 128) scanbuf[t] += v;
            __syncthreads();
        }
        if (t < 128) {
            int ex = scanbuf[t] - hist[t];
            offs[t] = ex;
            cur[t] = ex;
        }
        __syncthreads();
        for (int i = t; i < cnt; i += 256) {
            int2 p = sedge[e0 + i];
            int r = atomicAdd(&cur[p.x & 127], 1);
            sorted[r] = p;
        }
        __syncthreads();
        for (int i = t; i < cnt; i += 256) sedge[e0 + i] = sorted[i];
        if (t < 128) nseg[b * 128 + t] = make_int2(e0 + offs[t], hist[t]);
    } else {
        if (t < 128) nseg[b * 128 + t] = make_int2(e0, -cnt);
    }
}

// Moments only: 64 nodes per block, 8 lanes per node, no LDS.
// Writes 23 moments per node to SoA momG[k*N + n].
__global__ void __launch_bounds__(256) k_moment(const int2* __restrict__ nseg,
                                                const int2* __restrict__ sedge,
                                                const float4* __restrict__ s4,
                                                const float4* __restrict__ t4,
                                                float* __restrict__ momG, int N) {
    int b = blockIdx.x, t = threadIdx.x;
    int oct = t >> 3, lane8 = t & 7;
    int base = b * 64;
    for (int node = base + oct; node < base + 64; node += 32) {
        if (node >= N) break;
        int2 seg = nseg[node];
        float v[23];
#pragma unroll
        for (int i = 0; i < 23; ++i) v[i] = 0.0f;
        int start = seg.x;
        int cn = seg.y;
        int total = (cn >= 0) ? cn : -cn;
        int filter = (cn < 0);
        int nlow = node & 127;
        for (int j = lane8; j < total; j += 8) {
            int2 p = sedge[start + j];
            if (filter && (p.x & 127) != nlow) continue;
            unsigned n = ((unsigned)p.x) >> 7;
            if (n >= (unsigned)N) continue;
            float w = __int_as_float(p.y);
            float4 a = s4[n];
            float4 bb = t4[n];
            float sx = a.x, sy = a.y, sz = a.z;
            float tx = bb.x, ty = bb.y, tz = bb.z;
            v[0] += 1.0f;
            v[1] += sx; v[2] += sy; v[3] += sz;
            v[4] += tx; v[5] += ty; v[6] += tz;
            v[7] += w;
            float wsx = w * sx, wsy = w * sy, wsz = w * sz;
            v[8] += wsx; v[9] += wsy; v[10] += wsz;
            v[11] += w * tx; v[12] += w * ty; v[13] += w * tz;
            v[14] += wsx * tx; v[15] += wsx * ty; v[16] += wsx * tz;
            v[17] += wsy * tx; v[18] += wsy * ty; v[19] += wsy * tz;
            v[20] += wsz * tx; v[21] += wsz * ty; v[22] += wsz * tz;
        }
#pragma unroll
        for (int m = 1; m < 8; m <<= 1) {
#pragma unroll
            for (int i = 0; i < 23; ++i) v[i] += __shfl_xor(v[i], m, 64);
        }
        if (lane8 == 0) {
#pragma unroll
            for (int i = 0; i < 23; ++i) momG[(size_t)i * N + node] = v[i];
        }
    }
}

// One thread per node: expand moments -> M, fp64 Kabsch, R/T/wnode.
__global__ void __launch_bounds__(256) k_kabsch2(const float* __restrict__ momG,
                                                 const float4* __restrict__ s4,
                                                 const float4* __restrict__ t4,
                                                 float* __restrict__ Rout,
                                                 float* __restrict__ Tout,
                                                 float* __restrict__ wnode, int N) {
    int i = blockIdx.x * blockDim.x + threadIdx.x;
    if (i >= N) return;
    float m[23];
#pragma unroll
    for (int k = 0; k < 23; ++k) m[k] = momG[(size_t)k * N + i];
    double cntv = (double)m[0];
    double inv = 1.0 / fmax(cntv, 1.0);
    double sb[3] = {m[1] * inv, m[2] * inv, m[3] * inv};
    double tb[3] = {m[4] * inv, m[5] * inv, m[6] * inv};
    double Sw = m[7];
    double Sws[3] = {m[8], m[9], m[10]};
    double Swt[3] = {m[11], m[12], m[13]};
    double M[3][3];
#pragma unroll
    for (int r = 0; r < 3; ++r)
#pragma unroll
        for (int c = 0; c < 3; ++c)
            M[r][c] = (double)m[14 + 3 * r + c]
                    - sb[r] * Swt[c] - Sws[r] * tb[c] + Sw * sb[r] * tb[c];
    double Rm[3][3];
    kabsch_from_M(M, Rm);
    double T0 = tb[0] - (Rm[0][0] * sb[0] + Rm[0][1] * sb[1] + Rm[0][2] * sb[2]);
    double T1 = tb[1] - (Rm[1][0] * sb[0] + Rm[1][1] * sb[1] + Rm[1][2] * sb[2]);
    double T2 = tb[2] - (Rm[2][0] * sb[0] + Rm[2][1] * sb[1] + Rm[2][2] * sb[2]);
#pragma unroll
    for (int r = 0; r < 3; ++r)
#pragma unroll
        for (int c = 0; c < 3; ++c)
            Rout[9 * (long long)i + 3 * r + c] = (float)Rm[r][c];
    Tout[3 * i + 0] = (float)T0;
    Tout[3 * i + 1] = (float)T1;
    Tout[3 * i + 2] = (float)T2;
    float4 a = s4[i];
    float4 q = t4[i];
    double x0 = Rm[0][0] * a.x + Rm[0][1] * a.y + Rm[0][2] * a.z + T0;
    double x1 = Rm[1][0] * a.x + Rm[1][1] * a.y + Rm[1][2] * a.z + T1;
    double x2 = Rm[2][0] * a.x + Rm[2][1] * a.y + Rm[2][2] * a.z + T2;
    double d0 = x0 - q.x, d1 = x1 - q.y, d2 = x2 - q.z;
    double dd = d0 * d0 + d1 * d1 + d2 * d2;
    wnode[i] = (float)((double)kSigma2 / (dd + (double)kSigma2));
}

// wout[e] = wnode[nbr[e]] (8 edges/thread, vector loads, float4 stores).
__global__ void __launch_bounds__(256) k_wgather(const void* __restrict__ ei,
                                                 const float* __restrict__ wnode,
                                                 float* __restrict__ wout,
                                                 const int* __restrict__ nz,
                                                 int E, int N) {
    int gid = blockIdx.x * blockDim.x + threadIdx.x;
    long long base = (long long)gid * 8;
    if (base >= E) return;
    int is64 = (*nz == 0);
    int n_[8];
    int full = (base + 8 <= (long long)E);
    if (full) {
        if (is64) {
            const long long* p = (const long long*)ei + (long long)E + base;
#pragma unroll
            for (int k = 0; k < 4; ++k) {
                longlong2 a = ((const longlong2*)p)[k];
                n_[2 * k] = (int)a.x;
                n_[2 * k + 1] = (int)a.y;
            }
        } else {
            const int* p = (const int*)ei + (long long)E + base;
            int4 a = ((const int4*)p)[0];
            int4 b = ((const int4*)p)[1];
            n_[0] = a.x; n_[1] = a.y; n_[2] = a.z; n_[3] = a.w;
            n_[4] = b.x; n_[5] = b.y; n_[6] = b.z; n_[7] = b.w;
        }
        float w[8];
#pragma unroll
        for (int k = 0; k < 8; ++k)
            w[k] = ((unsigned)n_[k] < (unsigned)N) ? wnode[n_[k]] : 1.0f;
        *(float4*)(wout + base) = make_float4(w[0], w[1], w[2], w[3]);
        *(float4*)(wout + base + 4) = make_float4(w[4], w[5], w[6], w[7]);
    } else {
#pragma unroll
        for (int k = 0; k < 8; ++k) {
            long long e = base + k;
            if (e < E) {
                int n = load_idx(ei, (long long)E + e, is64);
                wout[e] = ((unsigned)n < (unsigned)N) ? wnode[n] : 1.0f;
            }
        }
    }
}

// ---------------- fallback atomic path ----------------

__global__ void k_accum1(const void* __restrict__ ei, const float* __restrict__ src,
                         const float* __restrict__ tgt, float* __restrict__ cnt,
                         float* __restrict__ ssum, float* __restrict__ tsum,
                         const int* __restrict__ nz, int E, int N) {
    int e = blockIdx.x * blockDim.x + threadIdx.x;
    if (e >= E) return;
    int is64 = (*nz == 0);
    int d = load_idx(ei, e, is64);
    int n = load_idx(ei, (long long)E + e, is64);
    if ((unsigned)d >= (unsigned)N || (unsigned)n >= (unsigned)N) return;
    atomicAdd(&cnt[d], 1.0f);
    atomicAdd(&ssum[3 * d + 0], src[3 * n + 0]);
    atomicAdd(&ssum[3 * d + 1], src[3 * n + 1]);
    atomicAdd(&ssum[3 * d + 2], src[3 * n + 2]);
    atomicAdd(&tsum[3 * d + 0], tgt[3 * n + 0]);
    atomicAdd(&tsum[3 * d + 1], tgt[3 * n + 1]);
    atomicAdd(&tsum[3 * d + 2], tgt[3 * n + 2]);
}

__global__ void k_centers(float* __restrict__ cnt, float* __restrict__ ssum,
                          float* __restrict__ tsum, int N) {
    int i = blockIdx.x * blockDim.x + threadIdx.x;
    if (i >= N) return;
    float inv = 1.0f / fmaxf(cnt[i], 1.0f);
    ssum[3 * i + 0] *= inv; ssum[3 * i + 1] *= inv; ssum[3 * i + 2] *= inv;
    tsum[3 * i + 0] *= inv; tsum[3 * i + 1] *= inv; tsum[3 * i + 2] *= inv;
}

__global__ void k_accum2(const void* __restrict__ ei, const float* __restrict__ src,
                         const float* __restrict__ tgt, const float* __restrict__ ew,
                         const float* __restrict__ sc, const float* __restrict__ tc,
                         float* __restrict__ Mm, const int* __restrict__ nz, int E, int N) {
    int e = blockIdx.x * blockDim.x + threadIdx.x;
    if (e >= E) return;
    int is64 = (*nz == 0);
    int d = load_idx(ei, e, is64);
    int n = load_idx(ei, (long long)E + e, is64);
    if ((unsigned)d >= (unsigned)N || (unsigned)n >= (unsigned)N) return;
    float w = ew[e];
    float a0 = (src[3 * n + 0] - sc[3 * d + 0]) * w;
    float a1 = (src[3 * n + 1] - sc[3 * d + 1]) * w;
    float a2 = (src[3 * n + 2] - sc[3 * d + 2]) * w;
    float b0 = tgt[3 * n + 0] - tc[3 * d + 0];
    float b1 = tgt[3 * n + 1] - tc[3 * d + 1];
    float b2 = tgt[3 * n + 2] - tc[3 * d + 2];
    float* Md = Mm + 9 * (long long)d;
    atomicAdd(Md + 0, a0 * b0); atomicAdd(Md + 1, a0 * b1); atomicAdd(Md + 2, a0 * b2);
    atomicAdd(Md + 3, a1 * b0); atomicAdd(Md + 4, a1 * b1); atomicAdd(Md + 5, a1 * b2);
    atomicAdd(Md + 6, a2 * b0); atomicAdd(Md + 7, a2 * b1); atomicAdd(Md + 8, a2 * b2);
}

__global__ void k_kabsch(const float* __restrict__ Mm, const float* __restrict__ sc,
                         const float* __restrict__ tc, float* __restrict__ Rout,
                         float* __restrict__ Tout, int N) {
    int i = blockIdx.x * blockDim.x + threadIdx.x;
    if (i >= N) return;
    double M[3][3];
#pragma unroll
    for (int r = 0; r < 3; ++r)
#pragma unroll
        for (int c = 0; c < 3; ++c)
            M[r][c] = (double)Mm[9 * (long long)i + 3 * r + c];
    double Rm[3][3];
    kabsch_from_M(M, Rm);
    double s0 = sc[3 * i + 0], s1 = sc[3 * i + 1], s2 = sc[3 * i + 2];
    double t0 = tc[3 * i + 0], t1 = tc[3 * i + 1], t2 = tc[3 * i + 2];
#pragma unroll
    for (int r = 0; r < 3; ++r)
#pragma unroll
        for (int c = 0; c < 3; ++c)
            Rout[9 * (long long)i + 3 * r + c] = (float)Rm[r][c];
    Tout[3 * i + 0] = (float)(t0 - (Rm[0][0] * s0 + Rm[0][1] * s1 + Rm[0][2] * s2));
    Tout[3 * i + 1] = (float)(t1 - (Rm[1][0] * s0 + Rm[1][1] * s1 + Rm[1][2] * s2));
    Tout[3 * i + 2] = (float)(t2 - (Rm[2][0] * s0 + Rm[2][1] * s1 + Rm[2][2] * s2));
}

__global__ void k_weights_plain(const void* __restrict__ ei,
                                const float* __restrict__ src,
                                const float* __restrict__ tgt,
                                const float* __restrict__ R,
                                const float* __restrict__ T,
                                float* __restrict__ wout,
                                const int* __restrict__ nz, int E, int N) {
    int e = blockIdx.x * blockDim.x + threadIdx.x;
    if (e >= E) return;
    int is64 = (*nz == 0);
    int n = load_idx(ei, (long long)E + e, is64);
    float w = 1.0f;
    if ((unsigned)n < (unsigned)N) {
        float p0 = src[3 * n + 0], p1 = src[3 * n + 1], p2 = src[3 * n + 2];
        float q0 = tgt[3 * n + 0], q1 = tgt[3 * n + 1], q2 = tgt[3 * n + 2];
        const float* Rn = R + 9 * (long long)n;
        const float* Tn = T + 3 * (long long)n;
        float x0 = Rn[0] * p0 + Rn[1] * p1 + Rn[2] * p2 + Tn[0];
        float x1 = Rn[3] * p0 + Rn[4] * p1 + Rn[5] * p2 + Tn[1];
        float x2 = Rn[6] * p0 + Rn[7] * p1 + Rn[8] * p2 + Tn[2];
        float d0 = x0 - q0, d1 = x1 - q1, d2 = x2 - q2;
        float dd = d0 * d0 + d1 * d1 + d2 * d2;
        w = kSigma2 / (dd + kSigma2);
    }
    wout[e] = w;
}

extern "C" void kernel_launch(void* const* d_in, const int* in_sizes, int n_in,
                              void* d_out, int out_size, void* d_ws, size_t ws_size,
                              hipStream_t stream) {
    const float* src = (const float*)d_in[0];
    const float* tgt = (const float*)d_in[1];
    const void* ei = d_in[2];
    const float* ew = (const float*)d_in[3];
    int N = in_sizes[0] / 3;
    int E = in_sizes[3];

    float* out = (float*)d_out;
    float* Rout = out;
    float* Tout = out + (size_t)9 * N;
    float* Wout = out + (size_t)12 * N;

    int eb = (E + 255) / 256;
    int nb = (N + 255) / 256;
    int nb64 = (N + 63) / 64;
    int nbuckets = (N + 127) / 128;
    int ncoarse = (nbuckets + 63) / 64;
    int tiles = (int)(((long long)E + 2047) / 2048);
    int tiles16 = (int)(((long long)E + 16383) / 16384);
    int wb8 = (int)(((long long)E + 2047) / 2048);

    // ws layout: [nz(16) | btot16 | cur16 | curC16(256) | boff | pad4 |
    //             sedge1 (E int2) | [sedge2 (E int2)] | s4 | t4 | wnode(N) |
    //             momG (23N) | nseg]
    size_t ctrl_ints = 16 + (size_t)nbuckets * 16 * 2 + 256 + (nbuckets + 1);
    ctrl_ints = (ctrl_ints + 3) & ~(size_t)3;
    size_t after1 = ctrl_ints + 2 * (size_t)E;
    after1 = (after1 + 3) & ~(size_t)3;
    size_t after2 = after1 + 2 * (size_t)E;
    after2 = (after2 + 3) & ~(size_t)3;
    size_t tail_ints = 8 * (size_t)N + (size_t)N + 23 * (size_t)N
                     + 2 * (size_t)128 * nbuckets;
    size_t needA = (after2 + tail_ints) * sizeof(int);
    size_t needB = (after1 + tail_ints) * sizeof(int);

    if (N <= 131072 && nbuckets <= 1024 && ws_size >= needB) {
        int twolevel = (ws_size >= needA) ? 1 : 0;
        int* nz = (int*)d_ws;
        int* btot16 = nz + 16;
        int* cur16 = btot16 + (size_t)nbuckets * 16;
        int* curC16 = cur16 + (size_t)nbuckets * 16;
        int* boff = curC16 + 256;
        int2* sedge1 = (int2*)((int*)d_ws + ctrl_ints);
        size_t tail_base = twolevel ? after2 : after1;
        int2* sedge2 = twolevel ? (int2*)((int*)d_ws + after1) : sedge1;
        float4* s4 = (float4*)((int*)d_ws + tail_base);
        float4* t4 = s4 + N;
        float* wnode = (float*)(t4 + N);
        float* momG = wnode + N;
        int2* nseg = (int2*)(momG + 23 * (size_t)N);

        hipMemsetAsync(d_ws, 0, ctrl_ints * sizeof(int), stream);

        k_detect<<<1, 256, 0, stream>>>((const int*)ei, E, nz);
        k_pack<<<nb, 256, 0, stream>>>(src, tgt, s4, t4, N);
        k_bhist<<<tiles16, 256, 0, stream>>>(ei, btot16, nz, E, N, nbuckets);
        k_scan<<<1, 1024, 0, stream>>>(btot16, boff, cur16, curC16, nbuckets);
        if (twolevel) {
            k_cscatter<<<tiles, 256, 0, stream>>>(ei, ew, curC16, sedge1, nz, E, N, ncoarse);
            k_fscatter<<<tiles, 256, 0, stream>>>(sedge1, cur16, boff, sedge2, E, nbuckets, ncoarse);
        } else {
            k_binscatter<<<tiles, 256, 0, stream>>>(ei, ew, cur16, sedge2, nz, E, N, nbuckets);
        }
        k_sort<<<nbuckets, 256, 0, stream>>>(boff, sedge2, nseg);
        k_moment<<<nb64, 256, 0, stream>>>(nseg, sedge2, s4, t4, momG, N);
        k_kabsch2<<<nb, 256, 0, stream>>>(momG, s4, t4, Rout, Tout, wnode, N);
        k_wgather<<<wb8, 256, 0, stream>>>(ei, wnode, Wout, nz, E, N);
    } else {
        // fallback: atomic path
        float* cnt = (float*)d_ws;
        float* ssum = cnt + N;
        float* tsum = ssum + 3 * (size_t)N;
        float* Mm = tsum + 3 * (size_t)N;
        int* nz = (int*)(Mm + 9 * (size_t)N);
        size_t ws_bytes = (size_t)16 * N * sizeof(float) + 16;
        hipMemsetAsync(d_ws, 0, ws_bytes, stream);
        k_detect<<<1, 256, 0, stream>>>((const int*)ei, E, nz);
        k_accum1<<<eb, 256, 0, stream>>>(ei, src, tgt, cnt, ssum, tsum, nz, E, N);
        k_centers<<<nb, 256, 0, stream>>>(cnt, ssum, tsum, N);
        k_accum2<<<eb, 256, 0, stream>>>(ei, src, tgt, ew, ssum, tsum, Mm, nz, E, N);
        k_kabsch<<<nb, 256, 0, stream>>>(Mm, ssum, tsum, Rout, Tout, N);
        k_weights_plain<<<eb, 256, 0, stream>>>(ei, src, tgt, Rout, Tout, Wout, nz, E, N);
    }
}

// Round 10
// 261.977 us; speedup vs baseline: 2.6172x; 1.0386x over previous
//
#include <hip/hip_runtime.h>
#include <math.h>

static constexpr float kSigma2 = 0.05f * 0.05f;
static constexpr int kCap2 = 2560;  // max edges per 64-node bucket in fused LDS sort

__device__ __forceinline__ int load_idx(const void* ei, long long j, int is64) {
    if (is64) return (int)(((const long long*)ei)[j]);
    return ((const int*)ei)[j];
}

// Detect whether edge_index is int64 (all odd int32 words zero) or int32.
__global__ void k_detect(const int* __restrict__ ei32, int E, int* __restrict__ nz) {
    int t = threadIdx.x;
    int lim = E < 2048 ? E : 2048;
    int acc = 0;
    for (int k = t; k < lim; k += blockDim.x) acc |= ei32[2 * k + 1];
    if (acc) atomicOr(nz, 1);
}

// Pack points into float4 arrays for vector gathers.
__global__ void k_pack(const float* __restrict__ src, const float* __restrict__ tgt,
                       float4* __restrict__ s4, float4* __restrict__ t4, int N) {
    int i = blockIdx.x * blockDim.x + threadIdx.x;
    if (i >= N) return;
    s4[i] = make_float4(src[3 * i + 0], src[3 * i + 1], src[3 * i + 2], 0.0f);
    t4[i] = make_float4(tgt[3 * i + 0], tgt[3 * i + 1], tgt[3 * i + 2], 0.0f);
}

// ---------------- shared Kabsch core (fp64, Jacobi on M^T M) ----------------
__device__ void kabsch_from_M(const double M[3][3], double Rm[3][3]) {
    Rm[0][0] = 1; Rm[0][1] = 0; Rm[0][2] = 0;
    Rm[1][0] = 0; Rm[1][1] = 1; Rm[1][2] = 0;
    Rm[2][0] = 0; Rm[2][1] = 0; Rm[2][2] = 1;

    double frob2 = 0.0;
#pragma unroll
    for (int r = 0; r < 3; ++r)
#pragma unroll
        for (int c = 0; c < 3; ++c) frob2 += M[r][c] * M[r][c];
    if (frob2 <= 1e-80) return;

    double A[3][3];
#pragma unroll
    for (int r = 0; r < 3; ++r)
#pragma unroll
        for (int c = 0; c < 3; ++c) {
            double s = 0.0;
#pragma unroll
            for (int k = 0; k < 3; ++k) s += M[k][r] * M[k][c];
            A[r][c] = s;
        }
    double V[3][3] = {{1, 0, 0}, {0, 1, 0}, {0, 0, 1}};
    const int PL[3] = {0, 0, 1};
    const int QL[3] = {1, 2, 2};
    for (int sweep = 0; sweep < 15; ++sweep) {
        double off = fabs(A[0][1]) + fabs(A[0][2]) + fabs(A[1][2]);
        if (off == 0.0) break;
        for (int pi = 0; pi < 3; ++pi) {
            int p = PL[pi], q = QL[pi], r3 = 3 - p - q;
            double apq = A[p][q];
            if (apq == 0.0) continue;
            double theta = (A[q][q] - A[p][p]) / (2.0 * apq);
            double t = copysign(1.0, theta) / (fabs(theta) + sqrt(theta * theta + 1.0));
            double c = 1.0 / sqrt(t * t + 1.0);
            double s = t * c;
            A[p][p] -= t * apq;
            A[q][q] += t * apq;
            A[p][q] = 0.0; A[q][p] = 0.0;
            double arp = A[r3][p], arq = A[r3][q];
            A[r3][p] = c * arp - s * arq; A[p][r3] = A[r3][p];
            A[r3][q] = s * arp + c * arq; A[q][r3] = A[r3][q];
#pragma unroll
            for (int k = 0; k < 3; ++k) {
                double vp = V[k][p], vq = V[k][q];
                V[k][p] = c * vp - s * vq;
                V[k][q] = s * vp + c * vq;
            }
        }
    }
    double lam[3] = {A[0][0], A[1][1], A[2][2]};
    int id0 = 0, id1 = 1, id2 = 2, tt;
    if (lam[id0] < lam[id1]) { tt = id0; id0 = id1; id1 = tt; }
    if (lam[id0] < lam[id2]) { tt = id0; id0 = id2; id2 = tt; }
    if (lam[id1] < lam[id2]) { tt = id1; id1 = id2; id2 = tt; }
    double v1[3] = {V[0][id0], V[1][id0], V[2][id0]};
    double v2[3] = {V[0][id1], V[1][id1], V[2][id1]};
    double v3[3] = {V[0][id2], V[1][id2], V[2][id2]};

    double b1[3], b2[3];
#pragma unroll
    for (int r = 0; r < 3; ++r) {
        b1[r] = M[r][0] * v1[0] + M[r][1] * v1[1] + M[r][2] * v1[2];
        b2[r] = M[r][0] * v2[0] + M[r][1] * v2[1] + M[r][2] * v2[2];
    }
    double n1 = sqrt(b1[0] * b1[0] + b1[1] * b1[1] + b1[2] * b1[2]);
    if (n1 <= 1e-150) return;
    double u1[3] = {b1[0] / n1, b1[1] / n1, b1[2] / n1};
    double dot = u1[0] * b2[0] + u1[1] * b2[1] + u1[2] * b2[2];
    double w2[3] = {b2[0] - dot * u1[0], b2[1] - dot * u1[1], b2[2] - dot * u1[2]};
    double n2 = sqrt(w2[0] * w2[0] + w2[1] * w2[1] + w2[2] * w2[2]);
    double u2[3];
    if (n2 > n1 * 1e-12) {
        u2[0] = w2[0] / n2; u2[1] = w2[1] / n2; u2[2] = w2[2] / n2;
    } else {
        double ex0 = (fabs(u1[0]) < 0.9) ? 1.0 : 0.0;
        double ex1 = 1.0 - ex0;
        double cx = u1[1] * 0.0 - u1[2] * ex1;
        double cy = u1[2] * ex0 - u1[0] * 0.0;
        double cz = u1[0] * ex1 - u1[1] * ex0;
        double cn = sqrt(cx * cx + cy * cy + cz * cz);
        u2[0] = cx / cn; u2[1] = cy / cn; u2[2] = cz / cn;
    }
    double u3[3] = {u1[1] * u2[2] - u1[2] * u2[1],
                    u1[2] * u2[0] - u1[0] * u2[2],
                    u1[0] * u2[1] - u1[1] * u2[0]};
    double dV = v1[0] * (v2[1] * v3[2] - v2[2] * v3[1])
              - v1[1] * (v2[0] * v3[2] - v2[2] * v3[0])
              + v1[2] * (v2[0] * v3[1] - v2[1] * v3[0]);
    dV = (dV >= 0.0) ? 1.0 : -1.0;
#pragma unroll
    for (int r = 0; r < 3; ++r)
#pragma unroll
        for (int c = 0; c < 3; ++c)
            Rm[r][c] = u1[r] * v1[c] + u2[r] * v2[c] + dV * u3[r] * v3[c];
}

// ---------------- bucketed counting-sort path ----------------
// fine bucket = dst >> 6 (64 nodes). final payload: x = (nbr<<6)|(dst&63), y = w bits.
// coarse bucket = dst >> 13 (128 fine buckets). intermediate payload:
//   x = (nbr<<13)|(dst&8191), y = w bits.

// 16384 edges per block (64/thread): amortizes the global-atomic histogram flush.
__global__ void __launch_bounds__(256) k_bhist(const void* __restrict__ ei,
                                               int* __restrict__ btot16,
                                               const int* __restrict__ nz,
                                               int E, int N, int nbuckets) {
    __shared__ int lhist[2048];
    int t = threadIdx.x;
    long long tile = (long long)blockIdx.x * 16384;
    long long remll = (long long)E - tile;
    int rem = (remll < 16384) ? (int)remll : 16384;
    int is64 = (*nz == 0);
    for (int i = t; i < 2048; i += 256) lhist[i] = 0;
    __syncthreads();
    if (rem == 16384) {
        for (int it = 0; it < 8; ++it) {
            long long base = tile + (long long)it * 2048 + (long long)t * 8;
            int d[8];
            if (is64) {
                const long long* p = (const long long*)ei + base;
#pragma unroll
                for (int k = 0; k < 4; ++k) {
                    longlong2 v = ((const longlong2*)p)[k];
                    d[2 * k] = (int)v.x;
                    d[2 * k + 1] = (int)v.y;
                }
            } else {
                const int* p = (const int*)ei + base;
                int4 a = ((const int4*)p)[0];
                int4 bb = ((const int4*)p)[1];
                d[0] = a.x; d[1] = a.y; d[2] = a.z; d[3] = a.w;
                d[4] = bb.x; d[5] = bb.y; d[6] = bb.z; d[7] = bb.w;
            }
#pragma unroll
            for (int k = 0; k < 8; ++k)
                if ((unsigned)d[k] < (unsigned)N) atomicAdd(&lhist[d[k] >> 6], 1);
        }
    } else {
        for (int idx = t; idx < rem; idx += 256) {
            int d = load_idx(ei, tile + idx, is64);
            if ((unsigned)d < (unsigned)N) atomicAdd(&lhist[d >> 6], 1);
        }
    }
    __syncthreads();
    for (int b = t; b < 2048; b += 256) {
        int c = lhist[b];
        if (c > 0 && b < nbuckets) atomicAdd(&btot16[b * 16], c);
    }
}

// fine exclusive scan (up to 2048 bins, 1024 thr x 2) -> boff, cur16, curC16.
__global__ void k_scan(const int* __restrict__ btot16, int* __restrict__ boff,
                       int* __restrict__ cur16, int* __restrict__ curC16, int nbuckets) {
    __shared__ int sm[2048];
    int t = threadIdx.x;
    int v0 = (t < nbuckets) ? btot16[t * 16] : 0;
    int v1 = (t + 1024 < nbuckets) ? btot16[(t + 1024) * 16] : 0;
    sm[t] = v0;
    sm[t + 1024] = v1;
    __syncthreads();
    for (int s = 1; s < 2048; s <<= 1) {
        int x0 = (t >= s) ? sm[t - s] : 0;
        int x1 = (t + 1024 >= s) ? sm[t + 1024 - s] : 0;
        __syncthreads();
        sm[t] += x0;
        sm[t + 1024] += x1;
        __syncthreads();
    }
    if (t < nbuckets) {
        int ex = sm[t] - v0;
        boff[t] = ex;
        cur16[t * 16] = ex;
        if ((t & 127) == 0) curC16[(t >> 7) * 16] = ex;
    }
    int t2 = t + 1024;
    if (t2 < nbuckets) {
        int ex = sm[t2] - v1;
        boff[t2] = ex;
        cur16[t2 * 16] = ex;
        if ((t2 & 127) == 0) curC16[(t2 >> 7) * 16] = ex;
    }
    if (t == nbuckets - 1) boff[nbuckets] = sm[t];
    if (t2 == nbuckets - 1) boff[nbuckets] = sm[t2];
}

// Level-1 scatter: raw edges -> coarse-sorted sedge1 (<=16 bins, long runs).
__global__ void __launch_bounds__(256) k_cscatter(const void* __restrict__ ei,
                                                  const float* __restrict__ ew,
                                                  int* __restrict__ curC16,
                                                  int2* __restrict__ sedge1,
                                                  const int* __restrict__ nz,
                                                  int E, int N, int ncoarse) {
    __shared__ int2 stage[2048];
    __shared__ unsigned char binOf[2048];
    __shared__ int hist[16];
    __shared__ int excl[16];
    __shared__ int gbase[16];
    int t = threadIdx.x;
    long long tile = (long long)blockIdx.x * 2048;
    long long remll = (long long)E - tile;
    int rem = (remll < 2048) ? (int)remll : 2048;
    int is64 = (*nz == 0);
    if (t < 16) hist[t] = 0;
    __syncthreads();

    int dd[8], nn[8];
    float ww[8];
    int cnt8 = 0;
    if (rem == 2048) {
        if (is64) {
            const long long* pd = (const long long*)ei + tile + (long long)t * 8;
            const long long* pn = (const long long*)ei + (long long)E + tile + (long long)t * 8;
#pragma unroll
            for (int k = 0; k < 4; ++k) {
                longlong2 vd = ((const longlong2*)pd)[k];
                longlong2 vn = ((const longlong2*)pn)[k];
                dd[2 * k] = (int)vd.x; dd[2 * k + 1] = (int)vd.y;
                nn[2 * k] = (int)vn.x; nn[2 * k + 1] = (int)vn.y;
            }
        } else {
            const int* pd = (const int*)ei + tile + (long long)t * 8;
            const int* pn = (const int*)ei + (long long)E + tile + (long long)t * 8;
            int4 a = ((const int4*)pd)[0], b = ((const int4*)pd)[1];
            int4 c = ((const int4*)pn)[0], d = ((const int4*)pn)[1];
            dd[0] = a.x; dd[1] = a.y; dd[2] = a.z; dd[3] = a.w;
            dd[4] = b.x; dd[5] = b.y; dd[6] = b.z; dd[7] = b.w;
            nn[0] = c.x; nn[1] = c.y; nn[2] = c.z; nn[3] = c.w;
            nn[4] = d.x; nn[5] = d.y; nn[6] = d.z; nn[7] = d.w;
        }
        const float* pw = ew + tile + (long long)t * 8;
        float4 wa = ((const float4*)pw)[0], wb = ((const float4*)pw)[1];
        ww[0] = wa.x; ww[1] = wa.y; ww[2] = wa.z; ww[3] = wa.w;
        ww[4] = wb.x; ww[5] = wb.y; ww[6] = wb.z; ww[7] = wb.w;
        cnt8 = 8;
    } else {
        int base = t * 8;
#pragma unroll
        for (int k = 0; k < 8; ++k) {
            int idx = base + k;
            if (idx < rem) {
                long long e = tile + idx;
                dd[cnt8] = load_idx(ei, e, is64);
                nn[cnt8] = load_idx(ei, (long long)E + e, is64);
                ww[cnt8] = ew[e];
                ++cnt8;
            }
        }
    }

    int mybin[8], myrank[8];
    int2 mypay[8];
#pragma unroll
    for (int k = 0; k < 8; ++k) {
        mybin[k] = -1;
        if (k < cnt8) {
            int d = dd[k];
            if ((unsigned)d < (unsigned)N) {
                int n = nn[k];
                if ((unsigned)n >= (unsigned)N) n = N;  // sentinel; filtered later
                int cb = d >> 13;
                mybin[k] = cb;
                myrank[k] = atomicAdd(&hist[cb], 1);
                mypay[k].x = (n << 13) | (d & 8191);
                mypay[k].y = __float_as_int(ww[k]);
            }
        }
    }
    __syncthreads();
    if (t == 0) {
        int run = 0;
#pragma unroll
        for (int c = 0; c < 16; ++c) { excl[c] = run; run += hist[c]; }
    }
    __syncthreads();
#pragma unroll
    for (int k = 0; k < 8; ++k) {
        if (mybin[k] >= 0) {
            int lpos = excl[mybin[k]] + myrank[k];
            stage[lpos] = mypay[k];
            binOf[lpos] = (unsigned char)mybin[k];
        }
    }
    if (t < 16) {
        int c = hist[t];
        gbase[t] = (c > 0 && t < ncoarse) ? atomicAdd(&curC16[t * 16], c) : 0;
    }
    __syncthreads();
    int total = excl[15] + hist[15];
    for (int lpos = t; lpos < total; lpos += 256) {
        int c = binOf[lpos];
        sedge1[gbase[c] + (lpos - excl[c])] = stage[lpos];
    }
}

// Level-2 scatter: coarse-sorted sedge1 -> fine-sorted sedge2 (repacks payload).
// Windowed ranking relative to the tile's first coarse bucket (x128 fine bins).
__global__ void __launch_bounds__(256) k_fscatter(const int2* __restrict__ sedge1,
                                                  int* __restrict__ cur16,
                                                  const int* __restrict__ boff,
                                                  int2* __restrict__ sedge2,
                                                  int E, int nbuckets, int ncoarse) {
    __shared__ int2 stage[2048];
    __shared__ unsigned short binOf[2048];
    __shared__ int lhist[1024];
    __shared__ int lincl[1024];
    __shared__ int gbase[1024];
    __shared__ int co[17];
    __shared__ int s_clo, s_W;
    int t = threadIdx.x;
    if (t <= ncoarse) {
        int f = t * 128;
        if (f > nbuckets) f = nbuckets;
        co[t] = boff[f];
    }
    __syncthreads();
    int Ev = co[ncoarse];
    long long tile = (long long)blockIdx.x * 2048;
    if (tile >= Ev) return;
    long long remll = (long long)Ev - tile;
    int rem = (remll < 2048) ? (int)remll : 2048;

    if (t == 0) {
        long long p0 = tile, p1 = tile + rem - 1;
        int c0 = 0;
        while (c0 + 1 < ncoarse && p0 >= co[c0 + 1]) ++c0;
        int c1 = c0;
        while (c1 + 1 < ncoarse && p1 >= co[c1 + 1]) ++c1;
        s_clo = c0;
        s_W = (c1 - c0 + 1) * 128;
    }
    __syncthreads();
    int clo = s_clo, W = s_W;

    int2 pay[8];
    int cnt8 = 0;
    if (rem == 2048) {
        const int4* p4 = (const int4*)(sedge1 + tile + (long long)t * 8);
#pragma unroll
        for (int k = 0; k < 4; ++k) {
            int4 v = p4[k];
            pay[2 * k].x = v.x; pay[2 * k].y = v.y;
            pay[2 * k + 1].x = v.z; pay[2 * k + 1].y = v.w;
        }
        cnt8 = 8;
    } else {
        int base = t * 8;
#pragma unroll
        for (int k = 0; k < 8; ++k) {
            int idx = base + k;
            if (idx < rem) pay[cnt8++] = sedge1[tile + idx];
        }
    }

    if (W > 1024) {
        // slow path (essentially never taken): per-edge global cursor bump
        for (int k = 0; k < cnt8; ++k) {
            long long pos = tile + t * 8 + k;
            int c = clo;
            while (c + 1 < ncoarse && pos >= co[c + 1]) ++c;
            int x1 = pay[k].x;
            unsigned nbr = ((unsigned)x1) >> 13;
            int fin = c * 128 + ((x1 & 8191) >> 6);
            int gpos = atomicAdd(&cur16[fin * 16], 1);
            int2 out;
            out.x = (int)((nbr << 6) | (unsigned)(x1 & 63));
            out.y = pay[k].y;
            sedge2[gpos] = out;
        }
        return;
    }

    for (int i = t; i < W; i += 256) lhist[i] = 0;
    __syncthreads();

    int mybin[8], myrank[8];
    int2 mypay[8];
#pragma unroll
    for (int k = 0; k < 8; ++k) {
        mybin[k] = -1;
        if (k < cnt8) {
            long long pos = tile + t * 8 + k;
            int c = clo;
            while (c + 1 < ncoarse && pos >= co[c + 1]) ++c;
            int x1 = pay[k].x;
            unsigned nbr = ((unsigned)x1) >> 13;
            int rel = (c - clo) * 128 + ((x1 & 8191) >> 6);
            mybin[k] = rel;
            myrank[k] = atomicAdd(&lhist[rel], 1);
            mypay[k].x = (int)((nbr << 6) | (unsigned)(x1 & 63));
            mypay[k].y = pay[k].y;
        }
    }
    __syncthreads();
    for (int i = t; i < W; i += 256) lincl[i] = lhist[i];
    __syncthreads();
    for (int s = 1; s < W; s <<= 1) {
        int tmp[4];
        int cj = 0;
        for (int i = t; i < W; i += 256) tmp[cj++] = (i >= s) ? lincl[i - s] : 0;
        __syncthreads();
        cj = 0;
        for (int i = t; i < W; i += 256) lincl[i] += tmp[cj++];
        __syncthreads();
    }
#pragma unroll
    for (int k = 0; k < 8; ++k) {
        if (mybin[k] >= 0) {
            int ex = lincl[mybin[k]] - lhist[mybin[k]];
            int lpos = ex + myrank[k];
            stage[lpos] = mypay[k];
            binOf[lpos] = (unsigned short)mybin[k];
        }
    }
    __syncthreads();
    for (int rel = t; rel < W; rel += 256) {
        int c = lhist[rel];
        int fin = clo * 128 + rel;
        gbase[rel] = (c > 0 && fin < nbuckets) ? atomicAdd(&cur16[fin * 16], c) : 0;
    }
    __syncthreads();
    int total = lincl[W - 1];
    for (int lpos = t; lpos < total; lpos += 256) {
        int rel = binOf[lpos];
        int ex = lincl[rel] - lhist[rel];
        sedge2[gbase[rel] + (lpos - ex)] = stage[lpos];
    }
}

// Single-level scatter (fallback when ws can't hold two edge buffers).
__global__ void __launch_bounds__(256) k_binscatter(const void* __restrict__ ei,
                                                    const float* __restrict__ ew,
                                                    int* __restrict__ cur16,
                                                    int2* __restrict__ sedge,
                                                    const int* __restrict__ nz,
                                                    int E, int N, int nbuckets) {
    __shared__ int2 stage[2048];
    __shared__ unsigned short binOf[2048];
    __shared__ int lhist[2048];
    __shared__ int lincl[2048];
    __shared__ int gbase[2048];
    int t = threadIdx.x;
    long long tile = (long long)blockIdx.x * 2048;
    long long remll = (long long)E - tile;
    int rem = (remll < 2048) ? (int)remll : 2048;
    int is64 = (*nz == 0);
    for (int i = t; i < 2048; i += 256) lhist[i] = 0;
    __syncthreads();

    int dd[8], nn[8];
    float ww[8];
    int cnt8 = 0;
    if (rem == 2048) {
        if (is64) {
            const long long* pd = (const long long*)ei + tile + (long long)t * 8;
            const long long* pn = (const long long*)ei + (long long)E + tile + (long long)t * 8;
#pragma unroll
            for (int k = 0; k < 4; ++k) {
                longlong2 vd = ((const longlong2*)pd)[k];
                longlong2 vn = ((const longlong2*)pn)[k];
                dd[2 * k] = (int)vd.x; dd[2 * k + 1] = (int)vd.y;
                nn[2 * k] = (int)vn.x; nn[2 * k + 1] = (int)vn.y;
            }
        } else {
            const int* pd = (const int*)ei + tile + (long long)t * 8;
            const int* pn = (const int*)ei + (long long)E + tile + (long long)t * 8;
            int4 a = ((const int4*)pd)[0], b = ((const int4*)pd)[1];
            int4 c = ((const int4*)pn)[0], d = ((const int4*)pn)[1];
            dd[0] = a.x; dd[1] = a.y; dd[2] = a.z; dd[3] = a.w;
            dd[4] = b.x; dd[5] = b.y; dd[6] = b.z; dd[7] = b.w;
            nn[0] = c.x; nn[1] = c.y; nn[2] = c.z; nn[3] = c.w;
            nn[4] = d.x; nn[5] = d.y; nn[6] = d.z; nn[7] = d.w;
        }
        const float* pw = ew + tile + (long long)t * 8;
        float4 wa = ((const float4*)pw)[0], wb = ((const float4*)pw)[1];
        ww[0] = wa.x; ww[1] = wa.y; ww[2] = wa.z; ww[3] = wa.w;
        ww[4] = wb.x; ww[5] = wb.y; ww[6] = wb.z; ww[7] = wb.w;
        cnt8 = 8;
    } else {
        int base = t * 8;
#pragma unroll
        for (int k = 0; k < 8; ++k) {
            int idx = base + k;
            if (idx < rem) {
                long long e = tile + idx;
                dd[cnt8] = load_idx(ei, e, is64);
                nn[cnt8] = load_idx(ei, (long long)E + e, is64);
                ww[cnt8] = ew[e];
                ++cnt8;
            }
        }
    }

    int mybin[8];
    int myrank[8];
    int2 mypay[8];
#pragma unroll
    for (int k = 0; k < 8; ++k) {
        mybin[k] = -1;
        if (k < cnt8) {
            int d = dd[k];
            if ((unsigned)d < (unsigned)N) {
                int n = nn[k];
                if ((unsigned)n >= (unsigned)N) n = N;  // sentinel
                int bb = d >> 6;
                mybin[k] = bb;
                myrank[k] = atomicAdd(&lhist[bb], 1);
                mypay[k].x = (n << 6) | (d & 63);
                mypay[k].y = __float_as_int(ww[k]);
            }
        }
    }
    __syncthreads();
    for (int i = t; i < 2048; i += 256) lincl[i] = lhist[i];
    __syncthreads();
    for (int s = 1; s < 2048; s <<= 1) {
        int tmp[8];
#pragma unroll
        for (int j = 0; j < 8; ++j) {
            int i = (j << 8) + t;
            tmp[j] = (i >= s) ? lincl[i - s] : 0;
        }
        __syncthreads();
#pragma unroll
        for (int j = 0; j < 8; ++j) {
            int i = (j << 8) + t;
            lincl[i] += tmp[j];
        }
        __syncthreads();
    }
#pragma unroll
    for (int k = 0; k < 8; ++k) {
        if (mybin[k] >= 0) {
            int ex = lincl[mybin[k]] - lhist[mybin[k]];
            int lpos = ex + myrank[k];
            stage[lpos] = mypay[k];
            binOf[lpos] = (unsigned short)mybin[k];
        }
    }
    __syncthreads();
    for (int bb = t; bb < 2048; bb += 256) {
        int c = lhist[bb];
        gbase[bb] = (c > 0 && bb < nbuckets) ? atomicAdd(&cur16[bb * 16], c) : 0;
    }
    __syncthreads();
    int total = lincl[2047];
    for (int lpos = t; lpos < total; lpos += 256) {
        int bb = binOf[lpos];
        int ex = lincl[bb] - lhist[bb];
        sedge[gbase[bb] + (lpos - ex)] = stage[lpos];
    }
}

// Fused per-bucket sort (64 nodes, in LDS, no write-back) + 23-moment pass.
// Writes moments to SoA momG[k*N + n].
__global__ void __launch_bounds__(256) k_sortmoment(const int* __restrict__ boff,
                                                    const int2* __restrict__ sedge2,
                                                    const float4* __restrict__ s4,
                                                    const float4* __restrict__ t4,
                                                    float* __restrict__ momG, int N) {
    __shared__ int2 sorted[kCap2];
    __shared__ int hist[64];
    __shared__ int scanbuf[64];
    __shared__ int offs[64];
    __shared__ int cur[64];
    int b = blockIdx.x, t = threadIdx.x;
    int e0 = boff[b], e1 = boff[b + 1];
    int cnt = e1 - e0;
    if (t < 64) hist[t] = 0;
    __syncthreads();
    int inlds = (cnt <= kCap2);
    if (inlds) {
        for (int i = t; i < cnt; i += 256)
            atomicAdd(&hist[sedge2[e0 + i].x & 63], 1);
        __syncthreads();
        if (t < 64) scanbuf[t] = hist[t];
        __syncthreads();
        for (int s = 1; s < 64; s <<= 1) {
            int v = 0;
            if (t < 64 && t >= s) v = scanbuf[t - s];
            __syncthreads();
            if (t < 64) scanbuf[t] += v;
            __syncthreads();
        }
        if (t < 64) {
            int ex = scanbuf[t] - hist[t];
            offs[t] = ex;
            cur[t] = ex;
        }
        __syncthreads();
        for (int i = t; i < cnt; i += 256) {
            int2 p = sedge2[e0 + i];
            int r = atomicAdd(&cur[p.x & 63], 1);
            sorted[r] = p;
        }
        __syncthreads();
    }
    int oct = t >> 3, lane8 = t & 7;
#pragma unroll
    for (int rr = 0; rr < 2; ++rr) {
        int nl = oct + rr * 32;
        long long node = (long long)b * 64 + nl;
        float v[23];
#pragma unroll
        for (int i = 0; i < 23; ++i) v[i] = 0.0f;
        if (node < N) {
            if (inlds) {
                int start = offs[nl];
                int cn = hist[nl];
                for (int j = lane8; j < cn; j += 8) {
                    int2 p = sorted[start + j];
                    unsigned n = ((unsigned)p.x) >> 6;
                    if (n >= (unsigned)N) continue;
                    float w = __int_as_float(p.y);
                    float4 a = s4[n];
                    float4 bb = t4[n];
                    float sx = a.x, sy = a.y, sz = a.z;
                    float tx = bb.x, ty = bb.y, tz = bb.z;
                    v[0] += 1.0f;
                    v[1] += sx; v[2] += sy; v[3] += sz;
                    v[4] += tx; v[5] += ty; v[6] += tz;
                    v[7] += w;
                    float wsx = w * sx, wsy = w * sy, wsz = w * sz;
                    v[8] += wsx; v[9] += wsy; v[10] += wsz;
                    v[11] += w * tx; v[12] += w * ty; v[13] += w * tz;
                    v[14] += wsx * tx; v[15] += wsx * ty; v[16] += wsx * tz;
                    v[17] += wsy * tx; v[18] += wsy * ty; v[19] += wsy * tz;
                    v[20] += wsz * tx; v[21] += wsz * ty; v[22] += wsz * tz;
                }
            } else {
                for (int j = lane8; j < cnt; j += 8) {
                    int2 p = sedge2[e0 + j];
                    if ((p.x & 63) != nl) continue;
                    unsigned n = ((unsigned)p.x) >> 6;
                    if (n >= (unsigned)N) continue;
                    float w = __int_as_float(p.y);
                    float4 a = s4[n];
                    float4 bb = t4[n];
                    float sx = a.x, sy = a.y, sz = a.z;
                    float tx = bb.x, ty = bb.y, tz = bb.z;
                    v[0] += 1.0f;
                    v[1] += sx; v[2] += sy; v[3] += sz;
                    v[4] += tx; v[5] += ty; v[6] += tz;
                    v[7] += w;
                    float wsx = w * sx, wsy = w * sy, wsz = w * sz;
                    v[8] += wsx; v[9] += wsy; v[10] += wsz;
                    v[11] += w * tx; v[12] += w * ty; v[13] += w * tz;
                    v[14] += wsx * tx; v[15] += wsx * ty; v[16] += wsx * tz;
                    v[17] += wsy * tx; v[18] += wsy * ty; v[19] += wsy * tz;
                    v[20] += wsz * tx; v[21] += wsz * ty; v[22] += wsz * tz;
                }
            }
        }
#pragma unroll
        for (int m = 1; m < 8; m <<= 1) {
#pragma unroll
            for (int i = 0; i < 23; ++i) v[i] += __shfl_xor(v[i], m, 64);
        }
        if (lane8 == 0 && node < N) {
#pragma unroll
            for (int i = 0; i < 23; ++i) momG[(size_t)i * N + node] = v[i];
        }
    }
}

// One thread per node: expand moments -> M, fp64 Kabsch, R/T/wnode.
__global__ void __launch_bounds__(256) k_kabsch2(const float* __restrict__ momG,
                                                 const float4* __restrict__ s4,
                                                 const float4* __restrict__ t4,
                                                 float* __restrict__ Rout,
                                                 float* __restrict__ Tout,
                                                 float* __restrict__ wnode, int N) {
    int i = blockIdx.x * blockDim.x + threadIdx.x;
    if (i >= N) return;
    float m[23];
#pragma unroll
    for (int k = 0; k < 23; ++k) m[k] = momG[(size_t)k * N + i];
    double cntv = (double)m[0];
    double inv = 1.0 / fmax(cntv, 1.0);
    double sb[3] = {m[1] * inv, m[2] * inv, m[3] * inv};
    double tb[3] = {m[4] * inv, m[5] * inv, m[6] * inv};
    double Sw = m[7];
    double Sws[3] = {m[8], m[9], m[10]};
    double Swt[3] = {m[11], m[12], m[13]};
    double M[3][3];
#pragma unroll
    for (int r = 0; r < 3; ++r)
#pragma unroll
        for (int c = 0; c < 3; ++c)
            M[r][c] = (double)m[14 + 3 * r + c]
                    - sb[r] * Swt[c] - Sws[r] * tb[c] + Sw * sb[r] * tb[c];
    double Rm[3][3];
    kabsch_from_M(M, Rm);
    double T0 = tb[0] - (Rm[0][0] * sb[0] + Rm[0][1] * sb[1] + Rm[0][2] * sb[2]);
    double T1 = tb[1] - (Rm[1][0] * sb[0] + Rm[1][1] * sb[1] + Rm[1][2] * sb[2]);
    double T2 = tb[2] - (Rm[2][0] * sb[0] + Rm[2][1] * sb[1] + Rm[2][2] * sb[2]);
#pragma unroll
    for (int r = 0; r < 3; ++r)
#pragma unroll
        for (int c = 0; c < 3; ++c)
            Rout[9 * (long long)i + 3 * r + c] = (float)Rm[r][c];
    Tout[3 * i + 0] = (float)T0;
    Tout[3 * i + 1] = (float)T1;
    Tout[3 * i + 2] = (float)T2;
    float4 a = s4[i];
    float4 q = t4[i];
    double x0 = Rm[0][0] * a.x + Rm[0][1] * a.y + Rm[0][2] * a.z + T0;
    double x1 = Rm[1][0] * a.x + Rm[1][1] * a.y + Rm[1][2] * a.z + T1;
    double x2 = Rm[2][0] * a.x + Rm[2][1] * a.y + Rm[2][2] * a.z + T2;
    double d0 = x0 - q.x, d1 = x1 - q.y, d2 = x2 - q.z;
    double dd = d0 * d0 + d1 * d1 + d2 * d2;
    wnode[i] = (float)((double)kSigma2 / (dd + (double)kSigma2));
}

// wout[e] = wnode[nbr[e]] (8 edges/thread, vector loads, float4 stores).
__global__ void __launch_bounds__(256) k_wgather(const void* __restrict__ ei,
                                                 const float* __restrict__ wnode,
                                                 float* __restrict__ wout,
                                                 const int* __restrict__ nz,
                                                 int E, int N) {
    int gid = blockIdx.x * blockDim.x + threadIdx.x;
    long long base = (long long)gid * 8;
    if (base >= E) return;
    int is64 = (*nz == 0);
    int n_[8];
    int full = (base + 8 <= (long long)E);
    if (full) {
        if (is64) {
            const long long* p = (const long long*)ei + (long long)E + base;
#pragma unroll
            for (int k = 0; k < 4; ++k) {
                longlong2 a = ((const longlong2*)p)[k];
                n_[2 * k] = (int)a.x;
                n_[2 * k + 1] = (int)a.y;
            }
        } else {
            const int* p = (const int*)ei + (long long)E + base;
            int4 a = ((const int4*)p)[0];
            int4 b = ((const int4*)p)[1];
            n_[0] = a.x; n_[1] = a.y; n_[2] = a.z; n_[3] = a.w;
            n_[4] = b.x; n_[5] = b.y; n_[6] = b.z; n_[7] = b.w;
        }
        float w[8];
#pragma unroll
        for (int k = 0; k < 8; ++k)
            w[k] = ((unsigned)n_[k] < (unsigned)N) ? wnode[n_[k]] : 1.0f;
        *(float4*)(wout + base) = make_float4(w[0], w[1], w[2], w[3]);
        *(float4*)(wout + base + 4) = make_float4(w[4], w[5], w[6], w[7]);
    } else {
#pragma unroll
        for (int k = 0; k < 8; ++k) {
            long long e = base + k;
            if (e < E) {
                int n = load_idx(ei, (long long)E + e, is64);
                wout[e] = ((unsigned)n < (unsigned)N) ? wnode[n] : 1.0f;
            }
        }
    }
}

// ---------------- fallback atomic path ----------------

__global__ void k_accum1(const void* __restrict__ ei, const float* __restrict__ src,
                         const float* __restrict__ tgt, float* __restrict__ cnt,
                         float* __restrict__ ssum, float* __restrict__ tsum,
                         const int* __restrict__ nz, int E, int N) {
    int e = blockIdx.x * blockDim.x + threadIdx.x;
    if (e >= E) return;
    int is64 = (*nz == 0);
    int d = load_idx(ei, e, is64);
    int n = load_idx(ei, (long long)E + e, is64);
    if ((unsigned)d >= (unsigned)N || (unsigned)n >= (unsigned)N) return;
    atomicAdd(&cnt[d], 1.0f);
    atomicAdd(&ssum[3 * d + 0], src[3 * n + 0]);
    atomicAdd(&ssum[3 * d + 1], src[3 * n + 1]);
    atomicAdd(&ssum[3 * d + 2], src[3 * n + 2]);
    atomicAdd(&tsum[3 * d + 0], tgt[3 * n + 0]);
    atomicAdd(&tsum[3 * d + 1], tgt[3 * n + 1]);
    atomicAdd(&tsum[3 * d + 2], tgt[3 * n + 2]);
}

__global__ void k_centers(float* __restrict__ cnt, float* __restrict__ ssum,
                          float* __restrict__ tsum, int N) {
    int i = blockIdx.x * blockDim.x + threadIdx.x;
    if (i >= N) return;
    float inv = 1.0f / fmaxf(cnt[i], 1.0f);
    ssum[3 * i + 0] *= inv; ssum[3 * i + 1] *= inv; ssum[3 * i + 2] *= inv;
    tsum[3 * i + 0] *= inv; tsum[3 * i + 1] *= inv; tsum[3 * i + 2] *= inv;
}

__global__ void k_accum2(const void* __restrict__ ei, const float* __restrict__ src,
                         const float* __restrict__ tgt, const float* __restrict__ ew,
                         const float* __restrict__ sc, const float* __restrict__ tc,
                         float* __restrict__ Mm, const int* __restrict__ nz, int E, int N) {
    int e = blockIdx.x * blockDim.x + threadIdx.x;
    if (e >= E) return;
    int is64 = (*nz == 0);
    int d = load_idx(ei, e, is64);
    int n = load_idx(ei, (long long)E + e, is64);
    if ((unsigned)d >= (unsigned)N || (unsigned)n >= (unsigned)N) return;
    float w = ew[e];
    float a0 = (src[3 * n + 0] - sc[3 * d + 0]) * w;
    float a1 = (src[3 * n + 1] - sc[3 * d + 1]) * w;
    float a2 = (src[3 * n + 2] - sc[3 * d + 2]) * w;
    float b0 = tgt[3 * n + 0] - tc[3 * d + 0];
    float b1 = tgt[3 * n + 1] - tc[3 * d + 1];
    float b2 = tgt[3 * n + 2] - tc[3 * d + 2];
    float* Md = Mm + 9 * (long long)d;
    atomicAdd(Md + 0, a0 * b0); atomicAdd(Md + 1, a0 * b1); atomicAdd(Md + 2, a0 * b2);
    atomicAdd(Md + 3, a1 * b0); atomicAdd(Md + 4, a1 * b1); atomicAdd(Md + 5, a1 * b2);
    atomicAdd(Md + 6, a2 * b0); atomicAdd(Md + 7, a2 * b1); atomicAdd(Md + 8, a2 * b2);
}

__global__ void k_kabsch(const float* __restrict__ Mm, const float* __restrict__ sc,
                         const float* __restrict__ tc, float* __restrict__ Rout,
                         float* __restrict__ Tout, int N) {
    int i = blockIdx.x * blockDim.x + threadIdx.x;
    if (i >= N) return;
    double M[3][3];
#pragma unroll
    for (int r = 0; r < 3; ++r)
#pragma unroll
        for (int c = 0; c < 3; ++c)
            M[r][c] = (double)Mm[9 * (long long)i + 3 * r + c];
    double Rm[3][3];
    kabsch_from_M(M, Rm);
    double s0 = sc[3 * i + 0], s1 = sc[3 * i + 1], s2 = sc[3 * i + 2];
    double t0 = tc[3 * i + 0], t1 = tc[3 * i + 1], t2 = tc[3 * i + 2];
#pragma unroll
    for (int r = 0; r < 3; ++r)
#pragma unroll
        for (int c = 0; c < 3; ++c)
            Rout[9 * (long long)i + 3 * r + c] = (float)Rm[r][c];
    Tout[3 * i + 0] = (float)(t0 - (Rm[0][0] * s0 + Rm[0][1] * s1 + Rm[0][2] * s2));
    Tout[3 * i + 1] = (float)(t1 - (Rm[1][0] * s0 + Rm[1][1] * s1 + Rm[1][2] * s2));
    Tout[3 * i + 2] = (float)(t2 - (Rm[2][0] * s0 + Rm[2][1] * s1 + Rm[2][2] * s2));
}

__global__ void k_weights_plain(const void* __restrict__ ei,
                                const float* __restrict__ src,
                                const float* __restrict__ tgt,
                                const float* __restrict__ R,
                                const float* __restrict__ T,
                                float* __restrict__ wout,
                                const int* __restrict__ nz, int E, int N) {
    int e = blockIdx.x * blockDim.x + threadIdx.x;
    if (e >= E) return;
    int is64 = (*nz == 0);
    int n = load_idx(ei, (long long)E + e, is64);
    float w = 1.0f;
    if ((unsigned)n < (unsigned)N) {
        float p0 = src[3 * n + 0], p1 = src[3 * n + 1], p2 = src[3 * n + 2];
        float q0 = tgt[3 * n + 0], q1 = tgt[3 * n + 1], q2 = tgt[3 * n + 2];
        const float* Rn = R + 9 * (long long)n;
        const float* Tn = T + 3 * (long long)n;
        float x0 = Rn[0] * p0 + Rn[1] * p1 + Rn[2] * p2 + Tn[0];
        float x1 = Rn[3] * p0 + Rn[4] * p1 + Rn[5] * p2 + Tn[1];
        float x2 = Rn[6] * p0 + Rn[7] * p1 + Rn[8] * p2 + Tn[2];
        float d0 = x0 - q0, d1 = x1 - q1, d2 = x2 - q2;
        float dd = d0 * d0 + d1 * d1 + d2 * d2;
        w = kSigma2 / (dd + kSigma2);
    }
    wout[e] = w;
}

extern "C" void kernel_launch(void* const* d_in, const int* in_sizes, int n_in,
                              void* d_out, int out_size, void* d_ws, size_t ws_size,
                              hipStream_t stream) {
    const float* src = (const float*)d_in[0];
    const float* tgt = (const float*)d_in[1];
    const void* ei = d_in[2];
    const float* ew = (const float*)d_in[3];
    int N = in_sizes[0] / 3;
    int E = in_sizes[3];

    float* out = (float*)d_out;
    float* Rout = out;
    float* Tout = out + (size_t)9 * N;
    float* Wout = out + (size_t)12 * N;

    int eb = (E + 255) / 256;
    int nb = (N + 255) / 256;
    int nbuckets = (N + 63) / 64;            // 64-node fine buckets
    int ncoarse = (nbuckets + 127) / 128;    // 8192-node coarse buckets
    int tiles = (int)(((long long)E + 2047) / 2048);
    int tiles16 = (int)(((long long)E + 16383) / 16384);
    int wb8 = (int)(((long long)E + 2047) / 2048);

    // ws layout: [nz(16) | btot16 | cur16 | curC16(256) | boff | pad4 |
    //             sedge1 (E int2) | [sedge2 (E int2)] | s4 | t4 | wnode(N) | momG(23N)]
    size_t ctrl_ints = 16 + (size_t)nbuckets * 16 * 2 + 256 + (nbuckets + 1);
    ctrl_ints = (ctrl_ints + 3) & ~(size_t)3;
    size_t after1 = ctrl_ints + 2 * (size_t)E;
    after1 = (after1 + 3) & ~(size_t)3;
    size_t after2 = after1 + 2 * (size_t)E;
    after2 = (after2 + 3) & ~(size_t)3;
    size_t tail_ints = 8 * (size_t)N + (size_t)N + 23 * (size_t)N;
    size_t needA = (after2 + tail_ints) * sizeof(int);
    size_t needB = (after1 + tail_ints) * sizeof(int);

    if (N <= 131072 && nbuckets <= 2048 && ws_size >= needB) {
        int twolevel = (ws_size >= needA) ? 1 : 0;
        int* nz = (int*)d_ws;
        int* btot16 = nz + 16;
        int* cur16 = btot16 + (size_t)nbuckets * 16;
        int* curC16 = cur16 + (size_t)nbuckets * 16;
        int* boff = curC16 + 256;
        int2* sedge1 = (int2*)((int*)d_ws + ctrl_ints);
        size_t tail_base = twolevel ? after2 : after1;
        int2* sedge2 = twolevel ? (int2*)((int*)d_ws + after1) : sedge1;
        float4* s4 = (float4*)((int*)d_ws + tail_base);
        float4* t4 = s4 + N;
        float* wnode = (float*)(t4 + N);
        float* momG = wnode + N;

        hipMemsetAsync(d_ws, 0, ctrl_ints * sizeof(int), stream);

        k_detect<<<1, 256, 0, stream>>>((const int*)ei, E, nz);
        k_pack<<<nb, 256, 0, stream>>>(src, tgt, s4, t4, N);
        k_bhist<<<tiles16, 256, 0, stream>>>(ei, btot16, nz, E, N, nbuckets);
        k_scan<<<1, 1024, 0, stream>>>(btot16, boff, cur16, curC16, nbuckets);
        if (twolevel) {
            k_cscatter<<<tiles, 256, 0, stream>>>(ei, ew, curC16, sedge1, nz, E, N, ncoarse);
            k_fscatter<<<tiles, 256, 0, stream>>>(sedge1, cur16, boff, sedge2, E, nbuckets, ncoarse);
        } else {
            k_binscatter<<<tiles, 256, 0, stream>>>(ei, ew, cur16, sedge2, nz, E, N, nbuckets);
        }
        k_sortmoment<<<nbuckets, 256, 0, stream>>>(boff, sedge2, s4, t4, momG, N);
        k_kabsch2<<<nb, 256, 0, stream>>>(momG, s4, t4, Rout, Tout, wnode, N);
        k_wgather<<<wb8, 256, 0, stream>>>(ei, wnode, Wout, nz, E, N);
    } else {
        // fallback: atomic path
        float* cnt = (float*)d_ws;
        float* ssum = cnt + N;
        float* tsum = ssum + 3 * (size_t)N;
        float* Mm = tsum + 3 * (size_t)N;
        int* nz = (int*)(Mm + 9 * (size_t)N);
        size_t ws_bytes = (size_t)16 * N * sizeof(float) + 16;
        hipMemsetAsync(d_ws, 0, ws_bytes, stream);
        k_detect<<<1, 256, 0, stream>>>((const int*)ei, E, nz);
        k_accum1<<<eb, 256, 0, stream>>>(ei, src, tgt, cnt, ssum, tsum, nz, E, N);
        k_centers<<<nb, 256, 0, stream>>>(cnt, ssum, tsum, N);
        k_accum2<<<eb, 256, 0, stream>>>(ei, src, tgt, ew, ssum, tsum, Mm, nz, E, N);
        k_kabsch<<<nb, 256, 0, stream>>>(Mm, ssum, tsum, Rout, Tout, N);
        k_weights_plain<<<eb, 256, 0, stream>>>(ei, src, tgt, Rout, Tout, Wout, nz, E, N);
    }
}

// Round 11
// 261.436 us; speedup vs baseline: 2.6226x; 1.0021x over previous
//
#include <hip/hip_runtime.h>
#include <math.h>

static constexpr float kSigma2 = 0.05f * 0.05f;
static constexpr int kCap2 = 2560;  // max edges per 64-node bucket in fused LDS sort

__device__ __forceinline__ int load_idx(const void* ei, long long j, int is64) {
    if (is64) return (int)(((const long long*)ei)[j]);
    return ((const int*)ei)[j];
}

// Detect whether edge_index is int64 (all odd int32 words zero) or int32.
__global__ void k_detect(const int* __restrict__ ei32, int E, int* __restrict__ nz) {
    int t = threadIdx.x;
    int lim = E < 2048 ? E : 2048;
    int acc = 0;
    for (int k = t; k < lim; k += blockDim.x) acc |= ei32[2 * k + 1];
    if (acc) atomicOr(nz, 1);
}

// Pack points into float4 arrays for vector gathers.
__global__ void k_pack(const float* __restrict__ src, const float* __restrict__ tgt,
                       float4* __restrict__ s4, float4* __restrict__ t4, int N) {
    int i = blockIdx.x * blockDim.x + threadIdx.x;
    if (i >= N) return;
    s4[i] = make_float4(src[3 * i + 0], src[3 * i + 1], src[3 * i + 2], 0.0f);
    t4[i] = make_float4(tgt[3 * i + 0], tgt[3 * i + 1], tgt[3 * i + 2], 0.0f);
}

// ---------------- shared Kabsch core (fp64, Jacobi on M^T M) ----------------
__device__ void kabsch_from_M(const double M[3][3], double Rm[3][3]) {
    Rm[0][0] = 1; Rm[0][1] = 0; Rm[0][2] = 0;
    Rm[1][0] = 0; Rm[1][1] = 1; Rm[1][2] = 0;
    Rm[2][0] = 0; Rm[2][1] = 0; Rm[2][2] = 1;

    double frob2 = 0.0;
#pragma unroll
    for (int r = 0; r < 3; ++r)
#pragma unroll
        for (int c = 0; c < 3; ++c) frob2 += M[r][c] * M[r][c];
    if (frob2 <= 1e-80) return;

    double A[3][3];
#pragma unroll
    for (int r = 0; r < 3; ++r)
#pragma unroll
        for (int c = 0; c < 3; ++c) {
            double s = 0.0;
#pragma unroll
            for (int k = 0; k < 3; ++k) s += M[k][r] * M[k][c];
            A[r][c] = s;
        }
    double V[3][3] = {{1, 0, 0}, {0, 1, 0}, {0, 0, 1}};
    const int PL[3] = {0, 0, 1};
    const int QL[3] = {1, 2, 2};
    for (int sweep = 0; sweep < 15; ++sweep) {
        double off = fabs(A[0][1]) + fabs(A[0][2]) + fabs(A[1][2]);
        if (off == 0.0) break;
        for (int pi = 0; pi < 3; ++pi) {
            int p = PL[pi], q = QL[pi], r3 = 3 - p - q;
            double apq = A[p][q];
            if (apq == 0.0) continue;
            double theta = (A[q][q] - A[p][p]) / (2.0 * apq);
            double t = copysign(1.0, theta) / (fabs(theta) + sqrt(theta * theta + 1.0));
            double c = 1.0 / sqrt(t * t + 1.0);
            double s = t * c;
            A[p][p] -= t * apq;
            A[q][q] += t * apq;
            A[p][q] = 0.0; A[q][p] = 0.0;
            double arp = A[r3][p], arq = A[r3][q];
            A[r3][p] = c * arp - s * arq; A[p][r3] = A[r3][p];
            A[r3][q] = s * arp + c * arq; A[q][r3] = A[r3][q];
#pragma unroll
            for (int k = 0; k < 3; ++k) {
                double vp = V[k][p], vq = V[k][q];
                V[k][p] = c * vp - s * vq;
                V[k][q] = s * vp + c * vq;
            }
        }
    }
    double lam[3] = {A[0][0], A[1][1], A[2][2]};
    int id0 = 0, id1 = 1, id2 = 2, tt;
    if (lam[id0] < lam[id1]) { tt = id0; id0 = id1; id1 = tt; }
    if (lam[id0] < lam[id2]) { tt = id0; id0 = id2; id2 = tt; }
    if (lam[id1] < lam[id2]) { tt = id1; id1 = id2; id2 = tt; }
    double v1[3] = {V[0][id0], V[1][id0], V[2][id0]};
    double v2[3] = {V[0][id1], V[1][id1], V[2][id1]};
    double v3[3] = {V[0][id2], V[1][id2], V[2][id2]};

    double b1[3], b2[3];
#pragma unroll
    for (int r = 0; r < 3; ++r) {
        b1[r] = M[r][0] * v1[0] + M[r][1] * v1[1] + M[r][2] * v1[2];
        b2[r] = M[r][0] * v2[0] + M[r][1] * v2[1] + M[r][2] * v2[2];
    }
    double n1 = sqrt(b1[0] * b1[0] + b1[1] * b1[1] + b1[2] * b1[2]);
    if (n1 <= 1e-150) return;
    double u1[3] = {b1[0] / n1, b1[1] / n1, b1[2] / n1};
    double dot = u1[0] * b2[0] + u1[1] * b2[1] + u1[2] * b2[2];
    double w2[3] = {b2[0] - dot * u1[0], b2[1] - dot * u1[1], b2[2] - dot * u1[2]};
    double n2 = sqrt(w2[0] * w2[0] + w2[1] * w2[1] + w2[2] * w2[2]);
    double u2[3];
    if (n2 > n1 * 1e-12) {
        u2[0] = w2[0] / n2; u2[1] = w2[1] / n2; u2[2] = w2[2] / n2;
    } else {
        double ex0 = (fabs(u1[0]) < 0.9) ? 1.0 : 0.0;
        double ex1 = 1.0 - ex0;
        double cx = u1[1] * 0.0 - u1[2] * ex1;
        double cy = u1[2] * ex0 - u1[0] * 0.0;
        double cz = u1[0] * ex1 - u1[1] * ex0;
        double cn = sqrt(cx * cx + cy * cy + cz * cz);
        u2[0] = cx / cn; u2[1] = cy / cn; u2[2] = cz / cn;
    }
    double u3[3] = {u1[1] * u2[2] - u1[2] * u2[1],
                    u1[2] * u2[0] - u1[0] * u2[2],
                    u1[0] * u2[1] - u1[1] * u2[0]};
    double dV = v1[0] * (v2[1] * v3[2] - v2[2] * v3[1])
              - v1[1] * (v2[0] * v3[2] - v2[2] * v3[0])
              + v1[2] * (v2[0] * v3[1] - v2[1] * v3[0]);
    dV = (dV >= 0.0) ? 1.0 : -1.0;
#pragma unroll
    for (int r = 0; r < 3; ++r)
#pragma unroll
        for (int c = 0; c < 3; ++c)
            Rm[r][c] = u1[r] * v1[c] + u2[r] * v2[c] + dV * u3[r] * v3[c];
}

// ---------------- bucketed counting-sort path ----------------
// fine bucket = dst >> 6 (64 nodes). final payload: x = (nbr<<6)|(dst&63), y = w bits.
// coarse bucket = dst >> 13 (128 fine buckets). intermediate payload:
//   x = (nbr<<13)|(dst&8191), y = w bits.

// 16384 edges per block (64/thread): amortizes the global-atomic histogram flush.
__global__ void __launch_bounds__(256) k_bhist(const void* __restrict__ ei,
                                               int* __restrict__ btot16,
                                               const int* __restrict__ nz,
                                               int E, int N, int nbuckets) {
    __shared__ int lhist[2048];
    int t = threadIdx.x;
    long long tile = (long long)blockIdx.x * 16384;
    long long remll = (long long)E - tile;
    int rem = (remll < 16384) ? (int)remll : 16384;
    int is64 = (*nz == 0);
    for (int i = t; i < 2048; i += 256) lhist[i] = 0;
    __syncthreads();
    if (rem == 16384) {
        for (int it = 0; it < 8; ++it) {
            long long base = tile + (long long)it * 2048 + (long long)t * 8;
            int d[8];
            if (is64) {
                const long long* p = (const long long*)ei + base;
#pragma unroll
                for (int k = 0; k < 4; ++k) {
                    longlong2 v = ((const longlong2*)p)[k];
                    d[2 * k] = (int)v.x;
                    d[2 * k + 1] = (int)v.y;
                }
            } else {
                const int* p = (const int*)ei + base;
                int4 a = ((const int4*)p)[0];
                int4 bb = ((const int4*)p)[1];
                d[0] = a.x; d[1] = a.y; d[2] = a.z; d[3] = a.w;
                d[4] = bb.x; d[5] = bb.y; d[6] = bb.z; d[7] = bb.w;
            }
#pragma unroll
            for (int k = 0; k < 8; ++k)
                if ((unsigned)d[k] < (unsigned)N) atomicAdd(&lhist[d[k] >> 6], 1);
        }
    } else {
        for (int idx = t; idx < rem; idx += 256) {
            int d = load_idx(ei, tile + idx, is64);
            if ((unsigned)d < (unsigned)N) atomicAdd(&lhist[d >> 6], 1);
        }
    }
    __syncthreads();
    for (int b = t; b < 2048; b += 256) {
        int c = lhist[b];
        if (c > 0 && b < nbuckets) atomicAdd(&btot16[b * 16], c);
    }
}

// fine exclusive scan (up to 2048 bins, 1024 thr x 2) -> boff, cur16, curC16.
__global__ void k_scan(const int* __restrict__ btot16, int* __restrict__ boff,
                       int* __restrict__ cur16, int* __restrict__ curC16, int nbuckets) {
    __shared__ int sm[2048];
    int t = threadIdx.x;
    int v0 = (t < nbuckets) ? btot16[t * 16] : 0;
    int v1 = (t + 1024 < nbuckets) ? btot16[(t + 1024) * 16] : 0;
    sm[t] = v0;
    sm[t + 1024] = v1;
    __syncthreads();
    for (int s = 1; s < 2048; s <<= 1) {
        int x0 = (t >= s) ? sm[t - s] : 0;
        int x1 = (t + 1024 >= s) ? sm[t + 1024 - s] : 0;
        __syncthreads();
        sm[t] += x0;
        sm[t + 1024] += x1;
        __syncthreads();
    }
    if (t < nbuckets) {
        int ex = sm[t] - v0;
        boff[t] = ex;
        cur16[t * 16] = ex;
        if ((t & 127) == 0) curC16[(t >> 7) * 16] = ex;
    }
    int t2 = t + 1024;
    if (t2 < nbuckets) {
        int ex = sm[t2] - v1;
        boff[t2] = ex;
        cur16[t2 * 16] = ex;
        if ((t2 & 127) == 0) curC16[(t2 >> 7) * 16] = ex;
    }
    if (t == nbuckets - 1) boff[nbuckets] = sm[t];
    if (t2 == nbuckets - 1) boff[nbuckets] = sm[t2];
}

// Level-1 scatter: raw edges -> coarse-sorted sedge1 (<=16 bins, long runs).
// Wave-ballot ranking: no per-edge LDS atomics; 16 LDS-row updates per wave
// per round + 128 LDS atomics per tile for cross-wave bases.
__global__ void __launch_bounds__(256) k_cscatter(const void* __restrict__ ei,
                                                  const float* __restrict__ ew,
                                                  int* __restrict__ curC16,
                                                  int2* __restrict__ sedge1,
                                                  const int* __restrict__ nz,
                                                  int E, int N, int ncoarse) {
    __shared__ int2 stage[2048];
    __shared__ unsigned char binOf[2048];
    __shared__ int hist[16];
    __shared__ int excl[16];
    __shared__ int gbase[16];
    __shared__ int woffs[4][16];   // per-wave running bin counts
    __shared__ int wbase[4][16];   // per-wave base within bin (tile-local)
    int t = threadIdx.x;
    int w = t >> 6, lane = t & 63;
    unsigned long long lanebelow = ((unsigned long long)1 << lane) - 1;
    long long tile = (long long)blockIdx.x * 2048;
    long long remll = (long long)E - tile;
    int rem = (remll < 2048) ? (int)remll : 2048;
    int is64 = (*nz == 0);
    if (t < 16) hist[t] = 0;
    if (t < 64) ((int*)woffs)[t] = 0;
    __syncthreads();

    int dd[8], nn[8];
    float ww[8];
    int cnt8 = 0;
    if (rem == 2048) {
        if (is64) {
            const long long* pd = (const long long*)ei + tile + (long long)t * 8;
            const long long* pn = (const long long*)ei + (long long)E + tile + (long long)t * 8;
#pragma unroll
            for (int k = 0; k < 4; ++k) {
                longlong2 vd = ((const longlong2*)pd)[k];
                longlong2 vn = ((const longlong2*)pn)[k];
                dd[2 * k] = (int)vd.x; dd[2 * k + 1] = (int)vd.y;
                nn[2 * k] = (int)vn.x; nn[2 * k + 1] = (int)vn.y;
            }
        } else {
            const int* pd = (const int*)ei + tile + (long long)t * 8;
            const int* pn = (const int*)ei + (long long)E + tile + (long long)t * 8;
            int4 a = ((const int4*)pd)[0], b = ((const int4*)pd)[1];
            int4 c = ((const int4*)pn)[0], d = ((const int4*)pn)[1];
            dd[0] = a.x; dd[1] = a.y; dd[2] = a.z; dd[3] = a.w;
            dd[4] = b.x; dd[5] = b.y; dd[6] = b.z; dd[7] = b.w;
            nn[0] = c.x; nn[1] = c.y; nn[2] = c.z; nn[3] = c.w;
            nn[4] = d.x; nn[5] = d.y; nn[6] = d.z; nn[7] = d.w;
        }
        const float* pw = ew + tile + (long long)t * 8;
        float4 wa = ((const float4*)pw)[0], wb = ((const float4*)pw)[1];
        ww[0] = wa.x; ww[1] = wa.y; ww[2] = wa.z; ww[3] = wa.w;
        ww[4] = wb.x; ww[5] = wb.y; ww[6] = wb.z; ww[7] = wb.w;
        cnt8 = 8;
    } else {
        int base = t * 8;
#pragma unroll
        for (int k = 0; k < 8; ++k) {
            int idx = base + k;
            if (idx < rem) {
                long long e = tile + idx;
                dd[cnt8] = load_idx(ei, e, is64);
                nn[cnt8] = load_idx(ei, (long long)E + e, is64);
                ww[cnt8] = ew[e];
                ++cnt8;
            }
        }
    }

    // ballot-ranked binning: per round, each lane handles one edge
    int mybin[8];
    int mypos[8];   // position within this wave's portion of the bin
    int2 mypay[8];
#pragma unroll
    for (int k = 0; k < 8; ++k) {
        int bin = -1;
        if (k < cnt8) {
            int d = dd[k];
            if ((unsigned)d < (unsigned)N) {
                int n = nn[k];
                if ((unsigned)n >= (unsigned)N) n = N;  // sentinel; filtered later
                bin = d >> 13;
                mypay[k].x = (n << 13) | (d & 8191);
                mypay[k].y = __float_as_int(ww[k]);
            }
        }
        mybin[k] = bin;
        unsigned long long valid = __ballot(bin >= 0);
        unsigned long long v0 = __ballot(bin & 1);
        unsigned long long v1 = __ballot(bin & 2);
        unsigned long long v2 = __ballot(bin & 4);
        unsigned long long v3 = __ballot(bin & 8);
        if (bin >= 0) {
            unsigned long long m = valid;
            m &= (bin & 1) ? v0 : ~v0;
            m &= (bin & 2) ? v1 : ~v1;
            m &= (bin & 4) ? v2 : ~v2;
            m &= (bin & 8) ? v3 : ~v3;
            int rank = __popcll(m & lanebelow);
            int cnt = __popcll(m);
            int cur = woffs[w][bin];
            mypos[k] = cur + rank;
            if (rank == 0) woffs[w][bin] = cur + cnt;
        }
    }
    __syncthreads();
    // cross-wave bases: 64 LDS atomics
    if (t < 64) {
        int w2 = t >> 4, b = t & 15;
        int c = woffs[w2][b];
        wbase[w2][b] = (c > 0) ? atomicAdd(&hist[b], c) : 0;
    }
    __syncthreads();
    if (t == 0) {
        int run = 0;
#pragma unroll
        for (int c = 0; c < 16; ++c) { excl[c] = run; run += hist[c]; }
    }
    __syncthreads();
#pragma unroll
    for (int k = 0; k < 8; ++k) {
        if (mybin[k] >= 0) {
            int lpos = excl[mybin[k]] + wbase[w][mybin[k]] + mypos[k];
            stage[lpos] = mypay[k];
            binOf[lpos] = (unsigned char)mybin[k];
        }
    }
    if (t < 16) {
        int c = hist[t];
        gbase[t] = (c > 0 && t < ncoarse) ? atomicAdd(&curC16[t * 16], c) : 0;
    }
    __syncthreads();
    int total = excl[15] + hist[15];
    for (int lpos = t; lpos < total; lpos += 256) {
        int c = binOf[lpos];
        sedge1[gbase[c] + (lpos - excl[c])] = stage[lpos];
    }
}

// Level-2 scatter: coarse-sorted sedge1 -> fine-sorted sedge2 (repacks payload).
// Windowed ranking relative to the tile's first coarse bucket (x128 fine bins).
__global__ void __launch_bounds__(256) k_fscatter(const int2* __restrict__ sedge1,
                                                  int* __restrict__ cur16,
                                                  const int* __restrict__ boff,
                                                  int2* __restrict__ sedge2,
                                                  int E, int nbuckets, int ncoarse) {
    __shared__ int2 stage[2048];
    __shared__ unsigned short binOf[2048];
    __shared__ int lhist[1024];
    __shared__ int lincl[1024];
    __shared__ int gbase[1024];
    __shared__ int co[17];
    __shared__ int s_clo, s_W;
    int t = threadIdx.x;
    if (t <= ncoarse) {
        int f = t * 128;
        if (f > nbuckets) f = nbuckets;
        co[t] = boff[f];
    }
    __syncthreads();
    int Ev = co[ncoarse];
    long long tile = (long long)blockIdx.x * 2048;
    if (tile >= Ev) return;
    long long remll = (long long)Ev - tile;
    int rem = (remll < 2048) ? (int)remll : 2048;

    if (t == 0) {
        long long p0 = tile, p1 = tile + rem - 1;
        int c0 = 0;
        while (c0 + 1 < ncoarse && p0 >= co[c0 + 1]) ++c0;
        int c1 = c0;
        while (c1 + 1 < ncoarse && p1 >= co[c1 + 1]) ++c1;
        s_clo = c0;
        s_W = (c1 - c0 + 1) * 128;
    }
    __syncthreads();
    int clo = s_clo, W = s_W;

    int2 pay[8];
    int cnt8 = 0;
    if (rem == 2048) {
        const int4* p4 = (const int4*)(sedge1 + tile + (long long)t * 8);
#pragma unroll
        for (int k = 0; k < 4; ++k) {
            int4 v = p4[k];
            pay[2 * k].x = v.x; pay[2 * k].y = v.y;
            pay[2 * k + 1].x = v.z; pay[2 * k + 1].y = v.w;
        }
        cnt8 = 8;
    } else {
        int base = t * 8;
#pragma unroll
        for (int k = 0; k < 8; ++k) {
            int idx = base + k;
            if (idx < rem) pay[cnt8++] = sedge1[tile + idx];
        }
    }

    if (W > 1024) {
        // slow path (essentially never taken): per-edge global cursor bump
        for (int k = 0; k < cnt8; ++k) {
            long long pos = tile + t * 8 + k;
            int c = clo;
            while (c + 1 < ncoarse && pos >= co[c + 1]) ++c;
            int x1 = pay[k].x;
            unsigned nbr = ((unsigned)x1) >> 13;
            int fin = c * 128 + ((x1 & 8191) >> 6);
            int gpos = atomicAdd(&cur16[fin * 16], 1);
            int2 out;
            out.x = (int)((nbr << 6) | (unsigned)(x1 & 63));
            out.y = pay[k].y;
            sedge2[gpos] = out;
        }
        return;
    }

    for (int i = t; i < W; i += 256) lhist[i] = 0;
    __syncthreads();

    int mybin[8], myrank[8];
    int2 mypay[8];
#pragma unroll
    for (int k = 0; k < 8; ++k) {
        mybin[k] = -1;
        if (k < cnt8) {
            long long pos = tile + t * 8 + k;
            int c = clo;
            while (c + 1 < ncoarse && pos >= co[c + 1]) ++c;
            int x1 = pay[k].x;
            unsigned nbr = ((unsigned)x1) >> 13;
            int rel = (c - clo) * 128 + ((x1 & 8191) >> 6);
            mybin[k] = rel;
            myrank[k] = atomicAdd(&lhist[rel], 1);
            mypay[k].x = (int)((nbr << 6) | (unsigned)(x1 & 63));
            mypay[k].y = pay[k].y;
        }
    }
    __syncthreads();
    for (int i = t; i < W; i += 256) lincl[i] = lhist[i];
    __syncthreads();
    for (int s = 1; s < W; s <<= 1) {
        int tmp[4];
        int cj = 0;
        for (int i = t; i < W; i += 256) tmp[cj++] = (i >= s) ? lincl[i - s] : 0;
        __syncthreads();
        cj = 0;
        for (int i = t; i < W; i += 256) lincl[i] += tmp[cj++];
        __syncthreads();
    }
#pragma unroll
    for (int k = 0; k < 8; ++k) {
        if (mybin[k] >= 0) {
            int ex = lincl[mybin[k]] - lhist[mybin[k]];
            int lpos = ex + myrank[k];
            stage[lpos] = mypay[k];
            binOf[lpos] = (unsigned short)mybin[k];
        }
    }
    __syncthreads();
    for (int rel = t; rel < W; rel += 256) {
        int c = lhist[rel];
        int fin = clo * 128 + rel;
        gbase[rel] = (c > 0 && fin < nbuckets) ? atomicAdd(&cur16[fin * 16], c) : 0;
    }
    __syncthreads();
    int total = lincl[W - 1];
    for (int lpos = t; lpos < total; lpos += 256) {
        int rel = binOf[lpos];
        int ex = lincl[rel] - lhist[rel];
        sedge2[gbase[rel] + (lpos - ex)] = stage[lpos];
    }
}

// Single-level scatter (fallback when ws can't hold two edge buffers).
__global__ void __launch_bounds__(256) k_binscatter(const void* __restrict__ ei,
                                                    const float* __restrict__ ew,
                                                    int* __restrict__ cur16,
                                                    int2* __restrict__ sedge,
                                                    const int* __restrict__ nz,
                                                    int E, int N, int nbuckets) {
    __shared__ int2 stage[2048];
    __shared__ unsigned short binOf[2048];
    __shared__ int lhist[2048];
    __shared__ int lincl[2048];
    __shared__ int gbase[2048];
    int t = threadIdx.x;
    long long tile = (long long)blockIdx.x * 2048;
    long long remll = (long long)E - tile;
    int rem = (remll < 2048) ? (int)remll : 2048;
    int is64 = (*nz == 0);
    for (int i = t; i < 2048; i += 256) lhist[i] = 0;
    __syncthreads();

    int dd[8], nn[8];
    float ww[8];
    int cnt8 = 0;
    if (rem == 2048) {
        if (is64) {
            const long long* pd = (const long long*)ei + tile + (long long)t * 8;
            const long long* pn = (const long long*)ei + (long long)E + tile + (long long)t * 8;
#pragma unroll
            for (int k = 0; k < 4; ++k) {
                longlong2 vd = ((const longlong2*)pd)[k];
                longlong2 vn = ((const longlong2*)pn)[k];
                dd[2 * k] = (int)vd.x; dd[2 * k + 1] = (int)vd.y;
                nn[2 * k] = (int)vn.x; nn[2 * k + 1] = (int)vn.y;
            }
        } else {
            const int* pd = (const int*)ei + tile + (long long)t * 8;
            const int* pn = (const int*)ei + (long long)E + tile + (long long)t * 8;
            int4 a = ((const int4*)pd)[0], b = ((const int4*)pd)[1];
            int4 c = ((const int4*)pn)[0], d = ((const int4*)pn)[1];
            dd[0] = a.x; dd[1] = a.y; dd[2] = a.z; dd[3] = a.w;
            dd[4] = b.x; dd[5] = b.y; dd[6] = b.z; dd[7] = b.w;
            nn[0] = c.x; nn[1] = c.y; nn[2] = c.z; nn[3] = c.w;
            nn[4] = d.x; nn[5] = d.y; nn[6] = d.z; nn[7] = d.w;
        }
        const float* pw = ew + tile + (long long)t * 8;
        float4 wa = ((const float4*)pw)[0], wb = ((const float4*)pw)[1];
        ww[0] = wa.x; ww[1] = wa.y; ww[2] = wa.z; ww[3] = wa.w;
        ww[4] = wb.x; ww[5] = wb.y; ww[6] = wb.z; ww[7] = wb.w;
        cnt8 = 8;
    } else {
        int base = t * 8;
#pragma unroll
        for (int k = 0; k < 8; ++k) {
            int idx = base + k;
            if (idx < rem) {
                long long e = tile + idx;
                dd[cnt8] = load_idx(ei, e, is64);
                nn[cnt8] = load_idx(ei, (long long)E + e, is64);
                ww[cnt8] = ew[e];
                ++cnt8;
            }
        }
    }

    int mybin[8];
    int myrank[8];
    int2 mypay[8];
#pragma unroll
    for (int k = 0; k < 8; ++k) {
        mybin[k] = -1;
        if (k < cnt8) {
            int d = dd[k];
            if ((unsigned)d < (unsigned)N) {
                int n = nn[k];
                if ((unsigned)n >= (unsigned)N) n = N;  // sentinel
                int bb = d >> 6;
                mybin[k] = bb;
                myrank[k] = atomicAdd(&lhist[bb], 1);
                mypay[k].x = (n << 6) | (d & 63);
                mypay[k].y = __float_as_int(ww[k]);
            }
        }
    }
    __syncthreads();
    for (int i = t; i < 2048; i += 256) lincl[i] = lhist[i];
    __syncthreads();
    for (int s = 1; s < 2048; s <<= 1) {
        int tmp[8];
#pragma unroll
        for (int j = 0; j < 8; ++j) {
            int i = (j << 8) + t;
            tmp[j] = (i >= s) ? lincl[i - s] : 0;
        }
        __syncthreads();
#pragma unroll
        for (int j = 0; j < 8; ++j) {
            int i = (j << 8) + t;
            lincl[i] += tmp[j];
        }
        __syncthreads();
    }
#pragma unroll
    for (int k = 0; k < 8; ++k) {
        if (mybin[k] >= 0) {
            int ex = lincl[mybin[k]] - lhist[mybin[k]];
            int lpos = ex + myrank[k];
            stage[lpos] = mypay[k];
            binOf[lpos] = (unsigned short)mybin[k];
        }
    }
    __syncthreads();
    for (int bb = t; bb < 2048; bb += 256) {
        int c = lhist[bb];
        gbase[bb] = (c > 0 && bb < nbuckets) ? atomicAdd(&cur16[bb * 16], c) : 0;
    }
    __syncthreads();
    int total = lincl[2047];
    for (int lpos = t; lpos < total; lpos += 256) {
        int bb = binOf[lpos];
        int ex = lincl[bb] - lhist[bb];
        sedge[gbase[bb] + (lpos - ex)] = stage[lpos];
    }
}

// Fused per-bucket sort (64 nodes, in LDS, no write-back) + 23-moment pass.
// Writes moments to SoA momG[k*N + n].
__global__ void __launch_bounds__(256) k_sortmoment(const int* __restrict__ boff,
                                                    const int2* __restrict__ sedge2,
                                                    const float4* __restrict__ s4,
                                                    const float4* __restrict__ t4,
                                                    float* __restrict__ momG, int N) {
    __shared__ int2 sorted[kCap2];
    __shared__ int hist[64];
    __shared__ int scanbuf[64];
    __shared__ int offs[64];
    __shared__ int cur[64];
    int b = blockIdx.x, t = threadIdx.x;
    int e0 = boff[b], e1 = boff[b + 1];
    int cnt = e1 - e0;
    if (t < 64) hist[t] = 0;
    __syncthreads();
    int inlds = (cnt <= kCap2);
    if (inlds) {
        for (int i = t; i < cnt; i += 256)
            atomicAdd(&hist[sedge2[e0 + i].x & 63], 1);
        __syncthreads();
        if (t < 64) scanbuf[t] = hist[t];
        __syncthreads();
        for (int s = 1; s < 64; s <<= 1) {
            int v = 0;
            if (t < 64 && t >= s) v = scanbuf[t - s];
            __syncthreads();
            if (t < 64) scanbuf[t] += v;
            __syncthreads();
        }
        if (t < 64) {
            int ex = scanbuf[t] - hist[t];
            offs[t] = ex;
            cur[t] = ex;
        }
        __syncthreads();
        for (int i = t; i < cnt; i += 256) {
            int2 p = sedge2[e0 + i];
            int r = atomicAdd(&cur[p.x & 63], 1);
            sorted[r] = p;
        }
        __syncthreads();
    }
    int oct = t >> 3, lane8 = t & 7;
#pragma unroll
    for (int rr = 0; rr < 2; ++rr) {
        int nl = oct + rr * 32;
        long long node = (long long)b * 64 + nl;
        float v[23];
#pragma unroll
        for (int i = 0; i < 23; ++i) v[i] = 0.0f;
        if (node < N) {
            if (inlds) {
                int start = offs[nl];
                int cn = hist[nl];
                for (int j = lane8; j < cn; j += 8) {
                    int2 p = sorted[start + j];
                    unsigned n = ((unsigned)p.x) >> 6;
                    if (n >= (unsigned)N) continue;
                    float w = __int_as_float(p.y);
                    float4 a = s4[n];
                    float4 bb = t4[n];
                    float sx = a.x, sy = a.y, sz = a.z;
                    float tx = bb.x, ty = bb.y, tz = bb.z;
                    v[0] += 1.0f;
                    v[1] += sx; v[2] += sy; v[3] += sz;
                    v[4] += tx; v[5] += ty; v[6] += tz;
                    v[7] += w;
                    float wsx = w * sx, wsy = w * sy, wsz = w * sz;
                    v[8] += wsx; v[9] += wsy; v[10] += wsz;
                    v[11] += w * tx; v[12] += w * ty; v[13] += w * tz;
                    v[14] += wsx * tx; v[15] += wsx * ty; v[16] += wsx * tz;
                    v[17] += wsy * tx; v[18] += wsy * ty; v[19] += wsy * tz;
                    v[20] += wsz * tx; v[21] += wsz * ty; v[22] += wsz * tz;
                }
            } else {
                for (int j = lane8; j < cnt; j += 8) {
                    int2 p = sedge2[e0 + j];
                    if ((p.x & 63) != nl) continue;
                    unsigned n = ((unsigned)p.x) >> 6;
                    if (n >= (unsigned)N) continue;
                    float w = __int_as_float(p.y);
                    float4 a = s4[n];
                    float4 bb = t4[n];
                    float sx = a.x, sy = a.y, sz = a.z;
                    float tx = bb.x, ty = bb.y, tz = bb.z;
                    v[0] += 1.0f;
                    v[1] += sx; v[2] += sy; v[3] += sz;
                    v[4] += tx; v[5] += ty; v[6] += tz;
                    v[7] += w;
                    float wsx = w * sx, wsy = w * sy, wsz = w * sz;
                    v[8] += wsx; v[9] += wsy; v[10] += wsz;
                    v[11] += w * tx; v[12] += w * ty; v[13] += w * tz;
                    v[14] += wsx * tx; v[15] += wsx * ty; v[16] += wsx * tz;
                    v[17] += wsy * tx; v[18] += wsy * ty; v[19] += wsy * tz;
                    v[20] += wsz * tx; v[21] += wsz * ty; v[22] += wsz * tz;
                }
            }
        }
#pragma unroll
        for (int m = 1; m < 8; m <<= 1) {
#pragma unroll
            for (int i = 0; i < 23; ++i) v[i] += __shfl_xor(v[i], m, 64);
        }
        if (lane8 == 0 && node < N) {
#pragma unroll
            for (int i = 0; i < 23; ++i) momG[(size_t)i * N + node] = v[i];
        }
    }
}

// One thread per node: expand moments -> M, fp64 Kabsch, R/T/wnode.
__global__ void __launch_bounds__(256) k_kabsch2(const float* __restrict__ momG,
                                                 const float4* __restrict__ s4,
                                                 const float4* __restrict__ t4,
                                                 float* __restrict__ Rout,
                                                 float* __restrict__ Tout,
                                                 float* __restrict__ wnode, int N) {
    int i = blockIdx.x * blockDim.x + threadIdx.x;
    if (i >= N) return;
    float m[23];
#pragma unroll
    for (int k = 0; k < 23; ++k) m[k] = momG[(size_t)k * N + i];
    double cntv = (double)m[0];
    double inv = 1.0 / fmax(cntv, 1.0);
    double sb[3] = {m[1] * inv, m[2] * inv, m[3] * inv};
    double tb[3] = {m[4] * inv, m[5] * inv, m[6] * inv};
    double Sw = m[7];
    double Sws[3] = {m[8], m[9], m[10]};
    double Swt[3] = {m[11], m[12], m[13]};
    double M[3][3];
#pragma unroll
    for (int r = 0; r < 3; ++r)
#pragma unroll
        for (int c = 0; c < 3; ++c)
            M[r][c] = (double)m[14 + 3 * r + c]
                    - sb[r] * Swt[c] - Sws[r] * tb[c] + Sw * sb[r] * tb[c];
    double Rm[3][3];
    kabsch_from_M(M, Rm);
    double T0 = tb[0] - (Rm[0][0] * sb[0] + Rm[0][1] * sb[1] + Rm[0][2] * sb[2]);
    double T1 = tb[1] - (Rm[1][0] * sb[0] + Rm[1][1] * sb[1] + Rm[1][2] * sb[2]);
    double T2 = tb[2] - (Rm[2][0] * sb[0] + Rm[2][1] * sb[1] + Rm[2][2] * sb[2]);
#pragma unroll
    for (int r = 0; r < 3; ++r)
#pragma unroll
        for (int c = 0; c < 3; ++c)
            Rout[9 * (long long)i + 3 * r + c] = (float)Rm[r][c];
    Tout[3 * i + 0] = (float)T0;
    Tout[3 * i + 1] = (float)T1;
    Tout[3 * i + 2] = (float)T2;
    float4 a = s4[i];
    float4 q = t4[i];
    double x0 = Rm[0][0] * a.x + Rm[0][1] * a.y + Rm[0][2] * a.z + T0;
    double x1 = Rm[1][0] * a.x + Rm[1][1] * a.y + Rm[1][2] * a.z + T1;
    double x2 = Rm[2][0] * a.x + Rm[2][1] * a.y + Rm[2][2] * a.z + T2;
    double d0 = x0 - q.x, d1 = x1 - q.y, d2 = x2 - q.z;
    double dd = d0 * d0 + d1 * d1 + d2 * d2;
    wnode[i] = (float)((double)kSigma2 / (dd + (double)kSigma2));
}

// wout[e] = wnode[nbr[e]] (8 edges/thread, vector loads, float4 stores).
__global__ void __launch_bounds__(256) k_wgather(const void* __restrict__ ei,
                                                 const float* __restrict__ wnode,
                                                 float* __restrict__ wout,
                                                 const int* __restrict__ nz,
                                                 int E, int N) {
    int gid = blockIdx.x * blockDim.x + threadIdx.x;
    long long base = (long long)gid * 8;
    if (base >= E) return;
    int is64 = (*nz == 0);
    int n_[8];
    int full = (base + 8 <= (long long)E);
    if (full) {
        if (is64) {
            const long long* p = (const long long*)ei + (long long)E + base;
#pragma unroll
            for (int k = 0; k < 4; ++k) {
                longlong2 a = ((const longlong2*)p)[k];
                n_[2 * k] = (int)a.x;
                n_[2 * k + 1] = (int)a.y;
            }
        } else {
            const int* p = (const int*)ei + (long long)E + base;
            int4 a = ((const int4*)p)[0];
            int4 b = ((const int4*)p)[1];
            n_[0] = a.x; n_[1] = a.y; n_[2] = a.z; n_[3] = a.w;
            n_[4] = b.x; n_[5] = b.y; n_[6] = b.z; n_[7] = b.w;
        }
        float w[8];
#pragma unroll
        for (int k = 0; k < 8; ++k)
            w[k] = ((unsigned)n_[k] < (unsigned)N) ? wnode[n_[k]] : 1.0f;
        *(float4*)(wout + base) = make_float4(w[0], w[1], w[2], w[3]);
        *(float4*)(wout + base + 4) = make_float4(w[4], w[5], w[6], w[7]);
    } else {
#pragma unroll
        for (int k = 0; k < 8; ++k) {
            long long e = base + k;
            if (e < E) {
                int n = load_idx(ei, (long long)E + e, is64);
                wout[e] = ((unsigned)n < (unsigned)N) ? wnode[n] : 1.0f;
            }
        }
    }
}

// ---------------- fallback atomic path ----------------

__global__ void k_accum1(const void* __restrict__ ei, const float* __restrict__ src,
                         const float* __restrict__ tgt, float* __restrict__ cnt,
                         float* __restrict__ ssum, float* __restrict__ tsum,
                         const int* __restrict__ nz, int E, int N) {
    int e = blockIdx.x * blockDim.x + threadIdx.x;
    if (e >= E) return;
    int is64 = (*nz == 0);
    int d = load_idx(ei, e, is64);
    int n = load_idx(ei, (long long)E + e, is64);
    if ((unsigned)d >= (unsigned)N || (unsigned)n >= (unsigned)N) return;
    atomicAdd(&cnt[d], 1.0f);
    atomicAdd(&ssum[3 * d + 0], src[3 * n + 0]);
    atomicAdd(&ssum[3 * d + 1], src[3 * n + 1]);
    atomicAdd(&ssum[3 * d + 2], src[3 * n + 2]);
    atomicAdd(&tsum[3 * d + 0], tgt[3 * n + 0]);
    atomicAdd(&tsum[3 * d + 1], tgt[3 * n + 1]);
    atomicAdd(&tsum[3 * d + 2], tgt[3 * n + 2]);
}

__global__ void k_centers(float* __restrict__ cnt, float* __restrict__ ssum,
                          float* __restrict__ tsum, int N) {
    int i = blockIdx.x * blockDim.x + threadIdx.x;
    if (i >= N) return;
    float inv = 1.0f / fmaxf(cnt[i], 1.0f);
    ssum[3 * i + 0] *= inv; ssum[3 * i + 1] *= inv; ssum[3 * i + 2] *= inv;
    tsum[3 * i + 0] *= inv; tsum[3 * i + 1] *= inv; tsum[3 * i + 2] *= inv;
}

__global__ void k_accum2(const void* __restrict__ ei, const float* __restrict__ src,
                         const float* __restrict__ tgt, const float* __restrict__ ew,
                         const float* __restrict__ sc, const float* __restrict__ tc,
                         float* __restrict__ Mm, const int* __restrict__ nz, int E, int N) {
    int e = blockIdx.x * blockDim.x + threadIdx.x;
    if (e >= E) return;
    int is64 = (*nz == 0);
    int d = load_idx(ei, e, is64);
    int n = load_idx(ei, (long long)E + e, is64);
    if ((unsigned)d >= (unsigned)N || (unsigned)n >= (unsigned)N) return;
    float w = ew[e];
    float a0 = (src[3 * n + 0] - sc[3 * d + 0]) * w;
    float a1 = (src[3 * n + 1] - sc[3 * d + 1]) * w;
    float a2 = (src[3 * n + 2] - sc[3 * d + 2]) * w;
    float b0 = tgt[3 * n + 0] - tc[3 * d + 0];
    float b1 = tgt[3 * n + 1] - tc[3 * d + 1];
    float b2 = tgt[3 * n + 2] - tc[3 * d + 2];
    float* Md = Mm + 9 * (long long)d;
    atomicAdd(Md + 0, a0 * b0); atomicAdd(Md + 1, a0 * b1); atomicAdd(Md + 2, a0 * b2);
    atomicAdd(Md + 3, a1 * b0); atomicAdd(Md + 4, a1 * b1); atomicAdd(Md + 5, a1 * b2);
    atomicAdd(Md + 6, a2 * b0); atomicAdd(Md + 7, a2 * b1); atomicAdd(Md + 8, a2 * b2);
}

__global__ void k_kabsch(const float* __restrict__ Mm, const float* __restrict__ sc,
                         const float* __restrict__ tc, float* __restrict__ Rout,
                         float* __restrict__ Tout, int N) {
    int i = blockIdx.x * blockDim.x + threadIdx.x;
    if (i >= N) return;
    double M[3][3];
#pragma unroll
    for (int r = 0; r < 3; ++r)
#pragma unroll
        for (int c = 0; c < 3; ++c)
            M[r][c] = (double)Mm[9 * (long long)i + 3 * r + c];
    double Rm[3][3];
    kabsch_from_M(M, Rm);
    double s0 = sc[3 * i + 0], s1 = sc[3 * i + 1], s2 = sc[3 * i + 2];
    double t0 = tc[3 * i + 0], t1 = tc[3 * i + 1], t2 = tc[3 * i + 2];
#pragma unroll
    for (int r = 0; r < 3; ++r)
#pragma unroll
        for (int c = 0; c < 3; ++c)
            Rout[9 * (long long)i + 3 * r + c] = (float)Rm[r][c];
    Tout[3 * i + 0] = (float)(t0 - (Rm[0][0] * s0 + Rm[0][1] * s1 + Rm[0][2] * s2));
    Tout[3 * i + 1] = (float)(t1 - (Rm[1][0] * s0 + Rm[1][1] * s1 + Rm[1][2] * s2));
    Tout[3 * i + 2] = (float)(t2 - (Rm[2][0] * s0 + Rm[2][1] * s1 + Rm[2][2] * s2));
}

__global__ void k_weights_plain(const void* __restrict__ ei,
                                const float* __restrict__ src,
                                const float* __restrict__ tgt,
                                const float* __restrict__ R,
                                const float* __restrict__ T,
                                float* __restrict__ wout,
                                const int* __restrict__ nz, int E, int N) {
    int e = blockIdx.x * blockDim.x + threadIdx.x;
    if (e >= E) return;
    int is64 = (*nz == 0);
    int n = load_idx(ei, (long long)E + e, is64);
    float w = 1.0f;
    if ((unsigned)n < (unsigned)N) {
        float p0 = src[3 * n + 0], p1 = src[3 * n + 1], p2 = src[3 * n + 2];
        float q0 = tgt[3 * n + 0], q1 = tgt[3 * n + 1], q2 = tgt[3 * n + 2];
        const float* Rn = R + 9 * (long long)n;
        const float* Tn = T + 3 * (long long)n;
        float x0 = Rn[0] * p0 + Rn[1] * p1 + Rn[2] * p2 + Tn[0];
        float x1 = Rn[3] * p0 + Rn[4] * p1 + Rn[5] * p2 + Tn[1];
        float x2 = Rn[6] * p0 + Rn[7] * p1 + Rn[8] * p2 + Tn[2];
        float d0 = x0 - q0, d1 = x1 - q1, d2 = x2 - q2;
        float dd = d0 * d0 + d1 * d1 + d2 * d2;
        w = kSigma2 / (dd + kSigma2);
    }
    wout[e] = w;
}

extern "C" void kernel_launch(void* const* d_in, const int* in_sizes, int n_in,
                              void* d_out, int out_size, void* d_ws, size_t ws_size,
                              hipStream_t stream) {
    const float* src = (const float*)d_in[0];
    const float* tgt = (const float*)d_in[1];
    const void* ei = d_in[2];
    const float* ew = (const float*)d_in[3];
    int N = in_sizes[0] / 3;
    int E = in_sizes[3];

    float* out = (float*)d_out;
    float* Rout = out;
    float* Tout = out + (size_t)9 * N;
    float* Wout = out + (size_t)12 * N;

    int eb = (E + 255) / 256;
    int nb = (N + 255) / 256;
    int nbuckets = (N + 63) / 64;            // 64-node fine buckets
    int ncoarse = (nbuckets + 127) / 128;    // 8192-node coarse buckets
    int tiles = (int)(((long long)E + 2047) / 2048);
    int tiles16 = (int)(((long long)E + 16383) / 16384);
    int wb8 = (int)(((long long)E + 2047) / 2048);

    // ws layout: [nz(16) | btot16 | cur16 | curC16(256) | boff | pad4 |
    //             sedge1 (E int2) | [sedge2 (E int2)] | s4 | t4 | wnode(N) | momG(23N)]
    size_t ctrl_ints = 16 + (size_t)nbuckets * 16 * 2 + 256 + (nbuckets + 1);
    ctrl_ints = (ctrl_ints + 3) & ~(size_t)3;
    size_t after1 = ctrl_ints + 2 * (size_t)E;
    after1 = (after1 + 3) & ~(size_t)3;
    size_t after2 = after1 + 2 * (size_t)E;
    after2 = (after2 + 3) & ~(size_t)3;
    size_t tail_ints = 8 * (size_t)N + (size_t)N + 23 * (size_t)N;
    size_t needA = (after2 + tail_ints) * sizeof(int);
    size_t needB = (after1 + tail_ints) * sizeof(int);

    if (N <= 131072 && nbuckets <= 2048 && ws_size >= needB) {
        int twolevel = (ws_size >= needA) ? 1 : 0;
        int* nz = (int*)d_ws;
        int* btot16 = nz + 16;
        int* cur16 = btot16 + (size_t)nbuckets * 16;
        int* curC16 = cur16 + (size_t)nbuckets * 16;
        int* boff = curC16 + 256;
        int2* sedge1 = (int2*)((int*)d_ws + ctrl_ints);
        size_t tail_base = twolevel ? after2 : after1;
        int2* sedge2 = twolevel ? (int2*)((int*)d_ws + after1) : sedge1;
        float4* s4 = (float4*)((int*)d_ws + tail_base);
        float4* t4 = s4 + N;
        float* wnode = (float*)(t4 + N);
        float* momG = wnode + N;

        hipMemsetAsync(d_ws, 0, ctrl_ints * sizeof(int), stream);

        k_detect<<<1, 256, 0, stream>>>((const int*)ei, E, nz);
        k_pack<<<nb, 256, 0, stream>>>(src, tgt, s4, t4, N);
        k_bhist<<<tiles16, 256, 0, stream>>>(ei, btot16, nz, E, N, nbuckets);
        k_scan<<<1, 1024, 0, stream>>>(btot16, boff, cur16, curC16, nbuckets);
        if (twolevel) {
            k_cscatter<<<tiles, 256, 0, stream>>>(ei, ew, curC16, sedge1, nz, E, N, ncoarse);
            k_fscatter<<<tiles, 256, 0, stream>>>(sedge1, cur16, boff, sedge2, E, nbuckets, ncoarse);
        } else {
            k_binscatter<<<tiles, 256, 0, stream>>>(ei, ew, cur16, sedge2, nz, E, N, nbuckets);
        }
        k_sortmoment<<<nbuckets, 256, 0, stream>>>(boff, sedge2, s4, t4, momG, N);
        k_kabsch2<<<nb, 256, 0, stream>>>(momG, s4, t4, Rout, Tout, wnode, N);
        k_wgather<<<wb8, 256, 0, stream>>>(ei, wnode, Wout, nz, E, N);
    } else {
        // fallback: atomic path
        float* cnt = (float*)d_ws;
        float* ssum = cnt + N;
        float* tsum = ssum + 3 * (size_t)N;
        float* Mm = tsum + 3 * (size_t)N;
        int* nz = (int*)(Mm + 9 * (size_t)N);
        size_t ws_bytes = (size_t)16 * N * sizeof(float) + 16;
        hipMemsetAsync(d_ws, 0, ws_bytes, stream);
        k_detect<<<1, 256, 0, stream>>>((const int*)ei, E, nz);
        k_accum1<<<eb, 256, 0, stream>>>(ei, src, tgt, cnt, ssum, tsum, nz, E, N);
        k_centers<<<nb, 256, 0, stream>>>(cnt, ssum, tsum, N);
        k_accum2<<<eb, 256, 0, stream>>>(ei, src, tgt, ew, ssum, tsum, Mm, nz, E, N);
        k_kabsch<<<nb, 256, 0, stream>>>(Mm, ssum, tsum, Rout, Tout, N);
        k_weights_plain<<<eb, 256, 0, stream>>>(ei, src, tgt, Rout, Tout, Wout, nz, E, N);
    }
}